// Round 11
// baseline (344.718 us; speedup 1.0000x reference)
//
#include <hip/hip_runtime.h>
#include <cstdint>

typedef unsigned short u16;
typedef __attribute__((ext_vector_type(4))) unsigned short u16x4;
typedef __attribute__((ext_vector_type(8))) short short8;
typedef __attribute__((ext_vector_type(4))) float f32x4;

#define DI 512
#define CIN 1024
#define NPIX 4096   // 64*64
#define MPIX 1024   // 32*32

__device__ __forceinline__ float bf2f(u16 u) {
  union { unsigned int i; float f; } v; v.i = ((unsigned int)u) << 16; return v.f;
}
__device__ __forceinline__ u16 f2bf(float f) {
  union { float f; unsigned int i; } v; v.f = f;
  unsigned int r = v.i + 0x7fffu + ((v.i >> 16) & 1u);
  return (u16)(r >> 16);
}
__device__ __forceinline__ void unpack8(uint4 v, float* f) {
  union { unsigned int i; float f; } u;
  u.i = v.x << 16;          f[0] = u.f;
  u.i = v.x & 0xffff0000u;  f[1] = u.f;
  u.i = v.y << 16;          f[2] = u.f;
  u.i = v.y & 0xffff0000u;  f[3] = u.f;
  u.i = v.z << 16;          f[4] = u.f;
  u.i = v.z & 0xffff0000u;  f[5] = u.f;
  u.i = v.w << 16;          f[6] = u.f;
  u.i = v.w & 0xffff0000u;  f[7] = u.f;
}

// async global->LDS, 16B per lane, wave-uniform LDS base + lane*16
__device__ __forceinline__ void gload16(const u16* g, u16* l) {
  __builtin_amdgcn_global_load_lds(
      (const __attribute__((address_space(1))) void*)g,
      (__attribute__((address_space(3))) void*)l, 16, 0, 0);
}

template<int N> __device__ __forceinline__ void wait_vmcnt() {
  asm volatile("s_waitcnt vmcnt(%0)" :: "n"(N) : "memory");
}
__device__ __forceinline__ void phase_begin() {
  __builtin_amdgcn_s_barrier();
  __builtin_amdgcn_sched_barrier(0);
  asm volatile("" ::: "memory");
}
__device__ __forceinline__ void phase_end() {
  asm volatile("s_waitcnt lgkmcnt(0)" ::: "memory");
  __builtin_amdgcn_sched_barrier(0);
  __builtin_amdgcn_s_barrier();
  __builtin_amdgcn_sched_barrier(0);
}

// ---------------- f32 -> bf16 convert (4 weight tensors in one launch) ----
__global__ __launch_bounds__(256) void cvt4_kernel(
    const float* __restrict__ s0, const float* __restrict__ s1,
    const float* __restrict__ s2, const float* __restrict__ s3,
    u16* __restrict__ d0, u16* __restrict__ d1,
    u16* __restrict__ d2, u16* __restrict__ d3) {
  int i = blockIdx.x * 256 + threadIdx.x;     // 0 .. 4*131072
  int sel = i >> 17;
  int j = i & 131071;
  const float* src = sel == 0 ? s0 : sel == 1 ? s1 : sel == 2 ? s2 : s3;
  u16* dst = sel == 0 ? d0 : sel == 1 ? d1 : sel == 2 ? d2 : d3;
  float4 v = *(const float4*)(src + (long)j * 4);
  u16x4 w;
  w[0] = f2bf(v.x); w[1] = f2bf(v.y); w[2] = f2bf(v.z); w[3] = f2bf(v.w);
  *(u16x4*)(dst + (long)j * 4) = w;
}

// ------- x [b][c][n] f32 -> x_T [b][n][c] bf16 + fused 2x2 maxpool -------
__global__ __launch_bounds__(256) void transpose_pool_kernel(
    const float* __restrict__ x, u16* __restrict__ xT, u16* __restrict__ poolT) {
  __shared__ u16 tile[64][136];
  const int b = blockIdx.z;
  const int n0 = blockIdx.x * 128, c0 = blockIdx.y * 64;
  const float* xb = x + (long)b * CIN * NPIX;
  u16* xTb = xT + (long)b * NPIX * CIN;
  const int t = threadIdx.x;
  const int tc = t >> 5, tn = (t & 31) * 4;
  #pragma unroll
  for (int i = 0; i < 8; i++) {
    int c = tc + i * 8;
    float4 v = *(const float4*)(xb + (long)(c0 + c) * NPIX + n0 + tn);
    u16x4 w;
    w[0] = f2bf(v.x); w[1] = f2bf(v.y); w[2] = f2bf(v.z); w[3] = f2bf(v.w);
    *(u16x4*)&tile[c][tn] = w;
  }
  __syncthreads();
  const int tn2 = t >> 4, tc2 = (t & 15) * 4;
  #pragma unroll
  for (int i = 0; i < 8; i++) {
    int n = tn2 + i * 16;
    u16x4 w;
    w[0] = tile[tc2 + 0][n];
    w[1] = tile[tc2 + 1][n];
    w[2] = tile[tc2 + 2][n];
    w[3] = tile[tc2 + 3][n];
    *(u16x4*)(xTb + (long)(n0 + n) * CIN + c0 + tc2) = w;
  }
  const int j = t & 31, g = t >> 5;
  u16 r[8] __attribute__((aligned(16)));
  #pragma unroll
  for (int k = 0; k < 8; k++) {
    const int c = g * 8 + k;
    const unsigned d0 = *(const unsigned*)&tile[c][2 * j];
    const unsigned d1 = *(const unsigned*)&tile[c][64 + 2 * j];
    float m0 = fmaxf(bf2f((u16)(d0 & 0xffffu)), bf2f((u16)(d0 >> 16)));
    float m1 = fmaxf(bf2f((u16)(d1 & 0xffffu)), bf2f((u16)(d1 >> 16)));
    r[k] = f2bf(fmaxf(m0, m1));
  }
  *(uint4*)(poolT + ((long)b * MPIX + blockIdx.x * 32 + j) * CIN + c0 + g * 8) =
      *(uint4*)r;
}

// =============== 256x256-tile GEMM, 8 waves, 8-phase counted-vmcnt =======
// C[M][N] = A[M][K]*B[N][K]^T. OM: 0 = bf16 [M][N], 1 = bf16 [N][M].
// LDS: 2 slots x 4 quarters {A-k0,A-k1,B-k0,B-k1}, 16KB each.
// Quarter layout: 256 rows x 32 bf16, 16B-slot swizzle s' = s ^ ((row>>1)&3)
// (matching pre-swizzled global source chunk (l&3)^((l>>3)&3)).
// Iteration u (tiles 2u->slot0, 2u+1->slot1), 8 phases; stage schedule:
//   ph0:A-k1(2u+1) ph1:B-k1(2u+1) ph2:A-k0(2u+2) ph3:B-k0(2u+2)
//   ph4:A-k1(2u+2) ph5:B-k1(2u+2) ph6:A-k0(2u+3) ph7:B-k0(2u+3)
// Compute: ph0-3 slot0 (kk0 ri0-3, kk0 ri4-7, kk1 ri0-3, kk1 ri4-7), ph4-7 slot1.
// Every consumed quarter staged >=5 phases earlier -> vmcnt(10) in main loop;
// peeled last iteration uses [10,10,8,6,4,2,0,0].
template<int OM, bool HAS_BIAS, bool HAS_SHIFT, bool HAS_EXP, bool HAS_PSUM2,
         bool HAS_CSP>
__global__ __launch_bounds__(512, 2)
void gemm256(const u16* __restrict__ A, const u16* __restrict__ B,
             void* __restrict__ Cv,
             const float* __restrict__ bias, long sBias,
             const float* __restrict__ cs, long sCS,
             const float* __restrict__ shift, long sShift,
             float* __restrict__ psum_out,
             float scale, int M, int N, int K, long sA, long sB, long sC)
{
  A += blockIdx.z * sA;
  B += blockIdx.z * sB;
  if (HAS_BIAS) bias += blockIdx.z * sBias;
  if (HAS_CSP) cs += blockIdx.z * sCS;
  if (HAS_SHIFT) shift += blockIdx.z * sShift;
  const int bm = blockIdx.y * 256, bn = blockIdx.x * 256;
  __shared__ __align__(16) u16 smem[65536];   // 2 slots x 64KB
  __shared__ float psum[4][256];
  __shared__ float psumq[4][256];
  __shared__ float invs[256];
  const int tid = threadIdx.x;
  const int lane = tid & 63, wave = tid >> 6;
  const int wr = wave >> 2, wc = wave & 3;       // 2M x 4N waves
  const int lr = lane & 15, q = lane >> 4;
  f32x4 acc[8][4] = {};

  if (HAS_CSP) {
    if (tid < 256) {
      float ssum = 0.f;
      #pragma unroll
      for (int xx = 0; xx < 4; xx++) ssum += cs[xx * 4096 + bn + tid];
      invs[tid] = 1.0f / ssum;
    }
    wait_vmcnt<0>();                 // keep cs loads out of the K-loop FIFO
    __builtin_amdgcn_sched_barrier(0);
  }

  // staging constants: lane l -> row 32w+16i+(l>>2), chunk (l&3)^((l>>3)&3)
  const int srow = 32 * wave + (lane >> 2);
  const int sk = (((lane & 3) ^ ((lane >> 3) & 3))) * 8;
  const u16* Abase = A + ((long)bm + srow) * K + sk;
  const u16* Bbase = B + ((long)bn + srow) * K + sk;
  // ds_read offsets (u16 units, within slot): row*32 + swizzled 16B slot
  const int rswz = (q ^ ((lr >> 1) & 3)) * 8;
  const int aoff = (wr * 128 + lr) * 32 + rswz;           // + slot*32768 + kk*8192
  const int boff = 16384 + (wc * 64 + lr) * 32 + rswz;

#define SA(T_, KK_) { const u16* g_ = Abase + (long)(T_) * 64 + (KK_) * 32; \
    u16* d_ = &smem[(((T_) & 1)) * 32768 + (KK_) * 8192 + wave * 1024]; \
    gload16(g_, d_); gload16(g_ + 16 * (long)K, d_ + 512); }
#define SB(T_, KK_) { const u16* g_ = Bbase + (long)(T_) * 64 + (KK_) * 32; \
    u16* d_ = &smem[(((T_) & 1)) * 32768 + 16384 + (KK_) * 8192 + wave * 1024]; \
    gload16(g_, d_); gload16(g_ + 16 * (long)K, d_ + 512); }
#define CQ(SLOT, KK, RI0, LOADBV) { \
    const int qb_ = (SLOT) * 32768 + (KK) * 8192; \
    if (LOADBV) { \
      _Pragma("unroll") \
      for (int ci_ = 0; ci_ < 4; ci_++) \
        bv[ci_] = *(const short8*)&smem[qb_ + boff + ci_ * 512]; \
    } \
    short8 av_[4]; \
    _Pragma("unroll") \
    for (int r_ = 0; r_ < 4; r_++) \
      av_[r_] = *(const short8*)&smem[qb_ + aoff + ((RI0) + r_) * 512]; \
    __builtin_amdgcn_s_setprio(1); \
    _Pragma("unroll") \
    for (int r_ = 0; r_ < 4; r_++) \
      _Pragma("unroll") \
      for (int ci_ = 0; ci_ < 4; ci_++) \
        acc[(RI0) + r_][ci_] = __builtin_amdgcn_mfma_f32_16x16x32_bf16( \
            av_[r_], bv[ci_], acc[(RI0) + r_][ci_], 0, 0, 0); \
    __builtin_amdgcn_s_setprio(0); }
#define PH(VM, STG, SLOT, KK, RI0, LOADBV) \
    STG; wait_vmcnt<VM>(); phase_begin(); CQ(SLOT, KK, RI0, LOADBV); phase_end();

  const int niter2 = K >> 7;   // iterations of 2 K-tiles (K=512->4, 1024->8)
  short8 bv[4];

  // prologue: 6 quarters in exact FIFO order (simulating iter -1 ph2..ph7)
  SA(0, 0); SB(0, 0); SA(0, 1); SB(0, 1); SA(1, 0); SB(1, 0);

  for (int u = 0; u < niter2 - 1; ++u) {
    const int t1 = 2 * u + 1, t2 = 2 * u + 2, t3 = 2 * u + 3;
    PH(10, SA(t1, 1), 0, 0, 0, 1)
    PH(10, SB(t1, 1), 0, 0, 4, 0)
    PH(10, SA(t2, 0), 0, 1, 0, 1)
    PH(10, SB(t2, 0), 0, 1, 4, 0)
    PH(10, SA(t2, 1), 1, 0, 0, 1)
    PH(10, SB(t2, 1), 1, 0, 4, 0)
    PH(10, SA(t3, 0), 1, 1, 0, 1)
    PH(10, SB(t3, 0), 1, 1, 4, 0)
  }
  {
    const int t1 = 2 * (niter2 - 1) + 1;   // = T-1
    PH(10, SA(t1, 1), 0, 0, 0, 1)
    PH(10, SB(t1, 1), 0, 0, 4, 0)
    PH(8,  ((void)0), 0, 1, 0, 1)
    PH(6,  ((void)0), 0, 1, 4, 0)
    PH(4,  ((void)0), 1, 0, 0, 1)
    PH(2,  ((void)0), 1, 0, 4, 0)
    PH(0,  ((void)0), 1, 1, 0, 1)
    PH(0,  ((void)0), 1, 1, 4, 0)
  }
#undef SA
#undef SB
#undef CQ
#undef PH

  __syncthreads();   // full drain; LDS free for epilogue staging

  const int dr = (lane >> 4) * 4;
  float invc[4];
  if (HAS_CSP) {
    #pragma unroll
    for (int ci = 0; ci < 4; ci++) invc[ci] = invs[wc * 64 + ci * 16 + lr];
  }
  float rowsum[8][4], rowsq[8][4];
  if (HAS_EXP || HAS_PSUM2) {
    #pragma unroll
    for (int ri = 0; ri < 8; ri++)
      #pragma unroll
      for (int r = 0; r < 4; r++) { rowsum[ri][r] = 0.f; rowsq[ri][r] = 0.f; }
  }
  #pragma unroll
  for (int ri = 0; ri < 8; ri++) {
    const int rowl = wr * 128 + ri * 16 + dr;
    const int rowb = bm + rowl;
    float bvs[4] = {0.f, 0.f, 0.f, 0.f};
    float shv[4] = {0.f, 0.f, 0.f, 0.f};
    if (HAS_BIAS) {
      #pragma unroll
      for (int r = 0; r < 4; r++) bvs[r] = bias[rowb + r];
    }
    if (HAS_SHIFT) {
      #pragma unroll
      for (int r = 0; r < 4; r++) shv[r] = shift[rowb + r];
    }
    #pragma unroll
    for (int ci = 0; ci < 4; ci++) {
      const int coll = wc * 64 + ci * 16 + lr;
      float v[4];
      #pragma unroll
      for (int r = 0; r < 4; r++) {
        float tv = acc[ri][ci][r] * scale;
        if (HAS_CSP) tv *= invc[ci];
        if (HAS_SHIFT) tv -= shv[r];
        if (HAS_BIAS) tv += bvs[r];
        if (HAS_EXP) tv = expf(tv);
        if (HAS_EXP || HAS_PSUM2) rowsum[ri][r] += tv;
        if (HAS_PSUM2) rowsq[ri][r] += tv * tv;
        v[r] = tv;
      }
      if (OM == 1) {
        u16x4 w;
        #pragma unroll
        for (int r = 0; r < 4; r++) w[r] = f2bf(v[r]);
        unsigned bo = (unsigned)((coll * 256 + rowl) * 2) ^ ((coll & 7) << 4);
        *(u16x4*)((char*)smem + bo) = w;
      } else {
        #pragma unroll
        for (int r = 0; r < 4; r++) smem[(rowl + r) * 256 + coll] = f2bf(v[r]);
      }
    }
  }
  if (HAS_EXP || HAS_PSUM2) {
    #pragma unroll
    for (int msk = 1; msk < 16; msk <<= 1)
      #pragma unroll
      for (int ri = 0; ri < 8; ri++)
        #pragma unroll
        for (int r = 0; r < 4; r++) {
          rowsum[ri][r] += __shfl_xor(rowsum[ri][r], msk);
          if (HAS_PSUM2) rowsq[ri][r] += __shfl_xor(rowsq[ri][r], msk);
        }
    if ((lane & 15) == 0) {
      #pragma unroll
      for (int ri = 0; ri < 8; ri++)
        #pragma unroll
        for (int r = 0; r < 4; r++) {
          psum[wc][wr * 128 + ri * 16 + dr + r] = rowsum[ri][r];
          if (HAS_PSUM2) psumq[wc][wr * 128 + ri * 16 + dr + r] = rowsq[ri][r];
        }
    }
  }
  __syncthreads();
  u16* C = (u16*)Cv + blockIdx.z * sC;
  if (OM == 1) {
    #pragma unroll
    for (int i = 0; i < 16; i++) {
      const int chunk = i * 512 + tid;
      const int coll = chunk >> 5, rq = chunk & 31;
      unsigned bo = (unsigned)(coll * 512 + rq * 16) ^ ((coll & 7) << 4);
      uint4 w = *(const uint4*)((const char*)smem + bo);
      *(uint4*)(C + (long)(bn + coll) * M + bm + rq * 8) = w;
    }
  } else {
    #pragma unroll
    for (int i = 0; i < 16; i++) {
      const int chunk = i * 512 + tid;
      const int row = chunk >> 5, cq = chunk & 31;
      uint4 w = *(const uint4*)(smem + row * 256 + cq * 8);
      *(uint4*)(C + (long)(bm + row) * N + bn + cq * 8) = w;
    }
  }
  if ((HAS_EXP || HAS_PSUM2) && tid < 256) {
    if (HAS_EXP)
      psum_out[((long)blockIdx.z * gridDim.x + blockIdx.x) * 4096 + bm + tid] =
          psum[0][tid] + psum[1][tid] + psum[2][tid] + psum[3][tid];
    if (HAS_PSUM2) {
      const long blk = ((long)blockIdx.z * gridDim.y + blockIdx.y) * gridDim.x
                       + blockIdx.x;
      psum_out[blk * 512 + tid] =
          psum[0][tid] + psum[1][tid] + psum[2][tid] + psum[3][tid];
      psum_out[blk * 512 + 256 + tid] =
          psumq[0][tid] + psumq[1][tid] + psumq[2][tid] + psumq[3][tid];
    }
  }
}

// ---------------- old 128x128 GEMM (kept for merged phi+g) ----------------
template<int OM, bool HAS_BIAS, bool HAS_CS, bool HAS_SHIFT, bool HAS_EXP,
         bool HAS_PSUM2, bool HAS_CSP>
__global__ __launch_bounds__(256)
void gemm_tn(const u16* __restrict__ A, const u16* __restrict__ B,
             void* __restrict__ Cv, void* __restrict__ Cv2,
             const float* __restrict__ bias, const float* __restrict__ bias2,
             long sBias,
             const float* __restrict__ cs, long sCS,
             const float* __restrict__ shift, long sShift,
             float* __restrict__ psum_out,
             float scale, int M, int N, int K, long sA, long sB, long sC)
{
  A += blockIdx.z * sA;
  B += blockIdx.z * sB;
  if (HAS_BIAS) bias += blockIdx.z * sBias;
  if (HAS_CS || HAS_CSP) cs += blockIdx.z * sCS;
  if (HAS_SHIFT) shift += blockIdx.z * sShift;
  const int bm = blockIdx.y * 128;
  const int bn = blockIdx.x * 128;
  __shared__ __align__(16) u16 smem[128 * 128];
  u16* As = smem;
  u16* Bs = smem + 128 * 64;
  __shared__ float psum[4][128];
  const int tid = threadIdx.x;
  const int lane = tid & 63;
  const int wave = tid >> 6;
  const int wm = (wave >> 1) * 64;
  const int wn = (wave & 1) * 64;
  const int lr = lane & 15;
  const int q  = lane >> 4;
  const int sxor = lane & 7;
  const bool gps = (OM == 3) && (bm >= 512);
  f32x4 acc[4][4] = {};

  if (HAS_CSP) {
    if (tid < 128) {
      float s = 0.f;
      #pragma unroll
      for (int xx = 0; xx < 8; xx++) s += cs[xx * 4096 + bn + tid];
      psum[0][tid] = 1.0f / s;
    }
  }

  const int swz = ((lane & 7) ^ (lane >> 3)) * 8;
  const long grow = 32 * wave + (lane >> 3);
  const u16* Ag = A + ((long)bm + grow) * K + swz;
  const u16* Bg = B + ((long)bn + grow) * K + swz;

  for (int kt = 0; kt < K; kt += 64) {
    __syncthreads();
    #pragma unroll
    for (int i = 0; i < 4; i++) {
      gload16(Ag + (long)(8 * i) * K + kt, &As[(wave * 4 + i) * 512]);
      gload16(Bg + (long)(8 * i) * K + kt, &Bs[(wave * 4 + i) * 512]);
    }
    __syncthreads();
    #pragma unroll
    for (int kk = 0; kk < 2; kk++) {
      short8 av[4], bv[4];
      #pragma unroll
      for (int mi = 0; mi < 4; mi++)
        av[mi] = *(const short8*)&As[(wm + mi * 16 + lr) * 64 +
                                     (((kk << 2) + q) ^ sxor) * 8];
      #pragma unroll
      for (int ni = 0; ni < 4; ni++)
        bv[ni] = *(const short8*)&Bs[(wn + ni * 16 + lr) * 64 +
                                     (((kk << 2) + q) ^ sxor) * 8];
      #pragma unroll
      for (int mi = 0; mi < 4; mi++) {
        #pragma unroll
        for (int ni = 0; ni < 4; ni++)
          acc[mi][ni] = __builtin_amdgcn_mfma_f32_16x16x32_bf16(
              av[mi], bv[ni], acc[mi][ni], 0, 0, 0);
      }
    }
  }

  float invc[4];
  if (HAS_CSP) {
    #pragma unroll
    for (int ni = 0; ni < 4; ni++) invc[ni] = psum[0][wn + ni * 16 + lr];
  }
  __syncthreads();
  const int dr = (lane >> 4) * 4;
  const bool trans_out = (OM == 1) || (OM == 3 && !gps);
  float rowsum[4][4];
  float rowsq[4][4];
  if (HAS_EXP || HAS_PSUM2 || gps) {
    #pragma unroll
    for (int mi = 0; mi < 4; mi++)
      #pragma unroll
      for (int r = 0; r < 4; r++) { rowsum[mi][r] = 0.f; rowsq[mi][r] = 0.f; }
  }
  const float* bp = (OM == 3 && gps) ? bias2 - 512 : bias;
  #pragma unroll
  for (int mi = 0; mi < 4; mi++) {
    const int rowl = wm + mi * 16 + dr;
    const int rowb = bm + rowl;
    float bvs[4] = {0.f, 0.f, 0.f, 0.f};
    float shv[4] = {0.f, 0.f, 0.f, 0.f};
    if (HAS_BIAS) {
      #pragma unroll
      for (int r = 0; r < 4; r++) bvs[r] = bp[rowb + r];
    }
    if (HAS_SHIFT) {
      #pragma unroll
      for (int r = 0; r < 4; r++) shv[r] = shift[rowb + r];
    }
    #pragma unroll
    for (int ni = 0; ni < 4; ni++) {
      const int coll = wn + ni * 16 + lr;
      const float csv = HAS_CSP ? invc[ni] : (HAS_CS ? cs[bn + coll] : 1.0f);
      float v[4];
      #pragma unroll
      for (int r = 0; r < 4; r++) {
        float t = acc[mi][ni][r] * scale;
        if (HAS_CS || HAS_CSP) t *= csv;
        if (HAS_SHIFT) t -= shv[r];
        if (HAS_BIAS) t += bvs[r];
        if (HAS_EXP) t = expf(t);
        if (HAS_EXP || HAS_PSUM2 || gps) rowsum[mi][r] += t;
        if (HAS_PSUM2) rowsq[mi][r] += t * t;
        v[r] = t;
      }
      if (trans_out) {
        u16x4 w;
        #pragma unroll
        for (int r = 0; r < 4; r++) w[r] = f2bf(v[r]);
        unsigned bo = (unsigned)((coll * 128 + rowl) * 2) ^ ((coll & 7) << 4);
        *(u16x4*)((char*)smem + bo) = w;
      } else {
        #pragma unroll
        for (int r = 0; r < 4; r++) smem[(rowl + r) * 128 + coll] = f2bf(v[r]);
      }
    }
  }
  if (HAS_EXP || HAS_PSUM2 || gps) {
    #pragma unroll
    for (int msk = 1; msk < 16; msk <<= 1)
      #pragma unroll
      for (int mi = 0; mi < 4; mi++)
        #pragma unroll
        for (int r = 0; r < 4; r++) {
          rowsum[mi][r] += __shfl_xor(rowsum[mi][r], msk);
          if (HAS_PSUM2) rowsq[mi][r] += __shfl_xor(rowsq[mi][r], msk);
        }
    if ((lane & 15) == 0) {
      #pragma unroll
      for (int mi = 0; mi < 4; mi++)
        #pragma unroll
        for (int r = 0; r < 4; r++) {
          psum[wave & 1][wm + mi * 16 + dr + r] = rowsum[mi][r];
          if (HAS_PSUM2) psum[2 + (wave & 1)][wm + mi * 16 + dr + r] = rowsq[mi][r];
        }
    }
  }
  __syncthreads();
  if (trans_out) {
    const int Ms = (OM == 3) ? 512 : M;
    u16* C = (u16*)Cv + blockIdx.z * sC;
    #pragma unroll
    for (int i = 0; i < 8; i++) {
      const int chunk = i * 256 + tid;
      const int coll = chunk >> 4, rq = chunk & 15;
      unsigned bo = (unsigned)(coll * 256 + rq * 16) ^ ((coll & 7) << 4);
      uint4 w = *(const uint4*)((const char*)smem + bo);
      *(uint4*)(C + (long)(bn + coll) * Ms + bm + rq * 8) = w;
    }
  } else {
    u16* C = (OM == 3) ? (u16*)Cv2 + blockIdx.z * sC : (u16*)Cv + blockIdx.z * sC;
    const int rbase = (OM == 3) ? bm - 512 : bm;
    #pragma unroll
    for (int i = 0; i < 8; i++) {
      const int chunk = i * 256 + tid;
      const int row = chunk >> 4, cq = chunk & 15;
      uint4 w = *(const uint4*)(smem + row * 128 + cq * 8);
      *(uint4*)(C + (long)(rbase + row) * N + bn + cq * 8) = w;
    }
  }
  if (HAS_EXP || HAS_PSUM2 || gps) {
    if (tid < 128) {
      if (HAS_EXP)
        psum_out[((long)blockIdx.z * gridDim.x + blockIdx.x) * 4096 + bm + tid] =
            psum[0][tid] + psum[1][tid];
      if (HAS_PSUM2) {
        const long blk = ((long)blockIdx.z * gridDim.y + blockIdx.y) * gridDim.x
                         + blockIdx.x;
        psum_out[blk * 256 + tid] = psum[0][tid] + psum[1][tid];
        psum_out[blk * 256 + 128 + tid] = psum[2][tid] + psum[3][tid];
      }
      if (gps)
        psum_out[((long)blockIdx.z * gridDim.x + blockIdx.x) * 512 +
                 (bm - 512) + tid] = psum[0][tid] + psum[1][tid];
    }
  }
}

// ------- gbar[b][d] = (1/1024) * sum_x g_ps[b][x][d] --------------------
__global__ __launch_bounds__(256) void gbar_kernel(const float* __restrict__ g_ps,
                                                   float* __restrict__ gbar) {
  const int idx = blockIdx.x * 256 + threadIdx.x;   // 0..4095 = b*512+d
  const int b = idx >> 9, d = idx & 511;
  const float* p = g_ps + (long)b * 8 * 512 + d;
  float s = 0.f;
  #pragma unroll
  for (int xx = 0; xx < 8; xx++) s += p[(long)xx * 512];
  gbar[idx] = s * (1.0f / 1024.0f);
}

// ------- c0[b][c] = out_b[c] + sum_d out_w_f32[c][d]*gbar[b][d] ----------
__global__ __launch_bounds__(256) void c0_kernel(const float* __restrict__ out_w,
                                                 const float* __restrict__ out_b,
                                                 const float* __restrict__ gbar,
                                                 float* __restrict__ c0) {
  const int idx = blockIdx.x * 4 + (threadIdx.x >> 6);   // 0..8191 = b*1024+c
  const int lane = threadIdx.x & 63;
  const int b = idx >> 10, c = idx & 1023;
  const int d0 = lane * 8;
  float4 w0 = *(const float4*)(out_w + (long)c * DI + d0);
  float4 w1 = *(const float4*)(out_w + (long)c * DI + d0 + 4);
  float4 g0 = *(const float4*)(gbar + (long)b * DI + d0);
  float4 g1 = *(const float4*)(gbar + (long)b * DI + d0 + 4);
  float s = w0.x * g0.x + w0.y * g0.y + w0.z * g0.z + w0.w * g0.w
          + w1.x * g1.x + w1.y * g1.y + w1.z * g1.z + w1.w * g1.w;
  #pragma unroll
  for (int off = 32; off > 0; off >>= 1) s += __shfl_xor(s, off);
  if (lane == 0) c0[idx] = out_b[c] + s;
}

// ------ BN stats from y-GEMM (256-tile) partials + c0 --------------------
// partial blk = (b*4 + by)*16 + bx ; [0..255]=sum, [256..511]=sq
__global__ __launch_bounds__(256) void stats2_kernel(const float* __restrict__ partial,
                                                     const float* __restrict__ c0,
                                                     float* __restrict__ stats) {
  const int co = blockIdx.x * 256 + threadIdx.x;  // 0..1023
  const int by = co >> 8, r = co & 255;
  float sd = 0.f, sd2 = 0.f, sbc = 0.f;
  for (int b = 0; b < 8; b++) {
    float sb = 0.f, qb = 0.f;
    #pragma unroll
    for (int bx = 0; bx < 16; bx++) {
      const long blk = (((long)b * 4 + by) * 16 + bx) * 512;
      sb += partial[blk + r];
      qb += partial[blk + 256 + r];
    }
    sd += sb; sd2 += qb;
    sbc += c0[b * 1024 + co] * sb;
  }
  float sc0 = 0.f, sc02 = 0.f;
  #pragma unroll
  for (int b = 0; b < 8; b++) {
    float c = c0[b * 1024 + co];
    sc0 += c; sc02 += c * c;
  }
  stats[co] = 4096.0f * sc0 + sd;
  stats[1024 + co] = 4096.0f * sc02 + 2.0f * sbc + sd2;
}

// ---------------- BN apply + residual (bf16 dy + c0) ----------------
__global__ __launch_bounds__(256) void final_kernel(const u16* __restrict__ dy,
    const float* __restrict__ x, const float* __restrict__ stats,
    const float* __restrict__ c0,
    const float* __restrict__ bnw, const float* __restrict__ bnb,
    float* __restrict__ out) {
  const int bc = blockIdx.x;
  const int co = bc & 1023;
  const float mean = stats[co] * (1.0f / 32768.0f);
  const float var = stats[1024 + co] * (1.0f / 32768.0f) - mean * mean;
  const float inv = rsqrtf(var + 1e-5f) * bnw[co];
  const float addc = bnb[co] - mean * inv + c0[bc] * inv;
  const long base = (long)bc * 4096;
  const int t = threadIdx.x;
  #pragma unroll
  for (int i = 0; i < 2; i++) {
    const long off = base + (long)(i * 256 + t) * 8;
    uint4 v = *(const uint4*)(dy + off);
    float f[8]; unpack8(v, f);
    const float4 x0 = *(const float4*)(x + off);
    const float4 x1 = *(const float4*)(x + off + 4);
    float4 o0, o1;
    o0.x = f[0] * inv + addc + x0.x;
    o0.y = f[1] * inv + addc + x0.y;
    o0.z = f[2] * inv + addc + x0.z;
    o0.w = f[3] * inv + addc + x0.w;
    o1.x = f[4] * inv + addc + x1.x;
    o1.y = f[5] * inv + addc + x1.y;
    o1.z = f[6] * inv + addc + x1.z;
    o1.w = f[7] * inv + addc + x1.w;
    *(float4*)(out + off) = o0;
    *(float4*)(out + off + 4) = o1;
  }
}

extern "C" void kernel_launch(void* const* d_in, const int* in_sizes, int n_in,
                              void* d_out, int out_size, void* d_ws, size_t ws_size,
                              hipStream_t stream) {
  (void)in_sizes; (void)n_in; (void)out_size; (void)ws_size;
  const float* x       = (const float*)d_in[0];
  const float* theta_w = (const float*)d_in[1];
  const float* theta_b = (const float*)d_in[2];
  const float* phi_w   = (const float*)d_in[3];
  const float* phi_b   = (const float*)d_in[4];
  const float* g_w     = (const float*)d_in[5];
  const float* g_b     = (const float*)d_in[6];
  const float* out_w   = (const float*)d_in[7];
  const float* out_b   = (const float*)d_in[8];
  const float* bn_w    = (const float*)d_in[9];
  const float* bn_b    = (const float*)d_in[10];
  float* out = (float*)d_out;
  char* ws = (char*)d_ws;
  const size_t MB = 1024 * 1024;

  // workspace layout
  u16* xT     = (u16*)(ws + 0 * MB);       // 64MB; later: dy bf16 [0,64MB)
  u16* poolT  = (u16*)(ws + 64 * MB);      // 16MB
  u16* w_th   = (u16*)(ws + 80 * MB);      // 1MB
  u16* w_ph   = (u16*)(ws + 81 * MB);      // 1MB  (w_ph || w_g contiguous)
  u16* w_g    = (u16*)(ws + 82 * MB);      // 1MB
  u16* thetaT = (u16*)(ws + 84 * MB);      // 32MB
  u16* phiT   = (u16*)(ws + 116 * MB);     // 8MB
  u16* g_n    = (u16*)(ws + 124 * MB);     // 8MB
  u16* e      = (u16*)(ws + 132 * MB);     // 64MB (exp(scores))
  u16* tT     = (u16*)(ws + 196 * MB);     // 32MB (delta-t bf16)
  u16* w_out  = (u16*)(ws + 228 * MB);     // 1MB
  float* gbar  = (float*)(ws + 229 * MB);            // 16KB
  float* c0b   = (float*)(ws + 229 * MB + 16384);    // 32KB
  float* stats = (float*)(ws + 229 * MB + 49152);    // 8KB
  float* partial = (float*)(ws + 230 * MB);          // 512KB (8*4*4096 f32)
  float* partial2 = (float*)(ws + 231 * MB);         // 1MB (512 blk * 512 f32)
  float* g_ps = (float*)(ws + 233 * MB);             // 128KB (8*8*512 f32)
  u16* dy = xT;               // alias: x_T dead after theta GEMM

  // 1. weights -> bf16 (single launch)
  cvt4_kernel<<<2048, 256, 0, stream>>>(theta_w, phi_w, g_w, out_w,
                                        w_th, w_ph, w_g, w_out);
  // 2. x -> x_T bf16 with fused 2x2 maxpool
  transpose_pool_kernel<<<dim3(32, 16, 8), 256, 0, stream>>>(x, xT, poolT);
  // 4. theta -> theta_T [b][4096][512]  (256-tile 8-phase GEMM)
  gemm256<1, true, false, false, false, false>
      <<<dim3(16, 2, 8), 512, 0, stream>>>(
      w_th, xT, thetaT, theta_b, 0L, nullptr, 0L, nullptr, 0L, nullptr,
      1.0f, 512, 4096, 1024, 0L, (long)NPIX * CIN, (long)NPIX * DI);
  // 5+6. merged phi+g GEMM (128-tile kernel)
  gemm_tn<3, true, false, false, false, false, false>
      <<<dim3(8, 8, 8), 256, 0, stream>>>(
      w_ph, poolT, phiT, g_n, phi_b, g_b, 0L, nullptr, 0L, nullptr, 0L,
      g_ps, 1.0f, 1024, 1024, 1024, 0L, (long)MPIX * CIN, (long)MPIX * DI);
  // 6b. gbar from partials ; c0
  gbar_kernel<<<16, 256, 0, stream>>>(g_ps, gbar);
  c0_kernel<<<2048, 256, 0, stream>>>(out_w, out_b, gbar, c0b);
  // 7. e[n][m] = exp(scores) + per-block rowsum partials (gridX=4)
  gemm256<0, false, false, true, false, false>
      <<<dim3(4, 16, 8), 512, 0, stream>>>(
      thetaT, phiT, e, nullptr, 0L, nullptr, 0L, nullptr, 0L, partial,
      0.044194173824159216f, 4096, 1024, 512,
      (long)NPIX * DI, (long)MPIX * DI, (long)NPIX * MPIX);
  // 8+9. delta-t = (g_n * e^T)*inv[n] - gbar[d]; inv from partials (CSP)
  gemm256<1, false, true, false, false, true>
      <<<dim3(16, 2, 8), 512, 0, stream>>>(
      g_n, e, tT, nullptr, 0L, partial, 16384L, gbar, 512L, nullptr,
      1.0f, 512, 4096, 1024,
      (long)DI * MPIX, (long)NPIX * MPIX, (long)NPIX * DI);
  // 10. dy = out_w * delta-t^T + BN partials (PSUM2)
  gemm256<0, false, false, false, true, false>
      <<<dim3(16, 4, 8), 512, 0, stream>>>(
      w_out, tT, dy, nullptr, 0L, nullptr, 0L, nullptr, 0L, partial2,
      1.0f, 1024, 4096, 512, 0L, (long)NPIX * DI, (long)1024 * NPIX);
  // 11. BN stats from partials + c0 (deterministic)
  stats2_kernel<<<4, 256, 0, stream>>>(partial2, c0b, stats);
  // 12. BN apply + residual
  final_kernel<<<8192, 256, 0, stream>>>(dy, x, stats, c0b, bn_w, bn_b, out);
}

// Round 12
// 337.801 us; speedup vs baseline: 1.0205x; 1.0205x over previous
//
#include <hip/hip_runtime.h>
#include <cstdint>

typedef unsigned short u16;
typedef __attribute__((ext_vector_type(4))) unsigned short u16x4;
typedef __attribute__((ext_vector_type(8))) short short8;
typedef __attribute__((ext_vector_type(4))) float f32x4;

#define DI 512
#define CIN 1024
#define NPIX 4096   // 64*64
#define MPIX 1024   // 32*32

__device__ __forceinline__ float bf2f(u16 u) {
  union { unsigned int i; float f; } v; v.i = ((unsigned int)u) << 16; return v.f;
}
__device__ __forceinline__ u16 f2bf(float f) {
  union { float f; unsigned int i; } v; v.f = f;
  unsigned int r = v.i + 0x7fffu + ((v.i >> 16) & 1u);
  return (u16)(r >> 16);
}
__device__ __forceinline__ void unpack8(uint4 v, float* f) {
  union { unsigned int i; float f; } u;
  u.i = v.x << 16;          f[0] = u.f;
  u.i = v.x & 0xffff0000u;  f[1] = u.f;
  u.i = v.y << 16;          f[2] = u.f;
  u.i = v.y & 0xffff0000u;  f[3] = u.f;
  u.i = v.z << 16;          f[4] = u.f;
  u.i = v.z & 0xffff0000u;  f[5] = u.f;
  u.i = v.w << 16;          f[6] = u.f;
  u.i = v.w & 0xffff0000u;  f[7] = u.f;
}

// async global->LDS, 16B per lane, wave-uniform LDS base + lane*16
__device__ __forceinline__ void gload16(const u16* g, u16* l) {
  __builtin_amdgcn_global_load_lds(
      (const __attribute__((address_space(1))) void*)g,
      (__attribute__((address_space(3))) void*)l, 16, 0, 0);
}

template<int N> __device__ __forceinline__ void wait_vmcnt() {
  asm volatile("s_waitcnt vmcnt(%0)" :: "n"(N) : "memory");
}
__device__ __forceinline__ void phase_begin() {
  __builtin_amdgcn_s_barrier();
  __builtin_amdgcn_sched_barrier(0);
  asm volatile("" ::: "memory");
}
__device__ __forceinline__ void phase_end() {
  asm volatile("s_waitcnt lgkmcnt(0)" ::: "memory");
  __builtin_amdgcn_sched_barrier(0);
  __builtin_amdgcn_s_barrier();
  __builtin_amdgcn_sched_barrier(0);
}

// ---------------- f32 -> bf16 convert (4 weight tensors in one launch) ----
__global__ __launch_bounds__(256) void cvt4_kernel(
    const float* __restrict__ s0, const float* __restrict__ s1,
    const float* __restrict__ s2, const float* __restrict__ s3,
    u16* __restrict__ d0, u16* __restrict__ d1,
    u16* __restrict__ d2, u16* __restrict__ d3) {
  int i = blockIdx.x * 256 + threadIdx.x;     // 0 .. 4*131072
  int sel = i >> 17;
  int j = i & 131071;
  const float* src = sel == 0 ? s0 : sel == 1 ? s1 : sel == 2 ? s2 : s3;
  u16* dst = sel == 0 ? d0 : sel == 1 ? d1 : sel == 2 ? d2 : d3;
  float4 v = *(const float4*)(src + (long)j * 4);
  u16x4 w;
  w[0] = f2bf(v.x); w[1] = f2bf(v.y); w[2] = f2bf(v.z); w[3] = f2bf(v.w);
  *(u16x4*)(dst + (long)j * 4) = w;
}

// ------- x [b][c][n] f32 -> x_T [b][n][c] bf16 + fused 2x2 maxpool -------
__global__ __launch_bounds__(256) void transpose_pool_kernel(
    const float* __restrict__ x, u16* __restrict__ xT, u16* __restrict__ poolT) {
  __shared__ u16 tile[64][136];
  const int b = blockIdx.z;
  const int n0 = blockIdx.x * 128, c0 = blockIdx.y * 64;
  const float* xb = x + (long)b * CIN * NPIX;
  u16* xTb = xT + (long)b * NPIX * CIN;
  const int t = threadIdx.x;
  const int tc = t >> 5, tn = (t & 31) * 4;
  #pragma unroll
  for (int i = 0; i < 8; i++) {
    int c = tc + i * 8;
    float4 v = *(const float4*)(xb + (long)(c0 + c) * NPIX + n0 + tn);
    u16x4 w;
    w[0] = f2bf(v.x); w[1] = f2bf(v.y); w[2] = f2bf(v.z); w[3] = f2bf(v.w);
    *(u16x4*)&tile[c][tn] = w;
  }
  __syncthreads();
  const int tn2 = t >> 4, tc2 = (t & 15) * 4;
  #pragma unroll
  for (int i = 0; i < 8; i++) {
    int n = tn2 + i * 16;
    u16x4 w;
    w[0] = tile[tc2 + 0][n];
    w[1] = tile[tc2 + 1][n];
    w[2] = tile[tc2 + 2][n];
    w[3] = tile[tc2 + 3][n];
    *(u16x4*)(xTb + (long)(n0 + n) * CIN + c0 + tc2) = w;
  }
  const int j = t & 31, g = t >> 5;
  u16 r[8] __attribute__((aligned(16)));
  #pragma unroll
  for (int k = 0; k < 8; k++) {
    const int c = g * 8 + k;
    const unsigned d0 = *(const unsigned*)&tile[c][2 * j];
    const unsigned d1 = *(const unsigned*)&tile[c][64 + 2 * j];
    float m0 = fmaxf(bf2f((u16)(d0 & 0xffffu)), bf2f((u16)(d0 >> 16)));
    float m1 = fmaxf(bf2f((u16)(d1 & 0xffffu)), bf2f((u16)(d1 >> 16)));
    r[k] = f2bf(fmaxf(m0, m1));
  }
  *(uint4*)(poolT + ((long)b * MPIX + blockIdx.x * 32 + j) * CIN + c0 + g * 8) =
      *(uint4*)r;
}

// =============== 256x256-tile GEMM, 8 waves, 8-phase counted-vmcnt =======
// (structure as R11; epilogue: OM0 LDS-staging XOR-swizzled, __expf)
template<int OM, bool HAS_BIAS, bool HAS_SHIFT, bool HAS_EXP, bool HAS_PSUM2,
         bool HAS_CSP>
__global__ __launch_bounds__(512, 2)
void gemm256(const u16* __restrict__ A, const u16* __restrict__ B,
             void* __restrict__ Cv,
             const float* __restrict__ bias, long sBias,
             const float* __restrict__ cs, long sCS,
             const float* __restrict__ shift, long sShift,
             float* __restrict__ psum_out,
             float scale, int M, int N, int K, long sA, long sB, long sC)
{
  A += blockIdx.z * sA;
  B += blockIdx.z * sB;
  if (HAS_BIAS) bias += blockIdx.z * sBias;
  if (HAS_CSP) cs += blockIdx.z * sCS;
  if (HAS_SHIFT) shift += blockIdx.z * sShift;
  const int bm = blockIdx.y * 256, bn = blockIdx.x * 256;
  __shared__ __align__(16) u16 smem[65536];   // 2 slots x 64KB
  __shared__ float psum[4][256];
  __shared__ float psumq[4][256];
  __shared__ float invs[256];
  const int tid = threadIdx.x;
  const int lane = tid & 63, wave = tid >> 6;
  const int wr = wave >> 2, wc = wave & 3;       // 2M x 4N waves
  const int lr = lane & 15, q = lane >> 4;
  f32x4 acc[8][4] = {};

  if (HAS_CSP) {
    if (tid < 256) {
      float ssum = 0.f;
      #pragma unroll
      for (int xx = 0; xx < 4; xx++) ssum += cs[xx * 4096 + bn + tid];
      invs[tid] = 1.0f / ssum;
    }
    wait_vmcnt<0>();
    __builtin_amdgcn_sched_barrier(0);
  }

  const int srow = 32 * wave + (lane >> 2);
  const int sk = (((lane & 3) ^ ((lane >> 3) & 3))) * 8;
  const u16* Abase = A + ((long)bm + srow) * K + sk;
  const u16* Bbase = B + ((long)bn + srow) * K + sk;
  const int rswz = (q ^ ((lr >> 1) & 3)) * 8;
  const int aoff = (wr * 128 + lr) * 32 + rswz;
  const int boff = 16384 + (wc * 64 + lr) * 32 + rswz;

#define SA(T_, KK_) { const u16* g_ = Abase + (long)(T_) * 64 + (KK_) * 32; \
    u16* d_ = &smem[(((T_) & 1)) * 32768 + (KK_) * 8192 + wave * 1024]; \
    gload16(g_, d_); gload16(g_ + 16 * (long)K, d_ + 512); }
#define SB(T_, KK_) { const u16* g_ = Bbase + (long)(T_) * 64 + (KK_) * 32; \
    u16* d_ = &smem[(((T_) & 1)) * 32768 + 16384 + (KK_) * 8192 + wave * 1024]; \
    gload16(g_, d_); gload16(g_ + 16 * (long)K, d_ + 512); }
#define CQ(SLOT, KK, RI0, LOADBV) { \
    const int qb_ = (SLOT) * 32768 + (KK) * 8192; \
    if (LOADBV) { \
      _Pragma("unroll") \
      for (int ci_ = 0; ci_ < 4; ci_++) \
        bv[ci_] = *(const short8*)&smem[qb_ + boff + ci_ * 512]; \
    } \
    short8 av_[4]; \
    _Pragma("unroll") \
    for (int r_ = 0; r_ < 4; r_++) \
      av_[r_] = *(const short8*)&smem[qb_ + aoff + ((RI0) + r_) * 512]; \
    __builtin_amdgcn_s_setprio(1); \
    _Pragma("unroll") \
    for (int r_ = 0; r_ < 4; r_++) \
      _Pragma("unroll") \
      for (int ci_ = 0; ci_ < 4; ci_++) \
        acc[(RI0) + r_][ci_] = __builtin_amdgcn_mfma_f32_16x16x32_bf16( \
            av_[r_], bv[ci_], acc[(RI0) + r_][ci_], 0, 0, 0); \
    __builtin_amdgcn_s_setprio(0); }
#define PH(VM, STG, SLOT, KK, RI0, LOADBV) \
    STG; wait_vmcnt<VM>(); phase_begin(); CQ(SLOT, KK, RI0, LOADBV); phase_end();

  const int niter2 = K >> 7;
  short8 bv[4];

  SA(0, 0); SB(0, 0); SA(0, 1); SB(0, 1); SA(1, 0); SB(1, 0);

  for (int u = 0; u < niter2 - 1; ++u) {
    const int t1 = 2 * u + 1, t2 = 2 * u + 2, t3 = 2 * u + 3;
    PH(10, SA(t1, 1), 0, 0, 0, 1)
    PH(10, SB(t1, 1), 0, 0, 4, 0)
    PH(10, SA(t2, 0), 0, 1, 0, 1)
    PH(10, SB(t2, 0), 0, 1, 4, 0)
    PH(10, SA(t2, 1), 1, 0, 0, 1)
    PH(10, SB(t2, 1), 1, 0, 4, 0)
    PH(10, SA(t3, 0), 1, 1, 0, 1)
    PH(10, SB(t3, 0), 1, 1, 4, 0)
  }
  {
    const int t1 = 2 * (niter2 - 1) + 1;
    PH(10, SA(t1, 1), 0, 0, 0, 1)
    PH(10, SB(t1, 1), 0, 0, 4, 0)
    PH(8,  ((void)0), 0, 1, 0, 1)
    PH(6,  ((void)0), 0, 1, 4, 0)
    PH(4,  ((void)0), 1, 0, 0, 1)
    PH(2,  ((void)0), 1, 0, 4, 0)
    PH(0,  ((void)0), 1, 1, 0, 1)
    PH(0,  ((void)0), 1, 1, 4, 0)
  }
#undef SA
#undef SB
#undef CQ
#undef PH

  __syncthreads();

  const int dr = (lane >> 4) * 4;
  float invc[4];
  if (HAS_CSP) {
    #pragma unroll
    for (int ci = 0; ci < 4; ci++) invc[ci] = invs[wc * 64 + ci * 16 + lr];
  }
  float rowsum[8][4], rowsq[8][4];
  if (HAS_EXP || HAS_PSUM2) {
    #pragma unroll
    for (int ri = 0; ri < 8; ri++)
      #pragma unroll
      for (int r = 0; r < 4; r++) { rowsum[ri][r] = 0.f; rowsq[ri][r] = 0.f; }
  }
  #pragma unroll
  for (int ri = 0; ri < 8; ri++) {
    const int rowl = wr * 128 + ri * 16 + dr;
    const int rowb = bm + rowl;
    float bvs[4] = {0.f, 0.f, 0.f, 0.f};
    float shv[4] = {0.f, 0.f, 0.f, 0.f};
    if (HAS_BIAS) {
      #pragma unroll
      for (int r = 0; r < 4; r++) bvs[r] = bias[rowb + r];
    }
    if (HAS_SHIFT) {
      #pragma unroll
      for (int r = 0; r < 4; r++) shv[r] = shift[rowb + r];
    }
    #pragma unroll
    for (int ci = 0; ci < 4; ci++) {
      const int coll = wc * 64 + ci * 16 + lr;
      float v[4];
      #pragma unroll
      for (int r = 0; r < 4; r++) {
        float tv = acc[ri][ci][r] * scale;
        if (HAS_CSP) tv *= invc[ci];
        if (HAS_SHIFT) tv -= shv[r];
        if (HAS_BIAS) tv += bvs[r];
        if (HAS_EXP) tv = __expf(tv);
        if (HAS_EXP || HAS_PSUM2) rowsum[ri][r] += tv;
        if (HAS_PSUM2) rowsq[ri][r] += tv * tv;
        v[r] = tv;
      }
      if (OM == 1) {
        u16x4 w;
        #pragma unroll
        for (int r = 0; r < 4; r++) w[r] = f2bf(v[r]);
        unsigned bo = (unsigned)((coll * 256 + rowl) * 2) ^ ((coll & 7) << 4);
        *(u16x4*)((char*)smem + bo) = w;
      } else {
        // [row][col] with col XOR'd by row-quad (banks 8->32, 2-way free)
        #pragma unroll
        for (int r = 0; r < 4; r++) {
          const int row = rowl + r;
          smem[row * 256 + (coll ^ (((row >> 2) & 3) << 4))] = f2bf(v[r]);
        }
      }
    }
  }
  if (HAS_EXP || HAS_PSUM2) {
    #pragma unroll
    for (int msk = 1; msk < 16; msk <<= 1)
      #pragma unroll
      for (int ri = 0; ri < 8; ri++)
        #pragma unroll
        for (int r = 0; r < 4; r++) {
          rowsum[ri][r] += __shfl_xor(rowsum[ri][r], msk);
          if (HAS_PSUM2) rowsq[ri][r] += __shfl_xor(rowsq[ri][r], msk);
        }
    if ((lane & 15) == 0) {
      #pragma unroll
      for (int ri = 0; ri < 8; ri++)
        #pragma unroll
        for (int r = 0; r < 4; r++) {
          psum[wc][wr * 128 + ri * 16 + dr + r] = rowsum[ri][r];
          if (HAS_PSUM2) psumq[wc][wr * 128 + ri * 16 + dr + r] = rowsq[ri][r];
        }
    }
  }
  __syncthreads();
  u16* C = (u16*)Cv + blockIdx.z * sC;
  if (OM == 1) {
    #pragma unroll
    for (int i = 0; i < 16; i++) {
      const int chunk = i * 512 + tid;
      const int coll = chunk >> 5, rq = chunk & 31;
      unsigned bo = (unsigned)(coll * 512 + rq * 16) ^ ((coll & 7) << 4);
      uint4 w = *(const uint4*)((const char*)smem + bo);
      *(uint4*)(C + (long)(bn + coll) * M + bm + rq * 8) = w;
    }
  } else {
    #pragma unroll
    for (int i = 0; i < 16; i++) {
      const int chunk = i * 512 + tid;
      const int row = chunk >> 5, cq = chunk & 31;
      const int cbase = (cq * 8) ^ (((row >> 2) & 3) << 4);
      uint4 w = *(const uint4*)(smem + row * 256 + cbase);
      *(uint4*)(C + (long)(bm + row) * N + bn + cq * 8) = w;
    }
  }
  if ((HAS_EXP || HAS_PSUM2) && tid < 256) {
    if (HAS_EXP)
      psum_out[((long)blockIdx.z * gridDim.x + blockIdx.x) * 4096 + bm + tid] =
          psum[0][tid] + psum[1][tid] + psum[2][tid] + psum[3][tid];
    if (HAS_PSUM2) {
      const long blk = ((long)blockIdx.z * gridDim.y + blockIdx.y) * gridDim.x
                       + blockIdx.x;
      psum_out[blk * 512 + tid] =
          psum[0][tid] + psum[1][tid] + psum[2][tid] + psum[3][tid];
      psum_out[blk * 512 + 256 + tid] =
          psumq[0][tid] + psumq[1][tid] + psumq[2][tid] + psumq[3][tid];
    }
  }
}

// ---------------- old 128x128 GEMM (kept for merged phi+g) ----------------
template<int OM, bool HAS_BIAS, bool HAS_CS, bool HAS_SHIFT, bool HAS_EXP,
         bool HAS_PSUM2, bool HAS_CSP>
__global__ __launch_bounds__(256)
void gemm_tn(const u16* __restrict__ A, const u16* __restrict__ B,
             void* __restrict__ Cv, void* __restrict__ Cv2,
             const float* __restrict__ bias, const float* __restrict__ bias2,
             long sBias,
             const float* __restrict__ cs, long sCS,
             const float* __restrict__ shift, long sShift,
             float* __restrict__ psum_out,
             float scale, int M, int N, int K, long sA, long sB, long sC)
{
  A += blockIdx.z * sA;
  B += blockIdx.z * sB;
  if (HAS_BIAS) bias += blockIdx.z * sBias;
  if (HAS_CS || HAS_CSP) cs += blockIdx.z * sCS;
  if (HAS_SHIFT) shift += blockIdx.z * sShift;
  const int bm = blockIdx.y * 128;
  const int bn = blockIdx.x * 128;
  __shared__ __align__(16) u16 smem[128 * 128];
  u16* As = smem;
  u16* Bs = smem + 128 * 64;
  __shared__ float psum[4][128];
  const int tid = threadIdx.x;
  const int lane = tid & 63;
  const int wave = tid >> 6;
  const int wm = (wave >> 1) * 64;
  const int wn = (wave & 1) * 64;
  const int lr = lane & 15;
  const int q  = lane >> 4;
  const int sxor = lane & 7;
  const bool gps = (OM == 3) && (bm >= 512);
  f32x4 acc[4][4] = {};

  if (HAS_CSP) {
    if (tid < 128) {
      float s = 0.f;
      #pragma unroll
      for (int xx = 0; xx < 8; xx++) s += cs[xx * 4096 + bn + tid];
      psum[0][tid] = 1.0f / s;
    }
  }

  const int swz = ((lane & 7) ^ (lane >> 3)) * 8;
  const long grow = 32 * wave + (lane >> 3);
  const u16* Ag = A + ((long)bm + grow) * K + swz;
  const u16* Bg = B + ((long)bn + grow) * K + swz;

  for (int kt = 0; kt < K; kt += 64) {
    __syncthreads();
    #pragma unroll
    for (int i = 0; i < 4; i++) {
      gload16(Ag + (long)(8 * i) * K + kt, &As[(wave * 4 + i) * 512]);
      gload16(Bg + (long)(8 * i) * K + kt, &Bs[(wave * 4 + i) * 512]);
    }
    __syncthreads();
    #pragma unroll
    for (int kk = 0; kk < 2; kk++) {
      short8 av[4], bv[4];
      #pragma unroll
      for (int mi = 0; mi < 4; mi++)
        av[mi] = *(const short8*)&As[(wm + mi * 16 + lr) * 64 +
                                     (((kk << 2) + q) ^ sxor) * 8];
      #pragma unroll
      for (int ni = 0; ni < 4; ni++)
        bv[ni] = *(const short8*)&Bs[(wn + ni * 16 + lr) * 64 +
                                     (((kk << 2) + q) ^ sxor) * 8];
      #pragma unroll
      for (int mi = 0; mi < 4; mi++) {
        #pragma unroll
        for (int ni = 0; ni < 4; ni++)
          acc[mi][ni] = __builtin_amdgcn_mfma_f32_16x16x32_bf16(
              av[mi], bv[ni], acc[mi][ni], 0, 0, 0);
      }
    }
  }

  float invc[4];
  if (HAS_CSP) {
    #pragma unroll
    for (int ni = 0; ni < 4; ni++) invc[ni] = psum[0][wn + ni * 16 + lr];
  }
  __syncthreads();
  const int dr = (lane >> 4) * 4;
  const bool trans_out = (OM == 1) || (OM == 3 && !gps);
  float rowsum[4][4];
  float rowsq[4][4];
  if (HAS_EXP || HAS_PSUM2 || gps) {
    #pragma unroll
    for (int mi = 0; mi < 4; mi++)
      #pragma unroll
      for (int r = 0; r < 4; r++) { rowsum[mi][r] = 0.f; rowsq[mi][r] = 0.f; }
  }
  const float* bp = (OM == 3 && gps) ? bias2 - 512 : bias;
  #pragma unroll
  for (int mi = 0; mi < 4; mi++) {
    const int rowl = wm + mi * 16 + dr;
    const int rowb = bm + rowl;
    float bvs[4] = {0.f, 0.f, 0.f, 0.f};
    float shv[4] = {0.f, 0.f, 0.f, 0.f};
    if (HAS_BIAS) {
      #pragma unroll
      for (int r = 0; r < 4; r++) bvs[r] = bp[rowb + r];
    }
    if (HAS_SHIFT) {
      #pragma unroll
      for (int r = 0; r < 4; r++) shv[r] = shift[rowb + r];
    }
    #pragma unroll
    for (int ni = 0; ni < 4; ni++) {
      const int coll = wn + ni * 16 + lr;
      const float csv = HAS_CSP ? invc[ni] : (HAS_CS ? cs[bn + coll] : 1.0f);
      float v[4];
      #pragma unroll
      for (int r = 0; r < 4; r++) {
        float t = acc[mi][ni][r] * scale;
        if (HAS_CS || HAS_CSP) t *= csv;
        if (HAS_SHIFT) t -= shv[r];
        if (HAS_BIAS) t += bvs[r];
        if (HAS_EXP) t = __expf(t);
        if (HAS_EXP || HAS_PSUM2 || gps) rowsum[mi][r] += t;
        if (HAS_PSUM2) rowsq[mi][r] += t * t;
        v[r] = t;
      }
      if (trans_out) {
        u16x4 w;
        #pragma unroll
        for (int r = 0; r < 4; r++) w[r] = f2bf(v[r]);
        unsigned bo = (unsigned)((coll * 128 + rowl) * 2) ^ ((coll & 7) << 4);
        *(u16x4*)((char*)smem + bo) = w;
      } else {
        #pragma unroll
        for (int r = 0; r < 4; r++) {
          const int row = rowl + r;
          smem[row * 128 + (coll ^ (((row >> 2) & 3) << 4))] = f2bf(v[r]);
        }
      }
    }
  }
  if (HAS_EXP || HAS_PSUM2 || gps) {
    #pragma unroll
    for (int msk = 1; msk < 16; msk <<= 1)
      #pragma unroll
      for (int mi = 0; mi < 4; mi++)
        #pragma unroll
        for (int r = 0; r < 4; r++) {
          rowsum[mi][r] += __shfl_xor(rowsum[mi][r], msk);
          if (HAS_PSUM2) rowsq[mi][r] += __shfl_xor(rowsq[mi][r], msk);
        }
    if ((lane & 15) == 0) {
      #pragma unroll
      for (int mi = 0; mi < 4; mi++)
        #pragma unroll
        for (int r = 0; r < 4; r++) {
          psum[wave & 1][wm + mi * 16 + dr + r] = rowsum[mi][r];
          if (HAS_PSUM2) psum[2 + (wave & 1)][wm + mi * 16 + dr + r] = rowsq[mi][r];
        }
    }
  }
  __syncthreads();
  if (trans_out) {
    const int Ms = (OM == 3) ? 512 : M;
    u16* C = (u16*)Cv + blockIdx.z * sC;
    #pragma unroll
    for (int i = 0; i < 8; i++) {
      const int chunk = i * 256 + tid;
      const int coll = chunk >> 4, rq = chunk & 15;
      unsigned bo = (unsigned)(coll * 256 + rq * 16) ^ ((coll & 7) << 4);
      uint4 w = *(const uint4*)((const char*)smem + bo);
      *(uint4*)(C + (long)(bn + coll) * Ms + bm + rq * 8) = w;
    }
  } else {
    u16* C = (OM == 3) ? (u16*)Cv2 + blockIdx.z * sC : (u16*)Cv + blockIdx.z * sC;
    const int rbase = (OM == 3) ? bm - 512 : bm;
    #pragma unroll
    for (int i = 0; i < 8; i++) {
      const int chunk = i * 256 + tid;
      const int row = chunk >> 4, cq = chunk & 15;
      const int cbase = (cq * 8) ^ (((row >> 2) & 3) << 4);
      uint4 w = *(const uint4*)(smem + row * 128 + cbase);
      *(uint4*)(C + (long)(rbase + row) * N + bn + cq * 8) = w;
    }
  }
  if (HAS_EXP || HAS_PSUM2 || gps) {
    if (tid < 128) {
      if (HAS_EXP)
        psum_out[((long)blockIdx.z * gridDim.x + blockIdx.x) * 4096 + bm + tid] =
            psum[0][tid] + psum[1][tid];
      if (HAS_PSUM2) {
        const long blk = ((long)blockIdx.z * gridDim.y + blockIdx.y) * gridDim.x
                         + blockIdx.x;
        psum_out[blk * 256 + tid] = psum[0][tid] + psum[1][tid];
        psum_out[blk * 256 + 128 + tid] = psum[2][tid] + psum[3][tid];
      }
      if (gps)
        psum_out[((long)blockIdx.z * gridDim.x + blockIdx.x) * 512 +
                 (bm - 512) + tid] = psum[0][tid] + psum[1][tid];
    }
  }
}

// ------- gbar[b][d] = (1/1024) * sum_x g_ps[b][x][d] --------------------
__global__ __launch_bounds__(256) void gbar_kernel(const float* __restrict__ g_ps,
                                                   float* __restrict__ gbar) {
  const int idx = blockIdx.x * 256 + threadIdx.x;   // 0..4095 = b*512+d
  const int b = idx >> 9, d = idx & 511;
  const float* p = g_ps + (long)b * 8 * 512 + d;
  float s = 0.f;
  #pragma unroll
  for (int xx = 0; xx < 8; xx++) s += p[(long)xx * 512];
  gbar[idx] = s * (1.0f / 1024.0f);
}

// ------- c0[b][c] = out_b[c] + sum_d out_w_f32[c][d]*gbar[b][d] ----------
__global__ __launch_bounds__(256) void c0_kernel(const float* __restrict__ out_w,
                                                 const float* __restrict__ out_b,
                                                 const float* __restrict__ gbar,
                                                 float* __restrict__ c0) {
  const int idx = blockIdx.x * 4 + (threadIdx.x >> 6);   // 0..8191 = b*1024+c
  const int lane = threadIdx.x & 63;
  const int b = idx >> 10, c = idx & 1023;
  const int d0 = lane * 8;
  float4 w0 = *(const float4*)(out_w + (long)c * DI + d0);
  float4 w1 = *(const float4*)(out_w + (long)c * DI + d0 + 4);
  float4 g0 = *(const float4*)(gbar + (long)b * DI + d0);
  float4 g1 = *(const float4*)(gbar + (long)b * DI + d0 + 4);
  float s = w0.x * g0.x + w0.y * g0.y + w0.z * g0.z + w0.w * g0.w
          + w1.x * g1.x + w1.y * g1.y + w1.z * g1.z + w1.w * g1.w;
  #pragma unroll
  for (int off = 32; off > 0; off >>= 1) s += __shfl_xor(s, off);
  if (lane == 0) c0[idx] = out_b[c] + s;
}

// ------ BN stats (from y-GEMM partials) + apply + residual, fused --------
// partial blk = (b*4 + by)*16 + bx ; [0..255]=sum, [256..511]=sq
__global__ __launch_bounds__(256) void final_kernel(const u16* __restrict__ dy,
    const float* __restrict__ x, const float* __restrict__ partial,
    const float* __restrict__ c0,
    const float* __restrict__ bnw, const float* __restrict__ bnb,
    float* __restrict__ out) {
  __shared__ float red[6];
  __shared__ float bcast[2];
  const int bc = blockIdx.x;
  const int co = bc & 1023;
  const int t = threadIdx.x;
  if (t < 128) {
    const int b2 = t >> 4, bx = t & 15;
    const int by = co >> 8, r = co & 255;
    const long blk = (((long)b2 * 4 + by) * 16 + bx) * 512;
    float s = partial[blk + r];
    float qq = partial[blk + 256 + r];
    #pragma unroll
    for (int off = 1; off < 16; off <<= 1) {
      s += __shfl_xor(s, off);
      qq += __shfl_xor(qq, off);
    }
    float sbc = c0[b2 * 1024 + co] * s;
    #pragma unroll
    for (int off = 16; off < 64; off <<= 1) {
      s += __shfl_xor(s, off);
      qq += __shfl_xor(qq, off);
      sbc += __shfl_xor(sbc, off);
    }
    if (t == 0)  { red[0] = s; red[1] = qq; red[2] = sbc; }
    if (t == 64) { red[3] = s; red[4] = qq; red[5] = sbc; }
  }
  __syncthreads();
  if (t == 0) {
    float sdT = red[0] + red[3], sd2T = red[1] + red[4], sbcT = red[2] + red[5];
    float sc0 = 0.f, sc02 = 0.f;
    #pragma unroll
    for (int bb = 0; bb < 8; bb++) {
      float c = c0[bb * 1024 + co];
      sc0 += c; sc02 += c * c;
    }
    float S = 4096.0f * sc0 + sdT;
    float S2 = 4096.0f * sc02 + 2.0f * sbcT + sd2T;
    float mean = S * (1.0f / 32768.0f);
    float var = S2 * (1.0f / 32768.0f) - mean * mean;
    float inv = rsqrtf(var + 1e-5f) * bnw[co];
    bcast[0] = inv;
    bcast[1] = bnb[co] - mean * inv + c0[bc] * inv;
  }
  __syncthreads();
  const float inv = bcast[0], addc = bcast[1];
  const long base = (long)bc * 4096;
  #pragma unroll
  for (int i = 0; i < 2; i++) {
    const long off = base + (long)(i * 256 + t) * 8;
    uint4 v = *(const uint4*)(dy + off);
    float f[8]; unpack8(v, f);
    const float4 x0 = *(const float4*)(x + off);
    const float4 x1 = *(const float4*)(x + off + 4);
    float4 o0, o1;
    o0.x = f[0] * inv + addc + x0.x;
    o0.y = f[1] * inv + addc + x0.y;
    o0.z = f[2] * inv + addc + x0.z;
    o0.w = f[3] * inv + addc + x0.w;
    o1.x = f[4] * inv + addc + x1.x;
    o1.y = f[5] * inv + addc + x1.y;
    o1.z = f[6] * inv + addc + x1.z;
    o1.w = f[7] * inv + addc + x1.w;
    *(float4*)(out + off) = o0;
    *(float4*)(out + off + 4) = o1;
  }
}

extern "C" void kernel_launch(void* const* d_in, const int* in_sizes, int n_in,
                              void* d_out, int out_size, void* d_ws, size_t ws_size,
                              hipStream_t stream) {
  (void)in_sizes; (void)n_in; (void)out_size; (void)ws_size;
  const float* x       = (const float*)d_in[0];
  const float* theta_w = (const float*)d_in[1];
  const float* theta_b = (const float*)d_in[2];
  const float* phi_w   = (const float*)d_in[3];
  const float* phi_b   = (const float*)d_in[4];
  const float* g_w     = (const float*)d_in[5];
  const float* g_b     = (const float*)d_in[6];
  const float* out_w   = (const float*)d_in[7];
  const float* out_b   = (const float*)d_in[8];
  const float* bn_w    = (const float*)d_in[9];
  const float* bn_b    = (const float*)d_in[10];
  float* out = (float*)d_out;
  char* ws = (char*)d_ws;
  const size_t MB = 1024 * 1024;

  // workspace layout
  u16* xT     = (u16*)(ws + 0 * MB);       // 64MB; later: dy bf16 [0,64MB)
  u16* poolT  = (u16*)(ws + 64 * MB);      // 16MB
  u16* w_th   = (u16*)(ws + 80 * MB);      // 1MB
  u16* w_ph   = (u16*)(ws + 81 * MB);      // 1MB  (w_ph || w_g contiguous)
  u16* w_g    = (u16*)(ws + 82 * MB);      // 1MB
  u16* thetaT = (u16*)(ws + 84 * MB);      // 32MB
  u16* phiT   = (u16*)(ws + 116 * MB);     // 8MB
  u16* g_n    = (u16*)(ws + 124 * MB);     // 8MB
  u16* e      = (u16*)(ws + 132 * MB);     // 64MB (exp(scores))
  u16* tT     = (u16*)(ws + 196 * MB);     // 32MB (delta-t bf16)
  u16* w_out  = (u16*)(ws + 228 * MB);     // 1MB
  float* gbar  = (float*)(ws + 229 * MB);            // 16KB
  float* c0b   = (float*)(ws + 229 * MB + 16384);    // 32KB
  float* partial = (float*)(ws + 230 * MB);          // 512KB (8*4*4096 f32)
  float* partial2 = (float*)(ws + 231 * MB);         // 1MB (512 blk * 512 f32)
  float* g_ps = (float*)(ws + 233 * MB);             // 128KB (8*8*512 f32)
  u16* dy = xT;               // alias: x_T dead after theta GEMM

  // 1. weights -> bf16 (single launch)
  cvt4_kernel<<<2048, 256, 0, stream>>>(theta_w, phi_w, g_w, out_w,
                                        w_th, w_ph, w_g, w_out);
  // 2. x -> x_T bf16 with fused 2x2 maxpool
  transpose_pool_kernel<<<dim3(32, 16, 8), 256, 0, stream>>>(x, xT, poolT);
  // 4. theta -> theta_T [b][4096][512]  (256-tile 8-phase GEMM)
  gemm256<1, true, false, false, false, false>
      <<<dim3(16, 2, 8), 512, 0, stream>>>(
      w_th, xT, thetaT, theta_b, 0L, nullptr, 0L, nullptr, 0L, nullptr,
      1.0f, 512, 4096, 1024, 0L, (long)NPIX * CIN, (long)NPIX * DI);
  // 5+6. merged phi+g GEMM (128-tile kernel)
  gemm_tn<3, true, false, false, false, false, false>
      <<<dim3(8, 8, 8), 256, 0, stream>>>(
      w_ph, poolT, phiT, g_n, phi_b, g_b, 0L, nullptr, 0L, nullptr, 0L,
      g_ps, 1.0f, 1024, 1024, 1024, 0L, (long)MPIX * CIN, (long)MPIX * DI);
  // 6b. gbar from partials ; c0
  gbar_kernel<<<16, 256, 0, stream>>>(g_ps, gbar);
  c0_kernel<<<2048, 256, 0, stream>>>(out_w, out_b, gbar, c0b);
  // 7. e[n][m] = exp(scores) + per-block rowsum partials (gridX=4)
  gemm256<0, false, false, true, false, false>
      <<<dim3(4, 16, 8), 512, 0, stream>>>(
      thetaT, phiT, e, nullptr, 0L, nullptr, 0L, nullptr, 0L, partial,
      0.044194173824159216f, 4096, 1024, 512,
      (long)NPIX * DI, (long)MPIX * DI, (long)NPIX * MPIX);
  // 8+9. delta-t = (g_n * e^T)*inv[n] - gbar[d]; inv from partials (CSP)
  gemm256<1, false, true, false, false, true>
      <<<dim3(16, 2, 8), 512, 0, stream>>>(
      g_n, e, tT, nullptr, 0L, partial, 16384L, gbar, 512L, nullptr,
      1.0f, 512, 4096, 1024,
      (long)DI * MPIX, (long)NPIX * MPIX, (long)NPIX * DI);
  // 10. dy = out_w * delta-t^T + BN partials (PSUM2)
  gemm256<0, false, false, false, true, false>
      <<<dim3(16, 4, 8), 512, 0, stream>>>(
      w_out, tT, dy, nullptr, 0L, nullptr, 0L, nullptr, 0L, partial2,
      1.0f, 1024, 4096, 512, 0L, (long)NPIX * DI, (long)1024 * NPIX);
  // 11+12. BN stats (from partials, in-block) + apply + residual
  final_kernel<<<8192, 256, 0, stream>>>(dy, x, partial2, c0b, bn_w, bn_b, out);
}

// Round 13
// 335.140 us; speedup vs baseline: 1.0286x; 1.0079x over previous
//
#include <hip/hip_runtime.h>
#include <cstdint>

typedef unsigned short u16;
typedef __attribute__((ext_vector_type(4))) unsigned short u16x4;
typedef __attribute__((ext_vector_type(8))) short short8;
typedef __attribute__((ext_vector_type(4))) float f32x4;

#define DI 512
#define CIN 1024
#define NPIX 4096   // 64*64
#define MPIX 1024   // 32*32

__device__ __forceinline__ float bf2f(u16 u) {
  union { unsigned int i; float f; } v; v.i = ((unsigned int)u) << 16; return v.f;
}
__device__ __forceinline__ u16 f2bf(float f) {
  union { float f; unsigned int i; } v; v.f = f;
  unsigned int r = v.i + 0x7fffu + ((v.i >> 16) & 1u);
  return (u16)(r >> 16);
}
__device__ __forceinline__ void unpack8(uint4 v, float* f) {
  union { unsigned int i; float f; } u;
  u.i = v.x << 16;          f[0] = u.f;
  u.i = v.x & 0xffff0000u;  f[1] = u.f;
  u.i = v.y << 16;          f[2] = u.f;
  u.i = v.y & 0xffff0000u;  f[3] = u.f;
  u.i = v.z << 16;          f[4] = u.f;
  u.i = v.z & 0xffff0000u;  f[5] = u.f;
  u.i = v.w << 16;          f[6] = u.f;
  u.i = v.w & 0xffff0000u;  f[7] = u.f;
}

// async global->LDS, 16B per lane, wave-uniform LDS base + lane*16
__device__ __forceinline__ void gload16(const u16* g, u16* l) {
  __builtin_amdgcn_global_load_lds(
      (const __attribute__((address_space(1))) void*)g,
      (__attribute__((address_space(3))) void*)l, 16, 0, 0);
}

template<int N> __device__ __forceinline__ void wait_vmcnt() {
  asm volatile("s_waitcnt vmcnt(%0)" :: "n"(N) : "memory");
}
__device__ __forceinline__ void phase_begin() {
  __builtin_amdgcn_s_barrier();
  __builtin_amdgcn_sched_barrier(0);
  asm volatile("" ::: "memory");
}
__device__ __forceinline__ void phase_end() {
  asm volatile("s_waitcnt lgkmcnt(0)" ::: "memory");
  __builtin_amdgcn_sched_barrier(0);
  __builtin_amdgcn_s_barrier();
  __builtin_amdgcn_sched_barrier(0);
}

// ---- prep: blocks [0,4096): x -> x_T + 2x2 maxpool; [4096,6144): cvt ----
__global__ __launch_bounds__(256) void prep_kernel(
    const float* __restrict__ x, u16* __restrict__ xT, u16* __restrict__ poolT,
    const float* __restrict__ s0, const float* __restrict__ s1,
    const float* __restrict__ s2, const float* __restrict__ s3,
    u16* __restrict__ d0, u16* __restrict__ d1,
    u16* __restrict__ d2, u16* __restrict__ d3) {
  __shared__ u16 tile[64][136];
  const int blk = blockIdx.x;
  const int t = threadIdx.x;
  if (blk >= 4096) {                       // weight f32 -> bf16 convert
    int i = (blk - 4096) * 256 + t;        // 0 .. 4*131072
    int sel = i >> 17;
    int j = i & 131071;
    const float* src = sel == 0 ? s0 : sel == 1 ? s1 : sel == 2 ? s2 : s3;
    u16* dst = sel == 0 ? d0 : sel == 1 ? d1 : sel == 2 ? d2 : d3;
    float4 v = *(const float4*)(src + (long)j * 4);
    u16x4 w;
    w[0] = f2bf(v.x); w[1] = f2bf(v.y); w[2] = f2bf(v.z); w[3] = f2bf(v.w);
    *(u16x4*)(dst + (long)j * 4) = w;
    return;
  }
  const int bx = blk & 31, by = (blk >> 5) & 15, b = blk >> 9;
  const int n0 = bx * 128, c0 = by * 64;
  const float* xb = x + (long)b * CIN * NPIX;
  u16* xTb = xT + (long)b * NPIX * CIN;
  const int tc = t >> 5, tn = (t & 31) * 4;
  #pragma unroll
  for (int i = 0; i < 8; i++) {
    int c = tc + i * 8;
    float4 v = *(const float4*)(xb + (long)(c0 + c) * NPIX + n0 + tn);
    u16x4 w;
    w[0] = f2bf(v.x); w[1] = f2bf(v.y); w[2] = f2bf(v.z); w[3] = f2bf(v.w);
    *(u16x4*)&tile[c][tn] = w;
  }
  __syncthreads();
  const int tn2 = t >> 4, tc2 = (t & 15) * 4;
  #pragma unroll
  for (int i = 0; i < 8; i++) {
    int n = tn2 + i * 16;
    u16x4 w;
    w[0] = tile[tc2 + 0][n];
    w[1] = tile[tc2 + 1][n];
    w[2] = tile[tc2 + 2][n];
    w[3] = tile[tc2 + 3][n];
    *(u16x4*)(xTb + (long)(n0 + n) * CIN + c0 + tc2) = w;
  }
  const int j = t & 31, g = t >> 5;
  u16 r[8] __attribute__((aligned(16)));
  #pragma unroll
  for (int k = 0; k < 8; k++) {
    const int c = g * 8 + k;
    const unsigned w0 = *(const unsigned*)&tile[c][2 * j];
    const unsigned w1 = *(const unsigned*)&tile[c][64 + 2 * j];
    float m0 = fmaxf(bf2f((u16)(w0 & 0xffffu)), bf2f((u16)(w0 >> 16)));
    float m1 = fmaxf(bf2f((u16)(w1 & 0xffffu)), bf2f((u16)(w1 >> 16)));
    r[k] = f2bf(fmaxf(m0, m1));
  }
  *(uint4*)(poolT + ((long)b * MPIX + bx * 32 + j) * CIN + c0 + g * 8) =
      *(uint4*)r;
}

// =============== 256x256-tile GEMM, 8 waves, 8-phase counted-vmcnt =======
template<int OM, bool HAS_BIAS, bool HAS_SHIFT, bool HAS_EXP, bool HAS_PSUM2,
         bool HAS_CSP>
__global__ __launch_bounds__(512, 2)
void gemm256(const u16* __restrict__ A, const u16* __restrict__ B,
             void* __restrict__ Cv,
             const float* __restrict__ bias, long sBias,
             const float* __restrict__ cs, long sCS,
             const float* __restrict__ shift, long sShift,
             float* __restrict__ psum_out,
             float scale, int M, int N, int K, long sA, long sB, long sC)
{
  A += blockIdx.z * sA;
  B += blockIdx.z * sB;
  if (HAS_BIAS) bias += blockIdx.z * sBias;
  if (HAS_CSP) cs += blockIdx.z * sCS;
  if (HAS_SHIFT) shift += blockIdx.z * sShift;
  const int bm = blockIdx.y * 256, bn = blockIdx.x * 256;
  __shared__ __align__(16) u16 smem[65536];   // 2 slots x 64KB
  __shared__ float psum[4][256];
  __shared__ float psumq[4][256];
  __shared__ float invs[256];
  const int tid = threadIdx.x;
  const int lane = tid & 63, wave = tid >> 6;
  const int wr = wave >> 2, wc = wave & 3;       // 2M x 4N waves
  const int lr = lane & 15, q = lane >> 4;
  f32x4 acc[8][4] = {};

  if (HAS_CSP) {
    if (tid < 256) {
      float ssum = 0.f;
      #pragma unroll
      for (int xx = 0; xx < 4; xx++) ssum += cs[xx * 4096 + bn + tid];
      invs[tid] = 1.0f / ssum;
    }
    wait_vmcnt<0>();
    __builtin_amdgcn_sched_barrier(0);
  }

  const int srow = 32 * wave + (lane >> 2);
  const int sk = (((lane & 3) ^ ((lane >> 3) & 3))) * 8;
  const u16* Abase = A + ((long)bm + srow) * K + sk;
  const u16* Bbase = B + ((long)bn + srow) * K + sk;
  const int rswz = (q ^ ((lr >> 1) & 3)) * 8;
  const int aoff = (wr * 128 + lr) * 32 + rswz;
  const int boff = 16384 + (wc * 64 + lr) * 32 + rswz;

#define SA(T_, KK_) { const u16* g_ = Abase + (long)(T_) * 64 + (KK_) * 32; \
    u16* d_ = &smem[(((T_) & 1)) * 32768 + (KK_) * 8192 + wave * 1024]; \
    gload16(g_, d_); gload16(g_ + 16 * (long)K, d_ + 512); }
#define SB(T_, KK_) { const u16* g_ = Bbase + (long)(T_) * 64 + (KK_) * 32; \
    u16* d_ = &smem[(((T_) & 1)) * 32768 + 16384 + (KK_) * 8192 + wave * 1024]; \
    gload16(g_, d_); gload16(g_ + 16 * (long)K, d_ + 512); }
#define CQ(SLOT, KK, RI0, LOADBV) { \
    const int qb_ = (SLOT) * 32768 + (KK) * 8192; \
    if (LOADBV) { \
      _Pragma("unroll") \
      for (int ci_ = 0; ci_ < 4; ci_++) \
        bv[ci_] = *(const short8*)&smem[qb_ + boff + ci_ * 512]; \
    } \
    short8 av_[4]; \
    _Pragma("unroll") \
    for (int r_ = 0; r_ < 4; r_++) \
      av_[r_] = *(const short8*)&smem[qb_ + aoff + ((RI0) + r_) * 512]; \
    __builtin_amdgcn_s_setprio(1); \
    _Pragma("unroll") \
    for (int r_ = 0; r_ < 4; r_++) \
      _Pragma("unroll") \
      for (int ci_ = 0; ci_ < 4; ci_++) \
        acc[(RI0) + r_][ci_] = __builtin_amdgcn_mfma_f32_16x16x32_bf16( \
            av_[r_], bv[ci_], acc[(RI0) + r_][ci_], 0, 0, 0); \
    __builtin_amdgcn_s_setprio(0); }
#define PH(VM, STG, SLOT, KK, RI0, LOADBV) \
    STG; wait_vmcnt<VM>(); phase_begin(); CQ(SLOT, KK, RI0, LOADBV); phase_end();

  const int niter2 = K >> 7;
  short8 bv[4];

  SA(0, 0); SB(0, 0); SA(0, 1); SB(0, 1); SA(1, 0); SB(1, 0);

  for (int u = 0; u < niter2 - 1; ++u) {
    const int t1 = 2 * u + 1, t2 = 2 * u + 2, t3 = 2 * u + 3;
    PH(10, SA(t1, 1), 0, 0, 0, 1)
    PH(10, SB(t1, 1), 0, 0, 4, 0)
    PH(10, SA(t2, 0), 0, 1, 0, 1)
    PH(10, SB(t2, 0), 0, 1, 4, 0)
    PH(10, SA(t2, 1), 1, 0, 0, 1)
    PH(10, SB(t2, 1), 1, 0, 4, 0)
    PH(10, SA(t3, 0), 1, 1, 0, 1)
    PH(10, SB(t3, 0), 1, 1, 4, 0)
  }
  {
    const int t1 = 2 * (niter2 - 1) + 1;
    PH(10, SA(t1, 1), 0, 0, 0, 1)
    PH(10, SB(t1, 1), 0, 0, 4, 0)
    PH(8,  ((void)0), 0, 1, 0, 1)
    PH(6,  ((void)0), 0, 1, 4, 0)
    PH(4,  ((void)0), 1, 0, 0, 1)
    PH(2,  ((void)0), 1, 0, 4, 0)
    PH(0,  ((void)0), 1, 1, 0, 1)
    PH(0,  ((void)0), 1, 1, 4, 0)
  }
#undef SA
#undef SB
#undef CQ
#undef PH

  __syncthreads();

  const int dr = (lane >> 4) * 4;
  float invc[4];
  if (HAS_CSP) {
    #pragma unroll
    for (int ci = 0; ci < 4; ci++) invc[ci] = invs[wc * 64 + ci * 16 + lr];
  }
  float rowsum[8][4], rowsq[8][4];
  if (HAS_EXP || HAS_PSUM2) {
    #pragma unroll
    for (int ri = 0; ri < 8; ri++)
      #pragma unroll
      for (int r = 0; r < 4; r++) { rowsum[ri][r] = 0.f; rowsq[ri][r] = 0.f; }
  }
  #pragma unroll
  for (int ri = 0; ri < 8; ri++) {
    const int rowl = wr * 128 + ri * 16 + dr;
    const int rowb = bm + rowl;
    float bvs[4] = {0.f, 0.f, 0.f, 0.f};
    float shv[4] = {0.f, 0.f, 0.f, 0.f};
    if (HAS_BIAS) {
      #pragma unroll
      for (int r = 0; r < 4; r++) bvs[r] = bias[rowb + r];
    }
    if (HAS_SHIFT) {
      #pragma unroll
      for (int r = 0; r < 4; r++) shv[r] = shift[rowb + r];
    }
    #pragma unroll
    for (int ci = 0; ci < 4; ci++) {
      const int coll = wc * 64 + ci * 16 + lr;
      float v[4];
      #pragma unroll
      for (int r = 0; r < 4; r++) {
        float tv = acc[ri][ci][r] * scale;
        if (HAS_CSP) tv *= invc[ci];
        if (HAS_SHIFT) tv -= shv[r];
        if (HAS_BIAS) tv += bvs[r];
        if (HAS_EXP) tv = __expf(tv);
        if (HAS_EXP || HAS_PSUM2) rowsum[ri][r] += tv;
        if (HAS_PSUM2) rowsq[ri][r] += tv * tv;
        v[r] = tv;
      }
      if (OM == 1) {
        u16x4 w;
        #pragma unroll
        for (int r = 0; r < 4; r++) w[r] = f2bf(v[r]);
        unsigned bo = (unsigned)((coll * 256 + rowl) * 2) ^ ((coll & 7) << 4);
        *(u16x4*)((char*)smem + bo) = w;
      } else {
        #pragma unroll
        for (int r = 0; r < 4; r++) {
          const int row = rowl + r;
          smem[row * 256 + (coll ^ (((row >> 2) & 3) << 4))] = f2bf(v[r]);
        }
      }
    }
  }
  if (HAS_EXP || HAS_PSUM2) {
    #pragma unroll
    for (int msk = 1; msk < 16; msk <<= 1)
      #pragma unroll
      for (int ri = 0; ri < 8; ri++)
        #pragma unroll
        for (int r = 0; r < 4; r++) {
          rowsum[ri][r] += __shfl_xor(rowsum[ri][r], msk);
          if (HAS_PSUM2) rowsq[ri][r] += __shfl_xor(rowsq[ri][r], msk);
        }
    if ((lane & 15) == 0) {
      #pragma unroll
      for (int ri = 0; ri < 8; ri++)
        #pragma unroll
        for (int r = 0; r < 4; r++) {
          psum[wc][wr * 128 + ri * 16 + dr + r] = rowsum[ri][r];
          if (HAS_PSUM2) psumq[wc][wr * 128 + ri * 16 + dr + r] = rowsq[ri][r];
        }
    }
  }
  __syncthreads();
  u16* C = (u16*)Cv + blockIdx.z * sC;
  if (OM == 1) {
    #pragma unroll
    for (int i = 0; i < 16; i++) {
      const int chunk = i * 512 + tid;
      const int coll = chunk >> 5, rq = chunk & 31;
      unsigned bo = (unsigned)(coll * 512 + rq * 16) ^ ((coll & 7) << 4);
      uint4 w = *(const uint4*)((const char*)smem + bo);
      *(uint4*)(C + (long)(bn + coll) * M + bm + rq * 8) = w;
    }
  } else {
    #pragma unroll
    for (int i = 0; i < 16; i++) {
      const int chunk = i * 512 + tid;
      const int row = chunk >> 5, cq = chunk & 31;
      const int cbase = (cq * 8) ^ (((row >> 2) & 3) << 4);
      uint4 w = *(const uint4*)(smem + row * 256 + cbase);
      *(uint4*)(C + (long)(bm + row) * N + bn + cq * 8) = w;
    }
  }
  if ((HAS_EXP || HAS_PSUM2) && tid < 256) {
    if (HAS_EXP)
      psum_out[((long)blockIdx.z * gridDim.x + blockIdx.x) * 4096 + bm + tid] =
          psum[0][tid] + psum[1][tid] + psum[2][tid] + psum[3][tid];
    if (HAS_PSUM2) {
      const long blk = ((long)blockIdx.z * gridDim.y + blockIdx.y) * gridDim.x
                       + blockIdx.x;
      psum_out[blk * 512 + tid] =
          psum[0][tid] + psum[1][tid] + psum[2][tid] + psum[3][tid];
      psum_out[blk * 512 + 256 + tid] =
          psumq[0][tid] + psumq[1][tid] + psumq[2][tid] + psumq[3][tid];
    }
  }
}

// ---------------- 128x128 GEMM (merged phi+g) ----------------
template<int OM, bool HAS_BIAS, bool HAS_CS, bool HAS_SHIFT, bool HAS_EXP,
         bool HAS_PSUM2, bool HAS_CSP>
__global__ __launch_bounds__(256)
void gemm_tn(const u16* __restrict__ A, const u16* __restrict__ B,
             void* __restrict__ Cv, void* __restrict__ Cv2,
             const float* __restrict__ bias, const float* __restrict__ bias2,
             long sBias,
             const float* __restrict__ cs, long sCS,
             const float* __restrict__ shift, long sShift,
             float* __restrict__ psum_out,
             float scale, int M, int N, int K, long sA, long sB, long sC)
{
  A += blockIdx.z * sA;
  B += blockIdx.z * sB;
  if (HAS_BIAS) bias += blockIdx.z * sBias;
  if (HAS_CS || HAS_CSP) cs += blockIdx.z * sCS;
  if (HAS_SHIFT) shift += blockIdx.z * sShift;
  const int bm = blockIdx.y * 128;
  const int bn = blockIdx.x * 128;
  __shared__ __align__(16) u16 smem[128 * 128];
  u16* As = smem;
  u16* Bs = smem + 128 * 64;
  __shared__ float psum[4][128];
  const int tid = threadIdx.x;
  const int lane = tid & 63;
  const int wave = tid >> 6;
  const int wm = (wave >> 1) * 64;
  const int wn = (wave & 1) * 64;
  const int lr = lane & 15;
  const int q  = lane >> 4;
  const int sxor = lane & 7;
  const bool gps = (OM == 3) && (bm >= 512);
  f32x4 acc[4][4] = {};

  if (HAS_CSP) {
    if (tid < 128) {
      float s = 0.f;
      #pragma unroll
      for (int xx = 0; xx < 8; xx++) s += cs[xx * 4096 + bn + tid];
      psum[0][tid] = 1.0f / s;
    }
  }

  const int swz = ((lane & 7) ^ (lane >> 3)) * 8;
  const long grow = 32 * wave + (lane >> 3);
  const u16* Ag = A + ((long)bm + grow) * K + swz;
  const u16* Bg = B + ((long)bn + grow) * K + swz;

  for (int kt = 0; kt < K; kt += 64) {
    __syncthreads();
    #pragma unroll
    for (int i = 0; i < 4; i++) {
      gload16(Ag + (long)(8 * i) * K + kt, &As[(wave * 4 + i) * 512]);
      gload16(Bg + (long)(8 * i) * K + kt, &Bs[(wave * 4 + i) * 512]);
    }
    __syncthreads();
    #pragma unroll
    for (int kk = 0; kk < 2; kk++) {
      short8 av[4], bv[4];
      #pragma unroll
      for (int mi = 0; mi < 4; mi++)
        av[mi] = *(const short8*)&As[(wm + mi * 16 + lr) * 64 +
                                     (((kk << 2) + q) ^ sxor) * 8];
      #pragma unroll
      for (int ni = 0; ni < 4; ni++)
        bv[ni] = *(const short8*)&Bs[(wn + ni * 16 + lr) * 64 +
                                     (((kk << 2) + q) ^ sxor) * 8];
      #pragma unroll
      for (int mi = 0; mi < 4; mi++) {
        #pragma unroll
        for (int ni = 0; ni < 4; ni++)
          acc[mi][ni] = __builtin_amdgcn_mfma_f32_16x16x32_bf16(
              av[mi], bv[ni], acc[mi][ni], 0, 0, 0);
      }
    }
  }

  float invc[4];
  if (HAS_CSP) {
    #pragma unroll
    for (int ni = 0; ni < 4; ni++) invc[ni] = psum[0][wn + ni * 16 + lr];
  }
  __syncthreads();
  const int dr = (lane >> 4) * 4;
  const bool trans_out = (OM == 1) || (OM == 3 && !gps);
  float rowsum[4][4];
  float rowsq[4][4];
  if (HAS_EXP || HAS_PSUM2 || gps) {
    #pragma unroll
    for (int mi = 0; mi < 4; mi++)
      #pragma unroll
      for (int r = 0; r < 4; r++) { rowsum[mi][r] = 0.f; rowsq[mi][r] = 0.f; }
  }
  const float* bp = (OM == 3 && gps) ? bias2 - 512 : bias;
  #pragma unroll
  for (int mi = 0; mi < 4; mi++) {
    const int rowl = wm + mi * 16 + dr;
    const int rowb = bm + rowl;
    float bvs[4] = {0.f, 0.f, 0.f, 0.f};
    float shv[4] = {0.f, 0.f, 0.f, 0.f};
    if (HAS_BIAS) {
      #pragma unroll
      for (int r = 0; r < 4; r++) bvs[r] = bp[rowb + r];
    }
    if (HAS_SHIFT) {
      #pragma unroll
      for (int r = 0; r < 4; r++) shv[r] = shift[rowb + r];
    }
    #pragma unroll
    for (int ni = 0; ni < 4; ni++) {
      const int coll = wn + ni * 16 + lr;
      const float csv = HAS_CSP ? invc[ni] : (HAS_CS ? cs[bn + coll] : 1.0f);
      float v[4];
      #pragma unroll
      for (int r = 0; r < 4; r++) {
        float t = acc[mi][ni][r] * scale;
        if (HAS_CS || HAS_CSP) t *= csv;
        if (HAS_SHIFT) t -= shv[r];
        if (HAS_BIAS) t += bvs[r];
        if (HAS_EXP) t = __expf(t);
        if (HAS_EXP || HAS_PSUM2 || gps) rowsum[mi][r] += t;
        if (HAS_PSUM2) rowsq[mi][r] += t * t;
        v[r] = t;
      }
      if (trans_out) {
        u16x4 w;
        #pragma unroll
        for (int r = 0; r < 4; r++) w[r] = f2bf(v[r]);
        unsigned bo = (unsigned)((coll * 128 + rowl) * 2) ^ ((coll & 7) << 4);
        *(u16x4*)((char*)smem + bo) = w;
      } else {
        #pragma unroll
        for (int r = 0; r < 4; r++) {
          const int row = rowl + r;
          smem[row * 128 + (coll ^ (((row >> 2) & 3) << 4))] = f2bf(v[r]);
        }
      }
    }
  }
  if (HAS_EXP || HAS_PSUM2 || gps) {
    #pragma unroll
    for (int msk = 1; msk < 16; msk <<= 1)
      #pragma unroll
      for (int mi = 0; mi < 4; mi++)
        #pragma unroll
        for (int r = 0; r < 4; r++) {
          rowsum[mi][r] += __shfl_xor(rowsum[mi][r], msk);
          if (HAS_PSUM2) rowsq[mi][r] += __shfl_xor(rowsq[mi][r], msk);
        }
    if ((lane & 15) == 0) {
      #pragma unroll
      for (int mi = 0; mi < 4; mi++)
        #pragma unroll
        for (int r = 0; r < 4; r++) {
          psum[wave & 1][wm + mi * 16 + dr + r] = rowsum[mi][r];
          if (HAS_PSUM2) psum[2 + (wave & 1)][wm + mi * 16 + dr + r] = rowsq[mi][r];
        }
    }
  }
  __syncthreads();
  if (trans_out) {
    const int Ms = (OM == 3) ? 512 : M;
    u16* C = (u16*)Cv + blockIdx.z * sC;
    #pragma unroll
    for (int i = 0; i < 8; i++) {
      const int chunk = i * 256 + tid;
      const int coll = chunk >> 4, rq = chunk & 15;
      unsigned bo = (unsigned)(coll * 256 + rq * 16) ^ ((coll & 7) << 4);
      uint4 w = *(const uint4*)((const char*)smem + bo);
      *(uint4*)(C + (long)(bn + coll) * Ms + bm + rq * 8) = w;
    }
  } else {
    u16* C = (OM == 3) ? (u16*)Cv2 + blockIdx.z * sC : (u16*)Cv + blockIdx.z * sC;
    const int rbase = (OM == 3) ? bm - 512 : bm;
    #pragma unroll
    for (int i = 0; i < 8; i++) {
      const int chunk = i * 256 + tid;
      const int row = chunk >> 4, cq = chunk & 15;
      const int cbase = (cq * 8) ^ (((row >> 2) & 3) << 4);
      uint4 w = *(const uint4*)(smem + row * 128 + cbase);
      *(uint4*)(C + (long)(rbase + row) * N + bn + cq * 8) = w;
    }
  }
  if (HAS_EXP || HAS_PSUM2 || gps) {
    if (tid < 128) {
      if (HAS_EXP)
        psum_out[((long)blockIdx.z * gridDim.x + blockIdx.x) * 4096 + bm + tid] =
            psum[0][tid] + psum[1][tid];
      if (HAS_PSUM2) {
        const long blk = ((long)blockIdx.z * gridDim.y + blockIdx.y) * gridDim.x
                         + blockIdx.x;
        psum_out[blk * 256 + tid] = psum[0][tid] + psum[1][tid];
        psum_out[blk * 256 + 128 + tid] = psum[2][tid] + psum[3][tid];
      }
      if (gps)
        psum_out[((long)blockIdx.z * gridDim.x + blockIdx.x) * 512 +
                 (bm - 512) + tid] = psum[0][tid] + psum[1][tid];
    }
  }
}

// --- c0[b][c] = out_b[c] + sum_d out_w_f32[c][d]*gbar[b][d] ; gbar inline --
// gbar[b][d] = (1/1024) * sum_x g_ps[b][x][d]; written once per (b, d-slice)
__global__ __launch_bounds__(256) void c0_kernel(const float* __restrict__ out_w,
                                                 const float* __restrict__ out_b,
                                                 const float* __restrict__ g_ps,
                                                 float* __restrict__ gbar,
                                                 float* __restrict__ c0) {
  const int idx = blockIdx.x * 4 + (threadIdx.x >> 6);   // 0..8191 = b*1024+c
  const int lane = threadIdx.x & 63;
  const int b = idx >> 10, c = idx & 1023;
  const int d0 = lane * 8;
  float g8[8] = {0.f, 0.f, 0.f, 0.f, 0.f, 0.f, 0.f, 0.f};
  #pragma unroll
  for (int xx = 0; xx < 8; xx++) {
    const float* p = g_ps + ((long)b * 8 + xx) * 512 + d0;
    float4 a0 = *(const float4*)p;
    float4 a1 = *(const float4*)(p + 4);
    g8[0] += a0.x; g8[1] += a0.y; g8[2] += a0.z; g8[3] += a0.w;
    g8[4] += a1.x; g8[5] += a1.y; g8[6] += a1.z; g8[7] += a1.w;
  }
  #pragma unroll
  for (int k = 0; k < 8; k++) g8[k] *= (1.0f / 1024.0f);
  if (c == 0) {
    float4 o0, o1;
    o0.x = g8[0]; o0.y = g8[1]; o0.z = g8[2]; o0.w = g8[3];
    o1.x = g8[4]; o1.y = g8[5]; o1.z = g8[6]; o1.w = g8[7];
    *(float4*)(gbar + (long)b * 512 + d0) = o0;
    *(float4*)(gbar + (long)b * 512 + d0 + 4) = o1;
  }
  float4 w0 = *(const float4*)(out_w + (long)c * DI + d0);
  float4 w1 = *(const float4*)(out_w + (long)c * DI + d0 + 4);
  float s = w0.x * g8[0] + w0.y * g8[1] + w0.z * g8[2] + w0.w * g8[3]
          + w1.x * g8[4] + w1.y * g8[5] + w1.z * g8[6] + w1.w * g8[7];
  #pragma unroll
  for (int off = 32; off > 0; off >>= 1) s += __shfl_xor(s, off);
  if (lane == 0) c0[idx] = out_b[c] + s;
}

// ------ BN stats (from y-GEMM partials) + apply + residual, fused --------
__global__ __launch_bounds__(256) void final_kernel(const u16* __restrict__ dy,
    const float* __restrict__ x, const float* __restrict__ partial,
    const float* __restrict__ c0,
    const float* __restrict__ bnw, const float* __restrict__ bnb,
    float* __restrict__ out) {
  __shared__ float red[6];
  __shared__ float bcast[2];
  const int bc = blockIdx.x;
  const int co = bc & 1023;
  const int t = threadIdx.x;
  if (t < 128) {
    const int b2 = t >> 4, bx = t & 15;
    const int by = co >> 8, r = co & 255;
    const long blk = (((long)b2 * 4 + by) * 16 + bx) * 512;
    float s = partial[blk + r];
    float qq = partial[blk + 256 + r];
    #pragma unroll
    for (int off = 1; off < 16; off <<= 1) {
      s += __shfl_xor(s, off);
      qq += __shfl_xor(qq, off);
    }
    float sbc = c0[b2 * 1024 + co] * s;
    #pragma unroll
    for (int off = 16; off < 64; off <<= 1) {
      s += __shfl_xor(s, off);
      qq += __shfl_xor(qq, off);
      sbc += __shfl_xor(sbc, off);
    }
    if (t == 0)  { red[0] = s; red[1] = qq; red[2] = sbc; }
    if (t == 64) { red[3] = s; red[4] = qq; red[5] = sbc; }
  }
  __syncthreads();
  if (t == 0) {
    float sdT = red[0] + red[3], sd2T = red[1] + red[4], sbcT = red[2] + red[5];
    float sc0 = 0.f, sc02 = 0.f;
    #pragma unroll
    for (int bb = 0; bb < 8; bb++) {
      float c = c0[bb * 1024 + co];
      sc0 += c; sc02 += c * c;
    }
    float S = 4096.0f * sc0 + sdT;
    float S2 = 4096.0f * sc02 + 2.0f * sbcT + sd2T;
    float mean = S * (1.0f / 32768.0f);
    float var = S2 * (1.0f / 32768.0f) - mean * mean;
    float inv = rsqrtf(var + 1e-5f) * bnw[co];
    bcast[0] = inv;
    bcast[1] = bnb[co] - mean * inv + c0[bc] * inv;
  }
  __syncthreads();
  const float inv = bcast[0], addc = bcast[1];
  const long base = (long)bc * 4096;
  #pragma unroll
  for (int i = 0; i < 2; i++) {
    const long off = base + (long)(i * 256 + t) * 8;
    uint4 v = *(const uint4*)(dy + off);
    float f[8]; unpack8(v, f);
    const float4 x0 = *(const float4*)(x + off);
    const float4 x1 = *(const float4*)(x + off + 4);
    float4 o0, o1;
    o0.x = f[0] * inv + addc + x0.x;
    o0.y = f[1] * inv + addc + x0.y;
    o0.z = f[2] * inv + addc + x0.z;
    o0.w = f[3] * inv + addc + x0.w;
    o1.x = f[4] * inv + addc + x1.x;
    o1.y = f[5] * inv + addc + x1.y;
    o1.z = f[6] * inv + addc + x1.z;
    o1.w = f[7] * inv + addc + x1.w;
    *(float4*)(out + off) = o0;
    *(float4*)(out + off + 4) = o1;
  }
}

extern "C" void kernel_launch(void* const* d_in, const int* in_sizes, int n_in,
                              void* d_out, int out_size, void* d_ws, size_t ws_size,
                              hipStream_t stream) {
  (void)in_sizes; (void)n_in; (void)out_size; (void)ws_size;
  const float* x       = (const float*)d_in[0];
  const float* theta_w = (const float*)d_in[1];
  const float* theta_b = (const float*)d_in[2];
  const float* phi_w   = (const float*)d_in[3];
  const float* phi_b   = (const float*)d_in[4];
  const float* g_w     = (const float*)d_in[5];
  const float* g_b     = (const float*)d_in[6];
  const float* out_w   = (const float*)d_in[7];
  const float* out_b   = (const float*)d_in[8];
  const float* bn_w    = (const float*)d_in[9];
  const float* bn_b    = (const float*)d_in[10];
  float* out = (float*)d_out;
  char* ws = (char*)d_ws;
  const size_t MB = 1024 * 1024;

  // workspace layout
  u16* xT     = (u16*)(ws + 0 * MB);       // 64MB; later: dy bf16 [0,64MB)
  u16* poolT  = (u16*)(ws + 64 * MB);      // 16MB
  u16* w_th   = (u16*)(ws + 80 * MB);      // 1MB
  u16* w_ph   = (u16*)(ws + 81 * MB);      // 1MB  (w_ph || w_g contiguous)
  u16* w_g    = (u16*)(ws + 82 * MB);      // 1MB
  u16* thetaT = (u16*)(ws + 84 * MB);      // 32MB
  u16* phiT   = (u16*)(ws + 116 * MB);     // 8MB
  u16* g_n    = (u16*)(ws + 124 * MB);     // 8MB
  u16* e      = (u16*)(ws + 132 * MB);     // 64MB (exp(scores))
  u16* tT     = (u16*)(ws + 196 * MB);     // 32MB (delta-t bf16)
  u16* w_out  = (u16*)(ws + 228 * MB);     // 1MB
  float* gbar  = (float*)(ws + 229 * MB);            // 16KB
  float* c0b   = (float*)(ws + 229 * MB + 16384);    // 32KB
  float* partial = (float*)(ws + 230 * MB);          // 512KB (8*4*4096 f32)
  float* partial2 = (float*)(ws + 231 * MB);         // 1MB (512 blk * 512 f32)
  float* g_ps = (float*)(ws + 233 * MB);             // 128KB (8*8*512 f32)
  u16* dy = xT;               // alias: x_T dead after theta GEMM

  // 1. prep: weights->bf16 + x->x_T + pool (single launch)
  prep_kernel<<<6144, 256, 0, stream>>>(x, xT, poolT,
                                        theta_w, phi_w, g_w, out_w,
                                        w_th, w_ph, w_g, w_out);
  // 2. theta -> theta_T [b][4096][512]  (256-tile 8-phase GEMM)
  gemm256<1, true, false, false, false, false>
      <<<dim3(16, 2, 8), 512, 0, stream>>>(
      w_th, xT, thetaT, theta_b, 0L, nullptr, 0L, nullptr, 0L, nullptr,
      1.0f, 512, 4096, 1024, 0L, (long)NPIX * CIN, (long)NPIX * DI);
  // 3. merged phi+g GEMM (128-tile kernel) -> phiT, g_n, g_ps
  gemm_tn<3, true, false, false, false, false, false>
      <<<dim3(8, 8, 8), 256, 0, stream>>>(
      w_ph, poolT, phiT, g_n, phi_b, g_b, 0L, nullptr, 0L, nullptr, 0L,
      g_ps, 1.0f, 1024, 1024, 1024, 0L, (long)MPIX * CIN, (long)MPIX * DI);
  // 4. c0 (computes gbar inline from g_ps; writes gbar for t-GEMM)
  c0_kernel<<<2048, 256, 0, stream>>>(out_w, out_b, g_ps, gbar, c0b);
  // 5. e[n][m] = exp(scores) + per-block rowsum partials (gridX=4)
  gemm256<0, false, false, true, false, false>
      <<<dim3(4, 16, 8), 512, 0, stream>>>(
      thetaT, phiT, e, nullptr, 0L, nullptr, 0L, nullptr, 0L, partial,
      0.044194173824159216f, 4096, 1024, 512,
      (long)NPIX * DI, (long)MPIX * DI, (long)NPIX * MPIX);
  // 6. delta-t = (g_n * e^T)*inv[n] - gbar[d]; inv from partials (CSP)
  gemm256<1, false, true, false, false, true>
      <<<dim3(16, 2, 8), 512, 0, stream>>>(
      g_n, e, tT, nullptr, 0L, partial, 16384L, gbar, 512L, nullptr,
      1.0f, 512, 4096, 1024,
      (long)DI * MPIX, (long)NPIX * MPIX, (long)NPIX * DI);
  // 7. dy = out_w * delta-t^T + BN partials (PSUM2)
  gemm256<0, false, false, false, true, false>
      <<<dim3(16, 4, 8), 512, 0, stream>>>(
      w_out, tT, dy, nullptr, 0L, nullptr, 0L, nullptr, 0L, partial2,
      1.0f, 1024, 4096, 512, 0L, (long)NPIX * DI, (long)1024 * NPIX);
  // 8. BN stats (from partials, in-block) + apply + residual
  final_kernel<<<8192, 256, 0, stream>>>(dy, x, partial2, c0b, bn_w, bn_b, out);
}

// Round 14
// 332.478 us; speedup vs baseline: 1.0368x; 1.0080x over previous
//
#include <hip/hip_runtime.h>
#include <cstdint>

typedef unsigned short u16;
typedef __attribute__((ext_vector_type(4))) unsigned short u16x4;
typedef __attribute__((ext_vector_type(8))) short short8;
typedef __attribute__((ext_vector_type(4))) float f32x4;

#define DI 512
#define CIN 1024
#define NPIX 4096   // 64*64
#define MPIX 1024   // 32*32

__device__ __forceinline__ float bf2f(u16 u) {
  union { unsigned int i; float f; } v; v.i = ((unsigned int)u) << 16; return v.f;
}
__device__ __forceinline__ u16 f2bf(float f) {
  union { float f; unsigned int i; } v; v.f = f;
  unsigned int r = v.i + 0x7fffu + ((v.i >> 16) & 1u);
  return (u16)(r >> 16);
}
__device__ __forceinline__ void unpack8(uint4 v, float* f) {
  union { unsigned int i; float f; } u;
  u.i = v.x << 16;          f[0] = u.f;
  u.i = v.x & 0xffff0000u;  f[1] = u.f;
  u.i = v.y << 16;          f[2] = u.f;
  u.i = v.y & 0xffff0000u;  f[3] = u.f;
  u.i = v.z << 16;          f[4] = u.f;
  u.i = v.z & 0xffff0000u;  f[5] = u.f;
  u.i = v.w << 16;          f[6] = u.f;
  u.i = v.w & 0xffff0000u;  f[7] = u.f;
}

// async global->LDS, 16B per lane, wave-uniform LDS base + lane*16
__device__ __forceinline__ void gload16(const u16* g, u16* l) {
  __builtin_amdgcn_global_load_lds(
      (const __attribute__((address_space(1))) void*)g,
      (__attribute__((address_space(3))) void*)l, 16, 0, 0);
}

template<int N> __device__ __forceinline__ void wait_vmcnt() {
  asm volatile("s_waitcnt vmcnt(%0)" :: "n"(N) : "memory");
}
__device__ __forceinline__ void phase_begin() {
  __builtin_amdgcn_s_barrier();
  __builtin_amdgcn_sched_barrier(0);
  asm volatile("" ::: "memory");
}
__device__ __forceinline__ void phase_end() {
  asm volatile("s_waitcnt lgkmcnt(0)" ::: "memory");
  __builtin_amdgcn_sched_barrier(0);
  __builtin_amdgcn_s_barrier();
  __builtin_amdgcn_sched_barrier(0);
}

// ---- prep: blocks [0,4096): x -> x_T + 2x2 maxpool; [4096,6144): cvt ----
__global__ __launch_bounds__(256) void prep_kernel(
    const float* __restrict__ x, u16* __restrict__ xT, u16* __restrict__ poolT,
    const float* __restrict__ s0, const float* __restrict__ s1,
    const float* __restrict__ s2, const float* __restrict__ s3,
    u16* __restrict__ d0, u16* __restrict__ d1,
    u16* __restrict__ d2, u16* __restrict__ d3) {
  __shared__ u16 tile[64][136];
  const int blk = blockIdx.x;
  const int t = threadIdx.x;
  if (blk >= 4096) {                       // weight f32 -> bf16 convert
    int i = (blk - 4096) * 256 + t;        // 0 .. 4*131072
    int sel = i >> 17;
    int j = i & 131071;
    const float* src = sel == 0 ? s0 : sel == 1 ? s1 : sel == 2 ? s2 : s3;
    u16* dst = sel == 0 ? d0 : sel == 1 ? d1 : sel == 2 ? d2 : d3;
    float4 v = *(const float4*)(src + (long)j * 4);
    u16x4 w;
    w[0] = f2bf(v.x); w[1] = f2bf(v.y); w[2] = f2bf(v.z); w[3] = f2bf(v.w);
    *(u16x4*)(dst + (long)j * 4) = w;
    return;
  }
  const int bx = blk & 31, by = (blk >> 5) & 15, b = blk >> 9;
  const int n0 = bx * 128, c0 = by * 64;
  const float* xb = x + (long)b * CIN * NPIX;
  u16* xTb = xT + (long)b * NPIX * CIN;
  const int tc = t >> 5, tn = (t & 31) * 4;
  #pragma unroll
  for (int i = 0; i < 8; i++) {
    int c = tc + i * 8;
    float4 v = *(const float4*)(xb + (long)(c0 + c) * NPIX + n0 + tn);
    u16x4 w;
    w[0] = f2bf(v.x); w[1] = f2bf(v.y); w[2] = f2bf(v.z); w[3] = f2bf(v.w);
    *(u16x4*)&tile[c][tn] = w;
  }
  __syncthreads();
  const int tn2 = t >> 4, tc2 = (t & 15) * 4;
  #pragma unroll
  for (int i = 0; i < 8; i++) {
    int n = tn2 + i * 16;
    u16x4 w;
    w[0] = tile[tc2 + 0][n];
    w[1] = tile[tc2 + 1][n];
    w[2] = tile[tc2 + 2][n];
    w[3] = tile[tc2 + 3][n];
    *(u16x4*)(xTb + (long)(n0 + n) * CIN + c0 + tc2) = w;
  }
  const int j = t & 31, g = t >> 5;
  u16 r[8] __attribute__((aligned(16)));
  #pragma unroll
  for (int k = 0; k < 8; k++) {
    const int c = g * 8 + k;
    const unsigned w0 = *(const unsigned*)&tile[c][2 * j];
    const unsigned w1 = *(const unsigned*)&tile[c][64 + 2 * j];
    float m0 = fmaxf(bf2f((u16)(w0 & 0xffffu)), bf2f((u16)(w0 >> 16)));
    float m1 = fmaxf(bf2f((u16)(w1 & 0xffffu)), bf2f((u16)(w1 >> 16)));
    r[k] = f2bf(fmaxf(m0, m1));
  }
  *(uint4*)(poolT + ((long)b * MPIX + bx * 32 + j) * CIN + c0 + g * 8) =
      *(uint4*)r;
}

// =============== 256x256-tile GEMM, 8 waves, 8-phase counted-vmcnt =======
// XSWZ: flat 512-block launch, XCD-swizzled decode so the 4 blocks sharing
// an A-row-panel (logical x = 0..3) get linear ids {c,c+8,c+16,c+24} -> same
// XCD L2. Logical dims fixed at (4, 16, 8) in that mode.
template<int OM, bool HAS_BIAS, bool HAS_SHIFT, bool HAS_EXP, bool HAS_PSUM2,
         bool HAS_CSP, bool XSWZ>
__global__ __launch_bounds__(512, 2)
void gemm256(const u16* __restrict__ A, const u16* __restrict__ B,
             void* __restrict__ Cv,
             const float* __restrict__ bias, long sBias,
             const float* __restrict__ cs, long sCS,
             const float* __restrict__ shift, long sShift,
             float* __restrict__ psum_out,
             float scale, int M, int N, int K, long sA, long sB, long sC)
{
  int bxi, byi, bzi;
  if (XSWZ) {
    const int q = blockIdx.x >> 5, s = blockIdx.x & 31;
    bxi = s >> 3;                       // 0..3
    const int yz = q * 8 + (s & 7);     // 0..127
    byi = yz & 15;
    bzi = yz >> 4;
  } else {
    bxi = blockIdx.x; byi = blockIdx.y; bzi = blockIdx.z;
  }
  A += bzi * sA;
  B += bzi * sB;
  if (HAS_BIAS) bias += bzi * sBias;
  if (HAS_CSP) cs += bzi * sCS;
  if (HAS_SHIFT) shift += bzi * sShift;
  const int bm = byi * 256, bn = bxi * 256;
  __shared__ __align__(16) u16 smem[65536];   // 2 slots x 64KB
  __shared__ float psum[4][256];
  __shared__ float psumq[4][256];
  __shared__ float invs[256];
  const int tid = threadIdx.x;
  const int lane = tid & 63, wave = tid >> 6;
  const int wr = wave >> 2, wc = wave & 3;       // 2M x 4N waves
  const int lr = lane & 15, q = lane >> 4;
  f32x4 acc[8][4] = {};

  if (HAS_CSP) {
    if (tid < 256) {
      float ssum = 0.f;
      #pragma unroll
      for (int xx = 0; xx < 4; xx++) ssum += cs[xx * 4096 + bn + tid];
      invs[tid] = 1.0f / ssum;
    }
    wait_vmcnt<0>();
    __builtin_amdgcn_sched_barrier(0);
  }

  const int srow = 32 * wave + (lane >> 2);
  const int sk = (((lane & 3) ^ ((lane >> 3) & 3))) * 8;
  const u16* Abase = A + ((long)bm + srow) * K + sk;
  const u16* Bbase = B + ((long)bn + srow) * K + sk;
  const int rswz = (q ^ ((lr >> 1) & 3)) * 8;
  const int aoff = (wr * 128 + lr) * 32 + rswz;
  const int boff = 16384 + (wc * 64 + lr) * 32 + rswz;

#define SA(T_, KK_) { const u16* g_ = Abase + (long)(T_) * 64 + (KK_) * 32; \
    u16* d_ = &smem[(((T_) & 1)) * 32768 + (KK_) * 8192 + wave * 1024]; \
    gload16(g_, d_); gload16(g_ + 16 * (long)K, d_ + 512); }
#define SB(T_, KK_) { const u16* g_ = Bbase + (long)(T_) * 64 + (KK_) * 32; \
    u16* d_ = &smem[(((T_) & 1)) * 32768 + 16384 + (KK_) * 8192 + wave * 1024]; \
    gload16(g_, d_); gload16(g_ + 16 * (long)K, d_ + 512); }
#define CQ(SLOT, KK, RI0, LOADBV) { \
    const int qb_ = (SLOT) * 32768 + (KK) * 8192; \
    if (LOADBV) { \
      _Pragma("unroll") \
      for (int ci_ = 0; ci_ < 4; ci_++) \
        bv[ci_] = *(const short8*)&smem[qb_ + boff + ci_ * 512]; \
    } \
    short8 av_[4]; \
    _Pragma("unroll") \
    for (int r_ = 0; r_ < 4; r_++) \
      av_[r_] = *(const short8*)&smem[qb_ + aoff + ((RI0) + r_) * 512]; \
    __builtin_amdgcn_s_setprio(1); \
    _Pragma("unroll") \
    for (int r_ = 0; r_ < 4; r_++) \
      _Pragma("unroll") \
      for (int ci_ = 0; ci_ < 4; ci_++) \
        acc[(RI0) + r_][ci_] = __builtin_amdgcn_mfma_f32_16x16x32_bf16( \
            av_[r_], bv[ci_], acc[(RI0) + r_][ci_], 0, 0, 0); \
    __builtin_amdgcn_s_setprio(0); }
#define PH(VM, STG, SLOT, KK, RI0, LOADBV) \
    STG; wait_vmcnt<VM>(); phase_begin(); CQ(SLOT, KK, RI0, LOADBV); phase_end();

  const int niter2 = K >> 7;
  short8 bv[4];

  SA(0, 0); SB(0, 0); SA(0, 1); SB(0, 1); SA(1, 0); SB(1, 0);

  for (int u = 0; u < niter2 - 1; ++u) {
    const int t1 = 2 * u + 1, t2 = 2 * u + 2, t3 = 2 * u + 3;
    PH(10, SA(t1, 1), 0, 0, 0, 1)
    PH(10, SB(t1, 1), 0, 0, 4, 0)
    PH(10, SA(t2, 0), 0, 1, 0, 1)
    PH(10, SB(t2, 0), 0, 1, 4, 0)
    PH(10, SA(t2, 1), 1, 0, 0, 1)
    PH(10, SB(t2, 1), 1, 0, 4, 0)
    PH(10, SA(t3, 0), 1, 1, 0, 1)
    PH(10, SB(t3, 0), 1, 1, 4, 0)
  }
  {
    const int t1 = 2 * (niter2 - 1) + 1;
    PH(10, SA(t1, 1), 0, 0, 0, 1)
    PH(10, SB(t1, 1), 0, 0, 4, 0)
    PH(8,  ((void)0), 0, 1, 0, 1)
    PH(6,  ((void)0), 0, 1, 4, 0)
    PH(4,  ((void)0), 1, 0, 0, 1)
    PH(2,  ((void)0), 1, 0, 4, 0)
    PH(0,  ((void)0), 1, 1, 0, 1)
    PH(0,  ((void)0), 1, 1, 4, 0)
  }
#undef SA
#undef SB
#undef CQ
#undef PH

  __syncthreads();

  const int dr = (lane >> 4) * 4;
  float invc[4];
  if (HAS_CSP) {
    #pragma unroll
    for (int ci = 0; ci < 4; ci++) invc[ci] = invs[wc * 64 + ci * 16 + lr];
  }
  float rowsum[8][4], rowsq[8][4];
  if (HAS_EXP || HAS_PSUM2) {
    #pragma unroll
    for (int ri = 0; ri < 8; ri++)
      #pragma unroll
      for (int r = 0; r < 4; r++) { rowsum[ri][r] = 0.f; rowsq[ri][r] = 0.f; }
  }
  #pragma unroll
  for (int ri = 0; ri < 8; ri++) {
    const int rowl = wr * 128 + ri * 16 + dr;
    const int rowb = bm + rowl;
    float bvs[4] = {0.f, 0.f, 0.f, 0.f};
    float shv[4] = {0.f, 0.f, 0.f, 0.f};
    if (HAS_BIAS) {
      #pragma unroll
      for (int r = 0; r < 4; r++) bvs[r] = bias[rowb + r];
    }
    if (HAS_SHIFT) {
      #pragma unroll
      for (int r = 0; r < 4; r++) shv[r] = shift[rowb + r];
    }
    #pragma unroll
    for (int ci = 0; ci < 4; ci++) {
      const int coll = wc * 64 + ci * 16 + lr;
      float v[4];
      #pragma unroll
      for (int r = 0; r < 4; r++) {
        float tv = acc[ri][ci][r] * scale;
        if (HAS_CSP) tv *= invc[ci];
        if (HAS_SHIFT) tv -= shv[r];
        if (HAS_BIAS) tv += bvs[r];
        if (HAS_EXP) tv = __expf(tv);
        if (HAS_EXP || HAS_PSUM2) rowsum[ri][r] += tv;
        if (HAS_PSUM2) rowsq[ri][r] += tv * tv;
        v[r] = tv;
      }
      if (OM == 1) {
        u16x4 w;
        #pragma unroll
        for (int r = 0; r < 4; r++) w[r] = f2bf(v[r]);
        unsigned bo = (unsigned)((coll * 256 + rowl) * 2) ^ ((coll & 7) << 4);
        *(u16x4*)((char*)smem + bo) = w;
      } else {
        #pragma unroll
        for (int r = 0; r < 4; r++) {
          const int row = rowl + r;
          smem[row * 256 + (coll ^ (((row >> 2) & 3) << 4))] = f2bf(v[r]);
        }
      }
    }
  }
  if (HAS_EXP || HAS_PSUM2) {
    #pragma unroll
    for (int msk = 1; msk < 16; msk <<= 1)
      #pragma unroll
      for (int ri = 0; ri < 8; ri++)
        #pragma unroll
        for (int r = 0; r < 4; r++) {
          rowsum[ri][r] += __shfl_xor(rowsum[ri][r], msk);
          if (HAS_PSUM2) rowsq[ri][r] += __shfl_xor(rowsq[ri][r], msk);
        }
    if ((lane & 15) == 0) {
      #pragma unroll
      for (int ri = 0; ri < 8; ri++)
        #pragma unroll
        for (int r = 0; r < 4; r++) {
          psum[wc][wr * 128 + ri * 16 + dr + r] = rowsum[ri][r];
          if (HAS_PSUM2) psumq[wc][wr * 128 + ri * 16 + dr + r] = rowsq[ri][r];
        }
    }
  }
  __syncthreads();
  u16* C = (u16*)Cv + bzi * sC;
  if (OM == 1) {
    #pragma unroll
    for (int i = 0; i < 16; i++) {
      const int chunk = i * 512 + tid;
      const int coll = chunk >> 5, rq = chunk & 31;
      unsigned bo = (unsigned)(coll * 512 + rq * 16) ^ ((coll & 7) << 4);
      uint4 w = *(const uint4*)((const char*)smem + bo);
      *(uint4*)(C + (long)(bn + coll) * M + bm + rq * 8) = w;
    }
  } else {
    #pragma unroll
    for (int i = 0; i < 16; i++) {
      const int chunk = i * 512 + tid;
      const int row = chunk >> 5, cq = chunk & 31;
      const int cbase = (cq * 8) ^ (((row >> 2) & 3) << 4);
      uint4 w = *(const uint4*)(smem + row * 256 + cbase);
      *(uint4*)(C + (long)(bm + row) * N + bn + cq * 8) = w;
    }
  }
  if ((HAS_EXP || HAS_PSUM2) && tid < 256) {
    const int gX = XSWZ ? 4 : gridDim.x;
    if (HAS_EXP)
      psum_out[((long)bzi * gX + bxi) * 4096 + bm + tid] =
          psum[0][tid] + psum[1][tid] + psum[2][tid] + psum[3][tid];
    if (HAS_PSUM2) {
      const int gY = XSWZ ? 16 : gridDim.y;
      const long blk = ((long)bzi * gY + byi) * gX + bxi;
      psum_out[blk * 512 + tid] =
          psum[0][tid] + psum[1][tid] + psum[2][tid] + psum[3][tid];
      psum_out[blk * 512 + 256 + tid] =
          psumq[0][tid] + psumq[1][tid] + psumq[2][tid] + psumq[3][tid];
    }
  }
}

// ---------------- 128x128 GEMM (merged phi+g) ----------------
template<int OM, bool HAS_BIAS, bool HAS_CS, bool HAS_SHIFT, bool HAS_EXP,
         bool HAS_PSUM2, bool HAS_CSP>
__global__ __launch_bounds__(256)
void gemm_tn(const u16* __restrict__ A, const u16* __restrict__ B,
             void* __restrict__ Cv, void* __restrict__ Cv2,
             const float* __restrict__ bias, const float* __restrict__ bias2,
             long sBias,
             const float* __restrict__ cs, long sCS,
             const float* __restrict__ shift, long sShift,
             float* __restrict__ psum_out,
             float scale, int M, int N, int K, long sA, long sB, long sC)
{
  A += blockIdx.z * sA;
  B += blockIdx.z * sB;
  if (HAS_BIAS) bias += blockIdx.z * sBias;
  if (HAS_CS || HAS_CSP) cs += blockIdx.z * sCS;
  if (HAS_SHIFT) shift += blockIdx.z * sShift;
  const int bm = blockIdx.y * 128;
  const int bn = blockIdx.x * 128;
  __shared__ __align__(16) u16 smem[128 * 128];
  u16* As = smem;
  u16* Bs = smem + 128 * 64;
  __shared__ float psum[4][128];
  const int tid = threadIdx.x;
  const int lane = tid & 63;
  const int wave = tid >> 6;
  const int wm = (wave >> 1) * 64;
  const int wn = (wave & 1) * 64;
  const int lr = lane & 15;
  const int q  = lane >> 4;
  const int sxor = lane & 7;
  const bool gps = (OM == 3) && (bm >= 512);
  f32x4 acc[4][4] = {};

  if (HAS_CSP) {
    if (tid < 128) {
      float s = 0.f;
      #pragma unroll
      for (int xx = 0; xx < 8; xx++) s += cs[xx * 4096 + bn + tid];
      psum[0][tid] = 1.0f / s;
    }
  }

  const int swz = ((lane & 7) ^ (lane >> 3)) * 8;
  const long grow = 32 * wave + (lane >> 3);
  const u16* Ag = A + ((long)bm + grow) * K + swz;
  const u16* Bg = B + ((long)bn + grow) * K + swz;

  for (int kt = 0; kt < K; kt += 64) {
    __syncthreads();
    #pragma unroll
    for (int i = 0; i < 4; i++) {
      gload16(Ag + (long)(8 * i) * K + kt, &As[(wave * 4 + i) * 512]);
      gload16(Bg + (long)(8 * i) * K + kt, &Bs[(wave * 4 + i) * 512]);
    }
    __syncthreads();
    #pragma unroll
    for (int kk = 0; kk < 2; kk++) {
      short8 av[4], bv[4];
      #pragma unroll
      for (int mi = 0; mi < 4; mi++)
        av[mi] = *(const short8*)&As[(wm + mi * 16 + lr) * 64 +
                                     (((kk << 2) + q) ^ sxor) * 8];
      #pragma unroll
      for (int ni = 0; ni < 4; ni++)
        bv[ni] = *(const short8*)&Bs[(wn + ni * 16 + lr) * 64 +
                                     (((kk << 2) + q) ^ sxor) * 8];
      #pragma unroll
      for (int mi = 0; mi < 4; mi++) {
        #pragma unroll
        for (int ni = 0; ni < 4; ni++)
          acc[mi][ni] = __builtin_amdgcn_mfma_f32_16x16x32_bf16(
              av[mi], bv[ni], acc[mi][ni], 0, 0, 0);
      }
    }
  }

  float invc[4];
  if (HAS_CSP) {
    #pragma unroll
    for (int ni = 0; ni < 4; ni++) invc[ni] = psum[0][wn + ni * 16 + lr];
  }
  __syncthreads();
  const int dr = (lane >> 4) * 4;
  const bool trans_out = (OM == 1) || (OM == 3 && !gps);
  float rowsum[4][4];
  float rowsq[4][4];
  if (HAS_EXP || HAS_PSUM2 || gps) {
    #pragma unroll
    for (int mi = 0; mi < 4; mi++)
      #pragma unroll
      for (int r = 0; r < 4; r++) { rowsum[mi][r] = 0.f; rowsq[mi][r] = 0.f; }
  }
  const float* bp = (OM == 3 && gps) ? bias2 - 512 : bias;
  #pragma unroll
  for (int mi = 0; mi < 4; mi++) {
    const int rowl = wm + mi * 16 + dr;
    const int rowb = bm + rowl;
    float bvs[4] = {0.f, 0.f, 0.f, 0.f};
    float shv[4] = {0.f, 0.f, 0.f, 0.f};
    if (HAS_BIAS) {
      #pragma unroll
      for (int r = 0; r < 4; r++) bvs[r] = bp[rowb + r];
    }
    if (HAS_SHIFT) {
      #pragma unroll
      for (int r = 0; r < 4; r++) shv[r] = shift[rowb + r];
    }
    #pragma unroll
    for (int ni = 0; ni < 4; ni++) {
      const int coll = wn + ni * 16 + lr;
      const float csv = HAS_CSP ? invc[ni] : (HAS_CS ? cs[bn + coll] : 1.0f);
      float v[4];
      #pragma unroll
      for (int r = 0; r < 4; r++) {
        float t = acc[mi][ni][r] * scale;
        if (HAS_CS || HAS_CSP) t *= csv;
        if (HAS_SHIFT) t -= shv[r];
        if (HAS_BIAS) t += bvs[r];
        if (HAS_EXP) t = __expf(t);
        if (HAS_EXP || HAS_PSUM2 || gps) rowsum[mi][r] += t;
        if (HAS_PSUM2) rowsq[mi][r] += t * t;
        v[r] = t;
      }
      if (trans_out) {
        u16x4 w;
        #pragma unroll
        for (int r = 0; r < 4; r++) w[r] = f2bf(v[r]);
        unsigned bo = (unsigned)((coll * 128 + rowl) * 2) ^ ((coll & 7) << 4);
        *(u16x4*)((char*)smem + bo) = w;
      } else {
        #pragma unroll
        for (int r = 0; r < 4; r++) {
          const int row = rowl + r;
          smem[row * 128 + (coll ^ (((row >> 2) & 3) << 4))] = f2bf(v[r]);
        }
      }
    }
  }
  if (HAS_EXP || HAS_PSUM2 || gps) {
    #pragma unroll
    for (int msk = 1; msk < 16; msk <<= 1)
      #pragma unroll
      for (int mi = 0; mi < 4; mi++)
        #pragma unroll
        for (int r = 0; r < 4; r++) {
          rowsum[mi][r] += __shfl_xor(rowsum[mi][r], msk);
          if (HAS_PSUM2) rowsq[mi][r] += __shfl_xor(rowsq[mi][r], msk);
        }
    if ((lane & 15) == 0) {
      #pragma unroll
      for (int mi = 0; mi < 4; mi++)
        #pragma unroll
        for (int r = 0; r < 4; r++) {
          psum[wave & 1][wm + mi * 16 + dr + r] = rowsum[mi][r];
          if (HAS_PSUM2) psum[2 + (wave & 1)][wm + mi * 16 + dr + r] = rowsq[mi][r];
        }
    }
  }
  __syncthreads();
  if (trans_out) {
    const int Ms = (OM == 3) ? 512 : M;
    u16* C = (u16*)Cv + blockIdx.z * sC;
    #pragma unroll
    for (int i = 0; i < 8; i++) {
      const int chunk = i * 256 + tid;
      const int coll = chunk >> 4, rq = chunk & 15;
      unsigned bo = (unsigned)(coll * 256 + rq * 16) ^ ((coll & 7) << 4);
      uint4 w = *(const uint4*)((const char*)smem + bo);
      *(uint4*)(C + (long)(bn + coll) * Ms + bm + rq * 8) = w;
    }
  } else {
    u16* C = (OM == 3) ? (u16*)Cv2 + blockIdx.z * sC : (u16*)Cv + blockIdx.z * sC;
    const int rbase = (OM == 3) ? bm - 512 : bm;
    #pragma unroll
    for (int i = 0; i < 8; i++) {
      const int chunk = i * 256 + tid;
      const int row = chunk >> 4, cq = chunk & 15;
      const int cbase = (cq * 8) ^ (((row >> 2) & 3) << 4);
      uint4 w = *(const uint4*)(smem + row * 128 + cbase);
      *(uint4*)(C + (long)(rbase + row) * N + bn + cq * 8) = w;
    }
  }
  if (HAS_EXP || HAS_PSUM2 || gps) {
    if (tid < 128) {
      if (HAS_EXP)
        psum_out[((long)blockIdx.z * gridDim.x + blockIdx.x) * 4096 + bm + tid] =
            psum[0][tid] + psum[1][tid];
      if (HAS_PSUM2) {
        const long blk = ((long)blockIdx.z * gridDim.y + blockIdx.y) * gridDim.x
                         + blockIdx.x;
        psum_out[blk * 256 + tid] = psum[0][tid] + psum[1][tid];
        psum_out[blk * 256 + 128 + tid] = psum[2][tid] + psum[3][tid];
      }
      if (gps)
        psum_out[((long)blockIdx.z * gridDim.x + blockIdx.x) * 512 +
                 (bm - 512) + tid] = psum[0][tid] + psum[1][tid];
    }
  }
}

// --- c0[b][c] = out_b[c] + sum_d out_w_f32[c][d]*gbar[b][d] ; gbar inline --
__global__ __launch_bounds__(256) void c0_kernel(const float* __restrict__ out_w,
                                                 const float* __restrict__ out_b,
                                                 const float* __restrict__ g_ps,
                                                 float* __restrict__ gbar,
                                                 float* __restrict__ c0) {
  const int idx = blockIdx.x * 4 + (threadIdx.x >> 6);   // 0..8191 = b*1024+c
  const int lane = threadIdx.x & 63;
  const int b = idx >> 10, c = idx & 1023;
  const int d0 = lane * 8;
  float g8[8] = {0.f, 0.f, 0.f, 0.f, 0.f, 0.f, 0.f, 0.f};
  #pragma unroll
  for (int xx = 0; xx < 8; xx++) {
    const float* p = g_ps + ((long)b * 8 + xx) * 512 + d0;
    float4 a0 = *(const float4*)p;
    float4 a1 = *(const float4*)(p + 4);
    g8[0] += a0.x; g8[1] += a0.y; g8[2] += a0.z; g8[3] += a0.w;
    g8[4] += a1.x; g8[5] += a1.y; g8[6] += a1.z; g8[7] += a1.w;
  }
  #pragma unroll
  for (int k = 0; k < 8; k++) g8[k] *= (1.0f / 1024.0f);
  if (c == 0) {
    float4 o0, o1;
    o0.x = g8[0]; o0.y = g8[1]; o0.z = g8[2]; o0.w = g8[3];
    o1.x = g8[4]; o1.y = g8[5]; o1.z = g8[6]; o1.w = g8[7];
    *(float4*)(gbar + (long)b * 512 + d0) = o0;
    *(float4*)(gbar + (long)b * 512 + d0 + 4) = o1;
  }
  float4 w0 = *(const float4*)(out_w + (long)c * DI + d0);
  float4 w1 = *(const float4*)(out_w + (long)c * DI + d0 + 4);
  float s = w0.x * g8[0] + w0.y * g8[1] + w0.z * g8[2] + w0.w * g8[3]
          + w1.x * g8[4] + w1.y * g8[5] + w1.z * g8[6] + w1.w * g8[7];
  #pragma unroll
  for (int off = 32; off > 0; off >>= 1) s += __shfl_xor(s, off);
  if (lane == 0) c0[idx] = out_b[c] + s;
}

// ------ BN stats (from y-GEMM partials) + apply + residual, fused --------
__global__ __launch_bounds__(256) void final_kernel(const u16* __restrict__ dy,
    const float* __restrict__ x, const float* __restrict__ partial,
    const float* __restrict__ c0,
    const float* __restrict__ bnw, const float* __restrict__ bnb,
    float* __restrict__ out) {
  __shared__ float red[6];
  __shared__ float bcast[2];
  const int bc = blockIdx.x;
  const int co = bc & 1023;
  const int t = threadIdx.x;
  if (t < 128) {
    const int b2 = t >> 4, bx = t & 15;
    const int by = co >> 8, r = co & 255;
    const long blk = (((long)b2 * 4 + by) * 16 + bx) * 512;
    float s = partial[blk + r];
    float qq = partial[blk + 256 + r];
    #pragma unroll
    for (int off = 1; off < 16; off <<= 1) {
      s += __shfl_xor(s, off);
      qq += __shfl_xor(qq, off);
    }
    float sbc = c0[b2 * 1024 + co] * s;
    #pragma unroll
    for (int off = 16; off < 64; off <<= 1) {
      s += __shfl_xor(s, off);
      qq += __shfl_xor(qq, off);
      sbc += __shfl_xor(sbc, off);
    }
    if (t == 0)  { red[0] = s; red[1] = qq; red[2] = sbc; }
    if (t == 64) { red[3] = s; red[4] = qq; red[5] = sbc; }
  }
  __syncthreads();
  if (t == 0) {
    float sdT = red[0] + red[3], sd2T = red[1] + red[4], sbcT = red[2] + red[5];
    float sc0 = 0.f, sc02 = 0.f;
    #pragma unroll
    for (int bb = 0; bb < 8; bb++) {
      float c = c0[bb * 1024 + co];
      sc0 += c; sc02 += c * c;
    }
    float S = 4096.0f * sc0 + sdT;
    float S2 = 4096.0f * sc02 + 2.0f * sbcT + sd2T;
    float mean = S * (1.0f / 32768.0f);
    float var = S2 * (1.0f / 32768.0f) - mean * mean;
    float inv = rsqrtf(var + 1e-5f) * bnw[co];
    bcast[0] = inv;
    bcast[1] = bnb[co] - mean * inv + c0[bc] * inv;
  }
  __syncthreads();
  const float inv = bcast[0], addc = bcast[1];
  const long base = (long)bc * 4096;
  #pragma unroll
  for (int i = 0; i < 2; i++) {
    const long off = base + (long)(i * 256 + t) * 8;
    uint4 v = *(const uint4*)(dy + off);
    float f[8]; unpack8(v, f);
    const float4 x0 = *(const float4*)(x + off);
    const float4 x1 = *(const float4*)(x + off + 4);
    float4 o0, o1;
    o0.x = f[0] * inv + addc + x0.x;
    o0.y = f[1] * inv + addc + x0.y;
    o0.z = f[2] * inv + addc + x0.z;
    o0.w = f[3] * inv + addc + x0.w;
    o1.x = f[4] * inv + addc + x1.x;
    o1.y = f[5] * inv + addc + x1.y;
    o1.z = f[6] * inv + addc + x1.z;
    o1.w = f[7] * inv + addc + x1.w;
    *(float4*)(out + off) = o0;
    *(float4*)(out + off + 4) = o1;
  }
}

extern "C" void kernel_launch(void* const* d_in, const int* in_sizes, int n_in,
                              void* d_out, int out_size, void* d_ws, size_t ws_size,
                              hipStream_t stream) {
  (void)in_sizes; (void)n_in; (void)out_size; (void)ws_size;
  const float* x       = (const float*)d_in[0];
  const float* theta_w = (const float*)d_in[1];
  const float* theta_b = (const float*)d_in[2];
  const float* phi_w   = (const float*)d_in[3];
  const float* phi_b   = (const float*)d_in[4];
  const float* g_w     = (const float*)d_in[5];
  const float* g_b     = (const float*)d_in[6];
  const float* out_w   = (const float*)d_in[7];
  const float* out_b   = (const float*)d_in[8];
  const float* bn_w    = (const float*)d_in[9];
  const float* bn_b    = (const float*)d_in[10];
  float* out = (float*)d_out;
  char* ws = (char*)d_ws;
  const size_t MB = 1024 * 1024;

  // workspace layout
  u16* xT     = (u16*)(ws + 0 * MB);       // 64MB; later: dy bf16 [0,64MB)
  u16* poolT  = (u16*)(ws + 64 * MB);      // 16MB
  u16* w_th   = (u16*)(ws + 80 * MB);      // 1MB
  u16* w_ph   = (u16*)(ws + 81 * MB);      // 1MB  (w_ph || w_g contiguous)
  u16* w_g    = (u16*)(ws + 82 * MB);      // 1MB
  u16* thetaT = (u16*)(ws + 84 * MB);      // 32MB
  u16* phiT   = (u16*)(ws + 116 * MB);     // 8MB
  u16* g_n    = (u16*)(ws + 124 * MB);     // 8MB
  u16* e      = (u16*)(ws + 132 * MB);     // 64MB (exp(scores))
  u16* tT     = (u16*)(ws + 196 * MB);     // 32MB (delta-t bf16)
  u16* w_out  = (u16*)(ws + 228 * MB);     // 1MB
  float* gbar  = (float*)(ws + 229 * MB);            // 16KB
  float* c0b   = (float*)(ws + 229 * MB + 16384);    // 32KB
  float* partial = (float*)(ws + 230 * MB);          // 512KB (8*4*4096 f32)
  float* partial2 = (float*)(ws + 231 * MB);         // 1MB (512 blk * 512 f32)
  float* g_ps = (float*)(ws + 233 * MB);             // 128KB (8*8*512 f32)
  u16* dy = xT;               // alias: x_T dead after theta GEMM

  // 1. prep: weights->bf16 + x->x_T + pool (single launch)
  prep_kernel<<<6144, 256, 0, stream>>>(x, xT, poolT,
                                        theta_w, phi_w, g_w, out_w,
                                        w_th, w_ph, w_g, w_out);
  // 2. theta -> theta_T [b][4096][512]  (256-tile 8-phase GEMM)
  gemm256<1, true, false, false, false, false, false>
      <<<dim3(16, 2, 8), 512, 0, stream>>>(
      w_th, xT, thetaT, theta_b, 0L, nullptr, 0L, nullptr, 0L, nullptr,
      1.0f, 512, 4096, 1024, 0L, (long)NPIX * CIN, (long)NPIX * DI);
  // 3. merged phi+g GEMM (128-tile kernel) -> phiT, g_n, g_ps
  gemm_tn<3, true, false, false, false, false, false>
      <<<dim3(8, 8, 8), 256, 0, stream>>>(
      w_ph, poolT, phiT, g_n, phi_b, g_b, 0L, nullptr, 0L, nullptr, 0L,
      g_ps, 1.0f, 1024, 1024, 1024, 0L, (long)MPIX * CIN, (long)MPIX * DI);
  // 4. c0 (computes gbar inline from g_ps; writes gbar for t-GEMM)
  c0_kernel<<<2048, 256, 0, stream>>>(out_w, out_b, g_ps, gbar, c0b);
  // 5. e[n][m] = exp(scores) + rowsum partials; XCD-swizzled flat launch
  gemm256<0, false, false, true, false, false, true>
      <<<512, 512, 0, stream>>>(
      thetaT, phiT, e, nullptr, 0L, nullptr, 0L, nullptr, 0L, partial,
      0.044194173824159216f, 4096, 1024, 512,
      (long)NPIX * DI, (long)MPIX * DI, (long)NPIX * MPIX);
  // 6. delta-t = (g_n * e^T)*inv[n] - gbar[d]; inv from partials (CSP)
  gemm256<1, false, true, false, false, true, false>
      <<<dim3(16, 2, 8), 512, 0, stream>>>(
      g_n, e, tT, nullptr, 0L, partial, 16384L, gbar, 512L, nullptr,
      1.0f, 512, 4096, 1024,
      (long)DI * MPIX, (long)NPIX * MPIX, (long)NPIX * DI);
  // 7. dy = out_w * delta-t^T + BN partials (PSUM2)
  gemm256<0, false, false, false, true, false, false>
      <<<dim3(16, 4, 8), 512, 0, stream>>>(
      w_out, tT, dy, nullptr, 0L, nullptr, 0L, nullptr, 0L, partial2,
      1.0f, 1024, 4096, 512, 0L, (long)NPIX * DI, (long)1024 * NPIX);
  // 8. BN stats (from partials, in-block) + apply + residual
  final_kernel<<<8192, 256, 0, stream>>>(dy, x, partial2, c0b, bn_w, bn_b, out);
}

// Round 15
// 327.244 us; speedup vs baseline: 1.0534x; 1.0160x over previous
//
#include <hip/hip_runtime.h>
#include <cstdint>

typedef unsigned short u16;
typedef __attribute__((ext_vector_type(4))) unsigned short u16x4;
typedef __attribute__((ext_vector_type(8))) short short8;
typedef __attribute__((ext_vector_type(4))) float f32x4;

#define DI 512
#define CIN 1024
#define NPIX 4096   // 64*64
#define MPIX 1024   // 32*32

__device__ __forceinline__ float bf2f(u16 u) {
  union { unsigned int i; float f; } v; v.i = ((unsigned int)u) << 16; return v.f;
}
__device__ __forceinline__ u16 f2bf(float f) {
  union { float f; unsigned int i; } v; v.f = f;
  unsigned int r = v.i + 0x7fffu + ((v.i >> 16) & 1u);
  return (u16)(r >> 16);
}
__device__ __forceinline__ void unpack8(uint4 v, float* f) {
  union { unsigned int i; float f; } u;
  u.i = v.x << 16;          f[0] = u.f;
  u.i = v.x & 0xffff0000u;  f[1] = u.f;
  u.i = v.y << 16;          f[2] = u.f;
  u.i = v.y & 0xffff0000u;  f[3] = u.f;
  u.i = v.z << 16;          f[4] = u.f;
  u.i = v.z & 0xffff0000u;  f[5] = u.f;
  u.i = v.w << 16;          f[6] = u.f;
  u.i = v.w & 0xffff0000u;  f[7] = u.f;
}

// async global->LDS, 16B per lane, wave-uniform LDS base + lane*16
__device__ __forceinline__ void gload16(const u16* g, u16* l) {
  __builtin_amdgcn_global_load_lds(
      (const __attribute__((address_space(1))) void*)g,
      (__attribute__((address_space(3))) void*)l, 16, 0, 0);
}

template<int N> __device__ __forceinline__ void wait_vmcnt() {
  asm volatile("s_waitcnt vmcnt(%0)" :: "n"(N) : "memory");
}

// ---- prep: blocks [0,4096): x -> x_T + 2x2 maxpool; [4096,6144): cvt ----
__global__ __launch_bounds__(256) void prep_kernel(
    const float* __restrict__ x, u16* __restrict__ xT, u16* __restrict__ poolT,
    const float* __restrict__ s0, const float* __restrict__ s1,
    const float* __restrict__ s2, const float* __restrict__ s3,
    u16* __restrict__ d0, u16* __restrict__ d1,
    u16* __restrict__ d2, u16* __restrict__ d3) {
  __shared__ u16 tile[64][136];
  const int blk = blockIdx.x;
  const int t = threadIdx.x;
  if (blk >= 4096) {                       // weight f32 -> bf16 convert
    int i = (blk - 4096) * 256 + t;        // 0 .. 4*131072
    int sel = i >> 17;
    int j = i & 131071;
    const float* src = sel == 0 ? s0 : sel == 1 ? s1 : sel == 2 ? s2 : s3;
    u16* dst = sel == 0 ? d0 : sel == 1 ? d1 : sel == 2 ? d2 : d3;
    float4 v = *(const float4*)(src + (long)j * 4);
    u16x4 w;
    w[0] = f2bf(v.x); w[1] = f2bf(v.y); w[2] = f2bf(v.z); w[3] = f2bf(v.w);
    *(u16x4*)(dst + (long)j * 4) = w;
    return;
  }
  const int bx = blk & 31, by = (blk >> 5) & 15, b = blk >> 9;
  const int n0 = bx * 128, c0 = by * 64;
  const float* xb = x + (long)b * CIN * NPIX;
  u16* xTb = xT + (long)b * NPIX * CIN;
  const int tc = t >> 5, tn = (t & 31) * 4;
  #pragma unroll
  for (int i = 0; i < 8; i++) {
    int c = tc + i * 8;
    float4 v = *(const float4*)(xb + (long)(c0 + c) * NPIX + n0 + tn);
    u16x4 w;
    w[0] = f2bf(v.x); w[1] = f2bf(v.y); w[2] = f2bf(v.z); w[3] = f2bf(v.w);
    *(u16x4*)&tile[c][tn] = w;
  }
  __syncthreads();
  const int tn2 = t >> 4, tc2 = (t & 15) * 4;
  #pragma unroll
  for (int i = 0; i < 8; i++) {
    int n = tn2 + i * 16;
    u16x4 w;
    w[0] = tile[tc2 + 0][n];
    w[1] = tile[tc2 + 1][n];
    w[2] = tile[tc2 + 2][n];
    w[3] = tile[tc2 + 3][n];
    *(u16x4*)(xTb + (long)(n0 + n) * CIN + c0 + tc2) = w;
  }
  const int j = t & 31, g = t >> 5;
  u16 r[8] __attribute__((aligned(16)));
  #pragma unroll
  for (int k = 0; k < 8; k++) {
    const int c = g * 8 + k;
    const unsigned w0 = *(const unsigned*)&tile[c][2 * j];
    const unsigned w1 = *(const unsigned*)&tile[c][64 + 2 * j];
    float m0 = fmaxf(bf2f((u16)(w0 & 0xffffu)), bf2f((u16)(w0 >> 16)));
    float m1 = fmaxf(bf2f((u16)(w1 & 0xffffu)), bf2f((u16)(w1 >> 16)));
    r[k] = f2bf(fmaxf(m0, m1));
  }
  *(uint4*)(poolT + ((long)b * MPIX + bx * 32 + j) * CIN + c0 + g * 8) =
      *(uint4*)r;
}

// =============== 256x256-tile GEMM, 8 waves, 8-phase counted-vmcnt =======
// m201-faithful phase: {ds_reads(p) | stage | vmcnt(8) | BAR | lgkm(0) |
// setprio MFMA | BAR}. Reads certified by PREVIOUS phase's vmcnt(8)
// (derivation: per-wave FIFO, 2 gloads/stage-op; vmcnt(8) leaves last 4
// stage-ops outstanding; consumed quarter staged 5-6 ops back).
// Tail vmcnts [8,8,8,4,4,0,0,0].
template<int OM, bool HAS_BIAS, bool HAS_SHIFT, bool HAS_EXP, bool HAS_PSUM2,
         bool HAS_CSP, bool XSWZ>
__global__ __launch_bounds__(512, 2)
void gemm256(const u16* __restrict__ A, const u16* __restrict__ B,
             void* __restrict__ Cv,
             const float* __restrict__ bias, long sBias,
             const float* __restrict__ cs, long sCS,
             const float* __restrict__ shift, long sShift,
             float* __restrict__ psum_out,
             float scale, int M, int N, int K, long sA, long sB, long sC)
{
  int bxi, byi, bzi;
  if (XSWZ) {
    const int q = blockIdx.x >> 5, s = blockIdx.x & 31;
    bxi = s >> 3;                       // 0..3
    const int yz = q * 8 + (s & 7);     // 0..127
    byi = yz & 15;
    bzi = yz >> 4;
  } else {
    bxi = blockIdx.x; byi = blockIdx.y; bzi = blockIdx.z;
  }
  A += bzi * sA;
  B += bzi * sB;
  if (HAS_BIAS) bias += bzi * sBias;
  if (HAS_CSP) cs += bzi * sCS;
  if (HAS_SHIFT) shift += bzi * sShift;
  const int bm = byi * 256, bn = bxi * 256;
  __shared__ __align__(16) u16 smem[65536];   // 2 slots x 64KB
  __shared__ float psum[4][256];
  __shared__ float psumq[4][256];
  __shared__ float invs[256];
  const int tid = threadIdx.x;
  const int lane = tid & 63, wave = tid >> 6;
  const int wr = wave >> 2, wc = wave & 3;       // 2M x 4N waves
  const int lr = lane & 15, q = lane >> 4;
  f32x4 acc[8][4] = {};

  if (HAS_CSP) {
    if (tid < 256) {
      float ssum = 0.f;
      #pragma unroll
      for (int xx = 0; xx < 4; xx++) ssum += cs[xx * 4096 + bn + tid];
      invs[tid] = 1.0f / ssum;
    }
    wait_vmcnt<0>();
    __builtin_amdgcn_sched_barrier(0);
  }

  const int srow = 32 * wave + (lane >> 2);
  const int sk = (((lane & 3) ^ ((lane >> 3) & 3))) * 8;
  const u16* Abase = A + ((long)bm + srow) * K + sk;
  const u16* Bbase = B + ((long)bn + srow) * K + sk;
  const int rswz = (q ^ ((lr >> 1) & 3)) * 8;
  const int aoff = (wr * 128 + lr) * 32 + rswz;
  const int boff = 16384 + (wc * 64 + lr) * 32 + rswz;

#define SA(T_, KK_) { const u16* g_ = Abase + (long)(T_) * 64 + (KK_) * 32; \
    u16* d_ = &smem[(((T_) & 1)) * 32768 + (KK_) * 8192 + wave * 1024]; \
    gload16(g_, d_); gload16(g_ + 16 * (long)K, d_ + 512); }
#define SB(T_, KK_) { const u16* g_ = Bbase + (long)(T_) * 64 + (KK_) * 32; \
    u16* d_ = &smem[(((T_) & 1)) * 32768 + 16384 + (KK_) * 8192 + wave * 1024]; \
    gload16(g_, d_); gload16(g_ + 16 * (long)K, d_ + 512); }
#define PH(VM, STG, SLOT, KK, RI0, LOADBV) { \
    const int qb_ = (SLOT) * 32768 + (KK) * 8192; \
    short8 av_[4]; \
    if (LOADBV) { \
      _Pragma("unroll") \
      for (int ci_ = 0; ci_ < 4; ci_++) \
        bv[ci_] = *(const short8*)&smem[qb_ + boff + ci_ * 512]; \
    } \
    _Pragma("unroll") \
    for (int r_ = 0; r_ < 4; r_++) \
      av_[r_] = *(const short8*)&smem[qb_ + aoff + ((RI0) + r_) * 512]; \
    STG; \
    wait_vmcnt<VM>(); \
    __builtin_amdgcn_s_barrier(); \
    asm volatile("s_waitcnt lgkmcnt(0)" ::: "memory"); \
    __builtin_amdgcn_sched_barrier(0); \
    __builtin_amdgcn_s_setprio(1); \
    _Pragma("unroll") \
    for (int r_ = 0; r_ < 4; r_++) \
      _Pragma("unroll") \
      for (int ci_ = 0; ci_ < 4; ci_++) \
        acc[(RI0) + r_][ci_] = __builtin_amdgcn_mfma_f32_16x16x32_bf16( \
            av_[r_], bv[ci_], acc[(RI0) + r_][ci_], 0, 0, 0); \
    __builtin_amdgcn_s_setprio(0); \
    __builtin_amdgcn_sched_barrier(0); \
    __builtin_amdgcn_s_barrier(); \
    __builtin_amdgcn_sched_barrier(0); }

  const int niter2 = K >> 7;
  short8 bv[4];

  // prologue: 6 stage-ops (12 loads); vmcnt(8) certifies S1,S2 for ph0 reads
  SA(0, 0); SB(0, 0); SA(0, 1); SB(0, 1); SA(1, 0); SB(1, 0);
  wait_vmcnt<8>();
  __builtin_amdgcn_s_barrier();
  __builtin_amdgcn_sched_barrier(0);

  for (int u = 0; u < niter2 - 1; ++u) {
    const int t1 = 2 * u + 1, t2 = 2 * u + 2, t3 = 2 * u + 3;
    PH(8, SA(t1, 1), 0, 0, 0, 1)
    PH(8, SB(t1, 1), 0, 0, 4, 0)
    PH(8, SA(t2, 0), 0, 1, 0, 1)
    PH(8, SB(t2, 0), 0, 1, 4, 0)
    PH(8, SA(t2, 1), 1, 0, 0, 1)
    PH(8, SB(t2, 1), 1, 0, 4, 0)
    PH(8, SA(t3, 0), 1, 1, 0, 1)
    PH(8, SB(t3, 0), 1, 1, 4, 0)
  }
  {
    const int t1 = 2 * (niter2 - 1) + 1;
    PH(8, SA(t1, 1), 0, 0, 0, 1)
    PH(8, SB(t1, 1), 0, 0, 4, 0)
    PH(8, ((void)0), 0, 1, 0, 1)
    PH(4, ((void)0), 0, 1, 4, 0)
    PH(4, ((void)0), 1, 0, 0, 1)
    PH(0, ((void)0), 1, 0, 4, 0)
    PH(0, ((void)0), 1, 1, 0, 1)
    PH(0, ((void)0), 1, 1, 4, 0)
  }
#undef SA
#undef SB
#undef PH

  __syncthreads();

  const int dr = (lane >> 4) * 4;
  float invc[4];
  if (HAS_CSP) {
    #pragma unroll
    for (int ci = 0; ci < 4; ci++) invc[ci] = invs[wc * 64 + ci * 16 + lr];
  }
  float rowsum[8][4], rowsq[8][4];
  if (HAS_EXP || HAS_PSUM2) {
    #pragma unroll
    for (int ri = 0; ri < 8; ri++)
      #pragma unroll
      for (int r = 0; r < 4; r++) { rowsum[ri][r] = 0.f; rowsq[ri][r] = 0.f; }
  }
  #pragma unroll
  for (int ri = 0; ri < 8; ri++) {
    const int rowl = wr * 128 + ri * 16 + dr;
    const int rowb = bm + rowl;
    float bvs[4] = {0.f, 0.f, 0.f, 0.f};
    float shv[4] = {0.f, 0.f, 0.f, 0.f};
    if (HAS_BIAS) {
      #pragma unroll
      for (int r = 0; r < 4; r++) bvs[r] = bias[rowb + r];
    }
    if (HAS_SHIFT) {
      #pragma unroll
      for (int r = 0; r < 4; r++) shv[r] = shift[rowb + r];
    }
    #pragma unroll
    for (int ci = 0; ci < 4; ci++) {
      const int coll = wc * 64 + ci * 16 + lr;
      float v[4];
      #pragma unroll
      for (int r = 0; r < 4; r++) {
        float tv = acc[ri][ci][r] * scale;
        if (HAS_CSP) tv *= invc[ci];
        if (HAS_SHIFT) tv -= shv[r];
        if (HAS_BIAS) tv += bvs[r];
        if (HAS_EXP) tv = __expf(tv);
        if (HAS_EXP || HAS_PSUM2) rowsum[ri][r] += tv;
        if (HAS_PSUM2) rowsq[ri][r] += tv * tv;
        v[r] = tv;
      }
      if (OM == 1) {
        u16x4 w;
        #pragma unroll
        for (int r = 0; r < 4; r++) w[r] = f2bf(v[r]);
        unsigned bo = (unsigned)((coll * 256 + rowl) * 2) ^ ((coll & 7) << 4);
        *(u16x4*)((char*)smem + bo) = w;
      } else {
        #pragma unroll
        for (int r = 0; r < 4; r++) {
          const int row = rowl + r;
          smem[row * 256 + (coll ^ (((row >> 2) & 3) << 4))] = f2bf(v[r]);
        }
      }
    }
  }
  if (HAS_EXP || HAS_PSUM2) {
    #pragma unroll
    for (int msk = 1; msk < 16; msk <<= 1)
      #pragma unroll
      for (int ri = 0; ri < 8; ri++)
        #pragma unroll
        for (int r = 0; r < 4; r++) {
          rowsum[ri][r] += __shfl_xor(rowsum[ri][r], msk);
          if (HAS_PSUM2) rowsq[ri][r] += __shfl_xor(rowsq[ri][r], msk);
        }
    if ((lane & 15) == 0) {
      #pragma unroll
      for (int ri = 0; ri < 8; ri++)
        #pragma unroll
        for (int r = 0; r < 4; r++) {
          psum[wc][wr * 128 + ri * 16 + dr + r] = rowsum[ri][r];
          if (HAS_PSUM2) psumq[wc][wr * 128 + ri * 16 + dr + r] = rowsq[ri][r];
        }
    }
  }
  __syncthreads();
  u16* C = (u16*)Cv + bzi * sC;
  if (OM == 1) {
    #pragma unroll
    for (int i = 0; i < 16; i++) {
      const int chunk = i * 512 + tid;
      const int coll = chunk >> 5, rq = chunk & 31;
      unsigned bo = (unsigned)(coll * 512 + rq * 16) ^ ((coll & 7) << 4);
      uint4 w = *(const uint4*)((const char*)smem + bo);
      *(uint4*)(C + (long)(bn + coll) * M + bm + rq * 8) = w;
    }
  } else {
    #pragma unroll
    for (int i = 0; i < 16; i++) {
      const int chunk = i * 512 + tid;
      const int row = chunk >> 5, cq = chunk & 31;
      const int cbase = (cq * 8) ^ (((row >> 2) & 3) << 4);
      uint4 w = *(const uint4*)(smem + row * 256 + cbase);
      *(uint4*)(C + (long)(bm + row) * N + bn + cq * 8) = w;
    }
  }
  if ((HAS_EXP || HAS_PSUM2) && tid < 256) {
    const int gX = XSWZ ? 4 : gridDim.x;
    if (HAS_EXP)
      psum_out[((long)bzi * gX + bxi) * 4096 + bm + tid] =
          psum[0][tid] + psum[1][tid] + psum[2][tid] + psum[3][tid];
    if (HAS_PSUM2) {
      const int gY = XSWZ ? 16 : gridDim.y;
      const long blk = ((long)bzi * gY + byi) * gX + bxi;
      psum_out[blk * 512 + tid] =
          psum[0][tid] + psum[1][tid] + psum[2][tid] + psum[3][tid];
      psum_out[blk * 512 + 256 + tid] =
          psumq[0][tid] + psumq[1][tid] + psumq[2][tid] + psumq[3][tid];
    }
  }
}

// ---------------- 128x128 GEMM (merged phi+g) ----------------
template<int OM, bool HAS_BIAS, bool HAS_CS, bool HAS_SHIFT, bool HAS_EXP,
         bool HAS_PSUM2, bool HAS_CSP>
__global__ __launch_bounds__(256)
void gemm_tn(const u16* __restrict__ A, const u16* __restrict__ B,
             void* __restrict__ Cv, void* __restrict__ Cv2,
             const float* __restrict__ bias, const float* __restrict__ bias2,
             long sBias,
             const float* __restrict__ cs, long sCS,
             const float* __restrict__ shift, long sShift,
             float* __restrict__ psum_out,
             float scale, int M, int N, int K, long sA, long sB, long sC)
{
  A += blockIdx.z * sA;
  B += blockIdx.z * sB;
  if (HAS_BIAS) bias += blockIdx.z * sBias;
  if (HAS_CS || HAS_CSP) cs += blockIdx.z * sCS;
  if (HAS_SHIFT) shift += blockIdx.z * sShift;
  const int bm = blockIdx.y * 128;
  const int bn = blockIdx.x * 128;
  __shared__ __align__(16) u16 smem[128 * 128];
  u16* As = smem;
  u16* Bs = smem + 128 * 64;
  __shared__ float psum[4][128];
  const int tid = threadIdx.x;
  const int lane = tid & 63;
  const int wave = tid >> 6;
  const int wm = (wave >> 1) * 64;
  const int wn = (wave & 1) * 64;
  const int lr = lane & 15;
  const int q  = lane >> 4;
  const int sxor = lane & 7;
  const bool gps = (OM == 3) && (bm >= 512);
  f32x4 acc[4][4] = {};

  if (HAS_CSP) {
    if (tid < 128) {
      float s = 0.f;
      #pragma unroll
      for (int xx = 0; xx < 8; xx++) s += cs[xx * 4096 + bn + tid];
      psum[0][tid] = 1.0f / s;
    }
  }

  const int swz = ((lane & 7) ^ (lane >> 3)) * 8;
  const long grow = 32 * wave + (lane >> 3);
  const u16* Ag = A + ((long)bm + grow) * K + swz;
  const u16* Bg = B + ((long)bn + grow) * K + swz;

  for (int kt = 0; kt < K; kt += 64) {
    __syncthreads();
    #pragma unroll
    for (int i = 0; i < 4; i++) {
      gload16(Ag + (long)(8 * i) * K + kt, &As[(wave * 4 + i) * 512]);
      gload16(Bg + (long)(8 * i) * K + kt, &Bs[(wave * 4 + i) * 512]);
    }
    __syncthreads();
    #pragma unroll
    for (int kk = 0; kk < 2; kk++) {
      short8 av[4], bv[4];
      #pragma unroll
      for (int mi = 0; mi < 4; mi++)
        av[mi] = *(const short8*)&As[(wm + mi * 16 + lr) * 64 +
                                     (((kk << 2) + q) ^ sxor) * 8];
      #pragma unroll
      for (int ni = 0; ni < 4; ni++)
        bv[ni] = *(const short8*)&Bs[(wn + ni * 16 + lr) * 64 +
                                     (((kk << 2) + q) ^ sxor) * 8];
      #pragma unroll
      for (int mi = 0; mi < 4; mi++) {
        #pragma unroll
        for (int ni = 0; ni < 4; ni++)
          acc[mi][ni] = __builtin_amdgcn_mfma_f32_16x16x32_bf16(
              av[mi], bv[ni], acc[mi][ni], 0, 0, 0);
      }
    }
  }

  float invc[4];
  if (HAS_CSP) {
    #pragma unroll
    for (int ni = 0; ni < 4; ni++) invc[ni] = psum[0][wn + ni * 16 + lr];
  }
  __syncthreads();
  const int dr = (lane >> 4) * 4;
  const bool trans_out = (OM == 1) || (OM == 3 && !gps);
  float rowsum[4][4];
  float rowsq[4][4];
  if (HAS_EXP || HAS_PSUM2 || gps) {
    #pragma unroll
    for (int mi = 0; mi < 4; mi++)
      #pragma unroll
      for (int r = 0; r < 4; r++) { rowsum[mi][r] = 0.f; rowsq[mi][r] = 0.f; }
  }
  const float* bp = (OM == 3 && gps) ? bias2 - 512 : bias;
  #pragma unroll
  for (int mi = 0; mi < 4; mi++) {
    const int rowl = wm + mi * 16 + dr;
    const int rowb = bm + rowl;
    float bvs[4] = {0.f, 0.f, 0.f, 0.f};
    float shv[4] = {0.f, 0.f, 0.f, 0.f};
    if (HAS_BIAS) {
      #pragma unroll
      for (int r = 0; r < 4; r++) bvs[r] = bp[rowb + r];
    }
    if (HAS_SHIFT) {
      #pragma unroll
      for (int r = 0; r < 4; r++) shv[r] = shift[rowb + r];
    }
    #pragma unroll
    for (int ni = 0; ni < 4; ni++) {
      const int coll = wn + ni * 16 + lr;
      const float csv = HAS_CSP ? invc[ni] : (HAS_CS ? cs[bn + coll] : 1.0f);
      float v[4];
      #pragma unroll
      for (int r = 0; r < 4; r++) {
        float t = acc[mi][ni][r] * scale;
        if (HAS_CS || HAS_CSP) t *= csv;
        if (HAS_SHIFT) t -= shv[r];
        if (HAS_BIAS) t += bvs[r];
        if (HAS_EXP) t = __expf(t);
        if (HAS_EXP || HAS_PSUM2 || gps) rowsum[mi][r] += t;
        if (HAS_PSUM2) rowsq[mi][r] += t * t;
        v[r] = t;
      }
      if (trans_out) {
        u16x4 w;
        #pragma unroll
        for (int r = 0; r < 4; r++) w[r] = f2bf(v[r]);
        unsigned bo = (unsigned)((coll * 128 + rowl) * 2) ^ ((coll & 7) << 4);
        *(u16x4*)((char*)smem + bo) = w;
      } else {
        #pragma unroll
        for (int r = 0; r < 4; r++) {
          const int row = rowl + r;
          smem[row * 128 + (coll ^ (((row >> 2) & 3) << 4))] = f2bf(v[r]);
        }
      }
    }
  }
  if (HAS_EXP || HAS_PSUM2 || gps) {
    #pragma unroll
    for (int msk = 1; msk < 16; msk <<= 1)
      #pragma unroll
      for (int mi = 0; mi < 4; mi++)
        #pragma unroll
        for (int r = 0; r < 4; r++) {
          rowsum[mi][r] += __shfl_xor(rowsum[mi][r], msk);
          if (HAS_PSUM2) rowsq[mi][r] += __shfl_xor(rowsq[mi][r], msk);
        }
    if ((lane & 15) == 0) {
      #pragma unroll
      for (int mi = 0; mi < 4; mi++)
        #pragma unroll
        for (int r = 0; r < 4; r++) {
          psum[wave & 1][wm + mi * 16 + dr + r] = rowsum[mi][r];
          if (HAS_PSUM2) psum[2 + (wave & 1)][wm + mi * 16 + dr + r] = rowsq[mi][r];
        }
    }
  }
  __syncthreads();
  if (trans_out) {
    const int Ms = (OM == 3) ? 512 : M;
    u16* C = (u16*)Cv + blockIdx.z * sC;
    #pragma unroll
    for (int i = 0; i < 8; i++) {
      const int chunk = i * 256 + tid;
      const int coll = chunk >> 4, rq = chunk & 15;
      unsigned bo = (unsigned)(coll * 256 + rq * 16) ^ ((coll & 7) << 4);
      uint4 w = *(const uint4*)((const char*)smem + bo);
      *(uint4*)(C + (long)(bn + coll) * Ms + bm + rq * 8) = w;
    }
  } else {
    u16* C = (OM == 3) ? (u16*)Cv2 + blockIdx.z * sC : (u16*)Cv + blockIdx.z * sC;
    const int rbase = (OM == 3) ? bm - 512 : bm;
    #pragma unroll
    for (int i = 0; i < 8; i++) {
      const int chunk = i * 256 + tid;
      const int row = chunk >> 4, cq = chunk & 15;
      const int cbase = (cq * 8) ^ (((row >> 2) & 3) << 4);
      uint4 w = *(const uint4*)(smem + row * 128 + cbase);
      *(uint4*)(C + (long)(rbase + row) * N + bn + cq * 8) = w;
    }
  }
  if (HAS_EXP || HAS_PSUM2 || gps) {
    if (tid < 128) {
      if (HAS_EXP)
        psum_out[((long)blockIdx.z * gridDim.x + blockIdx.x) * 4096 + bm + tid] =
            psum[0][tid] + psum[1][tid];
      if (HAS_PSUM2) {
        const long blk = ((long)blockIdx.z * gridDim.y + blockIdx.y) * gridDim.x
                         + blockIdx.x;
        psum_out[blk * 256 + tid] = psum[0][tid] + psum[1][tid];
        psum_out[blk * 256 + 128 + tid] = psum[2][tid] + psum[3][tid];
      }
      if (gps)
        psum_out[((long)blockIdx.z * gridDim.x + blockIdx.x) * 512 +
                 (bm - 512) + tid] = psum[0][tid] + psum[1][tid];
    }
  }
}

// --- c0[b][c] = out_b[c] + sum_d out_w_f32[c][d]*gbar[b][d] ; gbar inline --
__global__ __launch_bounds__(256) void c0_kernel(const float* __restrict__ out_w,
                                                 const float* __restrict__ out_b,
                                                 const float* __restrict__ g_ps,
                                                 float* __restrict__ gbar,
                                                 float* __restrict__ c0) {
  const int idx = blockIdx.x * 4 + (threadIdx.x >> 6);   // 0..8191 = b*1024+c
  const int lane = threadIdx.x & 63;
  const int b = idx >> 10, c = idx & 1023;
  const int d0 = lane * 8;
  float g8[8] = {0.f, 0.f, 0.f, 0.f, 0.f, 0.f, 0.f, 0.f};
  #pragma unroll
  for (int xx = 0; xx < 8; xx++) {
    const float* p = g_ps + ((long)b * 8 + xx) * 512 + d0;
    float4 a0 = *(const float4*)p;
    float4 a1 = *(const float4*)(p + 4);
    g8[0] += a0.x; g8[1] += a0.y; g8[2] += a0.z; g8[3] += a0.w;
    g8[4] += a1.x; g8[5] += a1.y; g8[6] += a1.z; g8[7] += a1.w;
  }
  #pragma unroll
  for (int k = 0; k < 8; k++) g8[k] *= (1.0f / 1024.0f);
  if (c == 0) {
    float4 o0, o1;
    o0.x = g8[0]; o0.y = g8[1]; o0.z = g8[2]; o0.w = g8[3];
    o1.x = g8[4]; o1.y = g8[5]; o1.z = g8[6]; o1.w = g8[7];
    *(float4*)(gbar + (long)b * 512 + d0) = o0;
    *(float4*)(gbar + (long)b * 512 + d0 + 4) = o1;
  }
  float4 w0 = *(const float4*)(out_w + (long)c * DI + d0);
  float4 w1 = *(const float4*)(out_w + (long)c * DI + d0 + 4);
  float s = w0.x * g8[0] + w0.y * g8[1] + w0.z * g8[2] + w0.w * g8[3]
          + w1.x * g8[4] + w1.y * g8[5] + w1.z * g8[6] + w1.w * g8[7];
  #pragma unroll
  for (int off = 32; off > 0; off >>= 1) s += __shfl_xor(s, off);
  if (lane == 0) c0[idx] = out_b[c] + s;
}

// ------ BN stats (from y-GEMM partials) + apply + residual, fused --------
__global__ __launch_bounds__(256) void final_kernel(const u16* __restrict__ dy,
    const float* __restrict__ x, const float* __restrict__ partial,
    const float* __restrict__ c0,
    const float* __restrict__ bnw, const float* __restrict__ bnb,
    float* __restrict__ out) {
  __shared__ float red[6];
  __shared__ float bcast[2];
  const int bc = blockIdx.x;
  const int co = bc & 1023;
  const int t = threadIdx.x;
  if (t < 128) {
    const int b2 = t >> 4, bx = t & 15;
    const int by = co >> 8, r = co & 255;
    const long blk = (((long)b2 * 4 + by) * 16 + bx) * 512;
    float s = partial[blk + r];
    float qq = partial[blk + 256 + r];
    #pragma unroll
    for (int off = 1; off < 16; off <<= 1) {
      s += __shfl_xor(s, off);
      qq += __shfl_xor(qq, off);
    }
    float sbc = c0[b2 * 1024 + co] * s;
    #pragma unroll
    for (int off = 16; off < 64; off <<= 1) {
      s += __shfl_xor(s, off);
      qq += __shfl_xor(qq, off);
      sbc += __shfl_xor(sbc, off);
    }
    if (t == 0)  { red[0] = s; red[1] = qq; red[2] = sbc; }
    if (t == 64) { red[3] = s; red[4] = qq; red[5] = sbc; }
  }
  __syncthreads();
  if (t == 0) {
    float sdT = red[0] + red[3], sd2T = red[1] + red[4], sbcT = red[2] + red[5];
    float sc0 = 0.f, sc02 = 0.f;
    #pragma unroll
    for (int bb = 0; bb < 8; bb++) {
      float c = c0[bb * 1024 + co];
      sc0 += c; sc02 += c * c;
    }
    float S = 4096.0f * sc0 + sdT;
    float S2 = 4096.0f * sc02 + 2.0f * sbcT + sd2T;
    float mean = S * (1.0f / 32768.0f);
    float var = S2 * (1.0f / 32768.0f) - mean * mean;
    float inv = rsqrtf(var + 1e-5f) * bnw[co];
    bcast[0] = inv;
    bcast[1] = bnb[co] - mean * inv + c0[bc] * inv;
  }
  __syncthreads();
  const float inv = bcast[0], addc = bcast[1];
  const long base = (long)bc * 4096;
  #pragma unroll
  for (int i = 0; i < 2; i++) {
    const long off = base + (long)(i * 256 + t) * 8;
    uint4 v = *(const uint4*)(dy + off);
    float f[8]; unpack8(v, f);
    const float4 x0 = *(const float4*)(x + off);
    const float4 x1 = *(const float4*)(x + off + 4);
    float4 o0, o1;
    o0.x = f[0] * inv + addc + x0.x;
    o0.y = f[1] * inv + addc + x0.y;
    o0.z = f[2] * inv + addc + x0.z;
    o0.w = f[3] * inv + addc + x0.w;
    o1.x = f[4] * inv + addc + x1.x;
    o1.y = f[5] * inv + addc + x1.y;
    o1.z = f[6] * inv + addc + x1.z;
    o1.w = f[7] * inv + addc + x1.w;
    *(float4*)(out + off) = o0;
    *(float4*)(out + off + 4) = o1;
  }
}

extern "C" void kernel_launch(void* const* d_in, const int* in_sizes, int n_in,
                              void* d_out, int out_size, void* d_ws, size_t ws_size,
                              hipStream_t stream) {
  (void)in_sizes; (void)n_in; (void)out_size; (void)ws_size;
  const float* x       = (const float*)d_in[0];
  const float* theta_w = (const float*)d_in[1];
  const float* theta_b = (const float*)d_in[2];
  const float* phi_w   = (const float*)d_in[3];
  const float* phi_b   = (const float*)d_in[4];
  const float* g_w     = (const float*)d_in[5];
  const float* g_b     = (const float*)d_in[6];
  const float* out_w   = (const float*)d_in[7];
  const float* out_b   = (const float*)d_in[8];
  const float* bn_w    = (const float*)d_in[9];
  const float* bn_b    = (const float*)d_in[10];
  float* out = (float*)d_out;
  char* ws = (char*)d_ws;
  const size_t MB = 1024 * 1024;

  // workspace layout
  u16* xT     = (u16*)(ws + 0 * MB);       // 64MB; later: dy bf16 [0,64MB)
  u16* poolT  = (u16*)(ws + 64 * MB);      // 16MB
  u16* w_th   = (u16*)(ws + 80 * MB);      // 1MB
  u16* w_ph   = (u16*)(ws + 81 * MB);      // 1MB  (w_ph || w_g contiguous)
  u16* w_g    = (u16*)(ws + 82 * MB);      // 1MB
  u16* thetaT = (u16*)(ws + 84 * MB);      // 32MB
  u16* phiT   = (u16*)(ws + 116 * MB);     // 8MB
  u16* g_n    = (u16*)(ws + 124 * MB);     // 8MB
  u16* e      = (u16*)(ws + 132 * MB);     // 64MB (exp(scores))
  u16* tT     = (u16*)(ws + 196 * MB);     // 32MB (delta-t bf16)
  u16* w_out  = (u16*)(ws + 228 * MB);     // 1MB
  float* gbar  = (float*)(ws + 229 * MB);            // 16KB
  float* c0b   = (float*)(ws + 229 * MB + 16384);    // 32KB
  float* partial = (float*)(ws + 230 * MB);          // 512KB (8*4*4096 f32)
  float* partial2 = (float*)(ws + 231 * MB);         // 1MB (512 blk * 512 f32)
  float* g_ps = (float*)(ws + 233 * MB);             // 128KB (8*8*512 f32)
  u16* dy = xT;               // alias: x_T dead after theta GEMM

  // 1. prep: weights->bf16 + x->x_T + pool (single launch)
  prep_kernel<<<6144, 256, 0, stream>>>(x, xT, poolT,
                                        theta_w, phi_w, g_w, out_w,
                                        w_th, w_ph, w_g, w_out);
  // 2. theta -> theta_T [b][4096][512]  (256-tile 8-phase GEMM)
  gemm256<1, true, false, false, false, false, false>
      <<<dim3(16, 2, 8), 512, 0, stream>>>(
      w_th, xT, thetaT, theta_b, 0L, nullptr, 0L, nullptr, 0L, nullptr,
      1.0f, 512, 4096, 1024, 0L, (long)NPIX * CIN, (long)NPIX * DI);
  // 3. merged phi+g GEMM (128-tile kernel) -> phiT, g_n, g_ps
  gemm_tn<3, true, false, false, false, false, false>
      <<<dim3(8, 8, 8), 256, 0, stream>>>(
      w_ph, poolT, phiT, g_n, phi_b, g_b, 0L, nullptr, 0L, nullptr, 0L,
      g_ps, 1.0f, 1024, 1024, 1024, 0L, (long)MPIX * CIN, (long)MPIX * DI);
  // 4. c0 (computes gbar inline from g_ps; writes gbar for t-GEMM)
  c0_kernel<<<2048, 256, 0, stream>>>(out_w, out_b, g_ps, gbar, c0b);
  // 5. e[n][m] = exp(scores) + rowsum partials; XCD-swizzled flat launch
  gemm256<0, false, false, true, false, false, true>
      <<<512, 512, 0, stream>>>(
      thetaT, phiT, e, nullptr, 0L, nullptr, 0L, nullptr, 0L, partial,
      0.044194173824159216f, 4096, 1024, 512,
      (long)NPIX * DI, (long)MPIX * DI, (long)NPIX * MPIX);
  // 6. delta-t = (g_n * e^T)*inv[n] - gbar[d]; inv from partials (CSP)
  gemm256<1, false, true, false, false, true, false>
      <<<dim3(16, 2, 8), 512, 0, stream>>>(
      g_n, e, tT, nullptr, 0L, partial, 16384L, gbar, 512L, nullptr,
      1.0f, 512, 4096, 1024,
      (long)DI * MPIX, (long)NPIX * MPIX, (long)NPIX * DI);
  // 7. dy = out_w * delta-t^T + BN partials (PSUM2)
  gemm256<0, false, false, false, true, false, false>
      <<<dim3(16, 4, 8), 512, 0, stream>>>(
      w_out, tT, dy, nullptr, 0L, nullptr, 0L, nullptr, 0L, partial2,
      1.0f, 1024, 4096, 512, 0L, (long)NPIX * DI, (long)1024 * NPIX);
  // 8. BN stats (from partials, in-block) + apply + residual
  final_kernel<<<8192, 256, 0, stream>>>(dy, x, partial2, c0b, bn_w, bn_b, out);
}

// Round 16
// 322.080 us; speedup vs baseline: 1.0703x; 1.0160x over previous
//
#include <hip/hip_runtime.h>
#include <cstdint>

typedef unsigned short u16;
typedef __attribute__((ext_vector_type(4))) unsigned short u16x4;
typedef __attribute__((ext_vector_type(8))) short short8;
typedef __attribute__((ext_vector_type(4))) float f32x4;

#define DI 512
#define CIN 1024
#define NPIX 4096   // 64*64
#define MPIX 1024   // 32*32

__device__ __forceinline__ float bf2f(u16 u) {
  union { unsigned int i; float f; } v; v.i = ((unsigned int)u) << 16; return v.f;
}
__device__ __forceinline__ u16 f2bf(float f) {
  union { float f; unsigned int i; } v; v.f = f;
  unsigned int r = v.i + 0x7fffu + ((v.i >> 16) & 1u);
  return (u16)(r >> 16);
}
__device__ __forceinline__ void unpack8(uint4 v, float* f) {
  union { unsigned int i; float f; } u;
  u.i = v.x << 16;          f[0] = u.f;
  u.i = v.x & 0xffff0000u;  f[1] = u.f;
  u.i = v.y << 16;          f[2] = u.f;
  u.i = v.y & 0xffff0000u;  f[3] = u.f;
  u.i = v.z << 16;          f[4] = u.f;
  u.i = v.z & 0xffff0000u;  f[5] = u.f;
  u.i = v.w << 16;          f[6] = u.f;
  u.i = v.w & 0xffff0000u;  f[7] = u.f;
}

// async global->LDS, 16B per lane, wave-uniform LDS base + lane*16
__device__ __forceinline__ void gload16(const u16* g, u16* l) {
  __builtin_amdgcn_global_load_lds(
      (const __attribute__((address_space(1))) void*)g,
      (__attribute__((address_space(3))) void*)l, 16, 0, 0);
}

template<int N> __device__ __forceinline__ void wait_vmcnt() {
  asm volatile("s_waitcnt vmcnt(%0)" :: "n"(N) : "memory");
}

// ---- prep: blocks [0,4096): x -> x_T + 2x2 maxpool; [4096,6144): cvt ----
__global__ __launch_bounds__(256) void prep_kernel(
    const float* __restrict__ x, u16* __restrict__ xT, u16* __restrict__ poolT,
    const float* __restrict__ s0, const float* __restrict__ s1,
    const float* __restrict__ s2, const float* __restrict__ s3,
    u16* __restrict__ d0, u16* __restrict__ d1,
    u16* __restrict__ d2, u16* __restrict__ d3) {
  __shared__ u16 tile[64][136];
  const int blk = blockIdx.x;
  const int t = threadIdx.x;
  if (blk >= 4096) {                       // weight f32 -> bf16 convert
    int i = (blk - 4096) * 256 + t;        // 0 .. 4*131072
    int sel = i >> 17;
    int j = i & 131071;
    const float* src = sel == 0 ? s0 : sel == 1 ? s1 : sel == 2 ? s2 : s3;
    u16* dst = sel == 0 ? d0 : sel == 1 ? d1 : sel == 2 ? d2 : d3;
    float4 v = *(const float4*)(src + (long)j * 4);
    u16x4 w;
    w[0] = f2bf(v.x); w[1] = f2bf(v.y); w[2] = f2bf(v.z); w[3] = f2bf(v.w);
    *(u16x4*)(dst + (long)j * 4) = w;
    return;
  }
  const int bx = blk & 31, by = (blk >> 5) & 15, b = blk >> 9;
  const int n0 = bx * 128, c0 = by * 64;
  const float* xb = x + (long)b * CIN * NPIX;
  u16* xTb = xT + (long)b * NPIX * CIN;
  const int tc = t >> 5, tn = (t & 31) * 4;
  #pragma unroll
  for (int i = 0; i < 8; i++) {
    int c = tc + i * 8;
    float4 v = *(const float4*)(xb + (long)(c0 + c) * NPIX + n0 + tn);
    u16x4 w;
    w[0] = f2bf(v.x); w[1] = f2bf(v.y); w[2] = f2bf(v.z); w[3] = f2bf(v.w);
    *(u16x4*)&tile[c][tn] = w;
  }
  __syncthreads();
  const int tn2 = t >> 4, tc2 = (t & 15) * 4;
  #pragma unroll
  for (int i = 0; i < 8; i++) {
    int n = tn2 + i * 16;
    u16x4 w;
    w[0] = tile[tc2 + 0][n];
    w[1] = tile[tc2 + 1][n];
    w[2] = tile[tc2 + 2][n];
    w[3] = tile[tc2 + 3][n];
    *(u16x4*)(xTb + (long)(n0 + n) * CIN + c0 + tc2) = w;
  }
  const int j = t & 31, g = t >> 5;
  u16 r[8] __attribute__((aligned(16)));
  #pragma unroll
  for (int k = 0; k < 8; k++) {
    const int c = g * 8 + k;
    const unsigned w0 = *(const unsigned*)&tile[c][2 * j];
    const unsigned w1 = *(const unsigned*)&tile[c][64 + 2 * j];
    float m0 = fmaxf(bf2f((u16)(w0 & 0xffffu)), bf2f((u16)(w0 >> 16)));
    float m1 = fmaxf(bf2f((u16)(w1 & 0xffffu)), bf2f((u16)(w1 >> 16)));
    r[k] = f2bf(fmaxf(m0, m1));
  }
  *(uint4*)(poolT + ((long)b * MPIX + bx * 32 + j) * CIN + c0 + g * 8) =
      *(uint4*)r;
}

// =============== 256x256-tile GEMM, 8 waves, 8-phase counted-vmcnt =======
// Single barrier per phase: {reads(p) | stage(p) | vmcnt | BAR | lgkm(0) |
// setprio MFMA}. RAW: reads(p+1) after BAR(p); Q(p+1) certified by every
// wave's vmcnt(8) before BAR(p). WAR: stage(p) after BAR(p-1); last reads of
// its quarter were before all waves' BAR(p-1) arrival. Tail [8,8,8,4,4,0,0,0].
template<int OM, bool HAS_BIAS, bool HAS_SHIFT, bool HAS_EXP, bool HAS_PSUM2,
         bool HAS_CSP, bool XSWZ>
__global__ __launch_bounds__(512, 2)
void gemm256(const u16* __restrict__ A, const u16* __restrict__ B,
             void* __restrict__ Cv,
             const float* __restrict__ bias, long sBias,
             const float* __restrict__ cs, long sCS,
             const float* __restrict__ shift, long sShift,
             float* __restrict__ psum_out,
             float scale, int M, int N, int K, long sA, long sB, long sC)
{
  int bxi, byi, bzi;
  if (XSWZ) {
    const int q = blockIdx.x >> 5, s = blockIdx.x & 31;
    bxi = s >> 3;                       // 0..3
    const int yz = q * 8 + (s & 7);     // 0..127
    byi = yz & 15;
    bzi = yz >> 4;
  } else {
    bxi = blockIdx.x; byi = blockIdx.y; bzi = blockIdx.z;
  }
  A += bzi * sA;
  B += bzi * sB;
  if (HAS_BIAS) bias += bzi * sBias;
  if (HAS_CSP) cs += bzi * sCS;
  if (HAS_SHIFT) shift += bzi * sShift;
  const int bm = byi * 256, bn = bxi * 256;
  __shared__ __align__(16) u16 smem[65536];   // 2 slots x 64KB
  __shared__ float psum[4][256];
  __shared__ float psumq[4][256];
  __shared__ float invs[256];
  const int tid = threadIdx.x;
  const int lane = tid & 63, wave = tid >> 6;
  const int wr = wave >> 2, wc = wave & 3;       // 2M x 4N waves
  const int lr = lane & 15, q = lane >> 4;
  f32x4 acc[8][4] = {};

  if (HAS_CSP) {
    if (tid < 256) {
      float ssum = 0.f;
      #pragma unroll
      for (int xx = 0; xx < 4; xx++) ssum += cs[xx * 4096 + bn + tid];
      invs[tid] = 1.0f / ssum;
    }
    wait_vmcnt<0>();
    __builtin_amdgcn_sched_barrier(0);
  }

  const int srow = 32 * wave + (lane >> 2);
  const int sk = (((lane & 3) ^ ((lane >> 3) & 3))) * 8;
  const u16* Abase = A + ((long)bm + srow) * K + sk;
  const u16* Bbase = B + ((long)bn + srow) * K + sk;
  const int rswz = (q ^ ((lr >> 1) & 3)) * 8;
  const int aoff = (wr * 128 + lr) * 32 + rswz;
  const int boff = 16384 + (wc * 64 + lr) * 32 + rswz;

#define SA(T_, KK_) { const u16* g_ = Abase + (long)(T_) * 64 + (KK_) * 32; \
    u16* d_ = &smem[(((T_) & 1)) * 32768 + (KK_) * 8192 + wave * 1024]; \
    gload16(g_, d_); gload16(g_ + 16 * (long)K, d_ + 512); }
#define SB(T_, KK_) { const u16* g_ = Bbase + (long)(T_) * 64 + (KK_) * 32; \
    u16* d_ = &smem[(((T_) & 1)) * 32768 + 16384 + (KK_) * 8192 + wave * 1024]; \
    gload16(g_, d_); gload16(g_ + 16 * (long)K, d_ + 512); }
#define PH(VM, STG, SLOT, KK, RI0, LOADBV) { \
    const int qb_ = (SLOT) * 32768 + (KK) * 8192; \
    short8 av_[4]; \
    if (LOADBV) { \
      _Pragma("unroll") \
      for (int ci_ = 0; ci_ < 4; ci_++) \
        bv[ci_] = *(const short8*)&smem[qb_ + boff + ci_ * 512]; \
    } \
    _Pragma("unroll") \
    for (int r_ = 0; r_ < 4; r_++) \
      av_[r_] = *(const short8*)&smem[qb_ + aoff + ((RI0) + r_) * 512]; \
    STG; \
    wait_vmcnt<VM>(); \
    __builtin_amdgcn_sched_barrier(0); \
    __builtin_amdgcn_s_barrier(); \
    asm volatile("s_waitcnt lgkmcnt(0)" ::: "memory"); \
    __builtin_amdgcn_sched_barrier(0); \
    __builtin_amdgcn_s_setprio(1); \
    _Pragma("unroll") \
    for (int r_ = 0; r_ < 4; r_++) \
      _Pragma("unroll") \
      for (int ci_ = 0; ci_ < 4; ci_++) \
        acc[(RI0) + r_][ci_] = __builtin_amdgcn_mfma_f32_16x16x32_bf16( \
            av_[r_], bv[ci_], acc[(RI0) + r_][ci_], 0, 0, 0); \
    __builtin_amdgcn_s_setprio(0); \
    __builtin_amdgcn_sched_barrier(0); }

  const int niter2 = K >> 7;
  short8 bv[4];

  // prologue: 6 stage-ops (12 loads); vmcnt(8) certifies S1,S2 for ph0 reads
  SA(0, 0); SB(0, 0); SA(0, 1); SB(0, 1); SA(1, 0); SB(1, 0);
  wait_vmcnt<8>();
  __builtin_amdgcn_s_barrier();
  __builtin_amdgcn_sched_barrier(0);

  for (int u = 0; u < niter2 - 1; ++u) {
    const int t1 = 2 * u + 1, t2 = 2 * u + 2, t3 = 2 * u + 3;
    PH(8, SA(t1, 1), 0, 0, 0, 1)
    PH(8, SB(t1, 1), 0, 0, 4, 0)
    PH(8, SA(t2, 0), 0, 1, 0, 1)
    PH(8, SB(t2, 0), 0, 1, 4, 0)
    PH(8, SA(t2, 1), 1, 0, 0, 1)
    PH(8, SB(t2, 1), 1, 0, 4, 0)
    PH(8, SA(t3, 0), 1, 1, 0, 1)
    PH(8, SB(t3, 0), 1, 1, 4, 0)
  }
  {
    const int t1 = 2 * (niter2 - 1) + 1;
    PH(8, SA(t1, 1), 0, 0, 0, 1)
    PH(8, SB(t1, 1), 0, 0, 4, 0)
    PH(8, ((void)0), 0, 1, 0, 1)
    PH(4, ((void)0), 0, 1, 4, 0)
    PH(4, ((void)0), 1, 0, 0, 1)
    PH(0, ((void)0), 1, 0, 4, 0)
    PH(0, ((void)0), 1, 1, 0, 1)
    PH(0, ((void)0), 1, 1, 4, 0)
  }
#undef SA
#undef SB
#undef PH

  __syncthreads();

  const int dr = (lane >> 4) * 4;
  float invc[4];
  if (HAS_CSP) {
    #pragma unroll
    for (int ci = 0; ci < 4; ci++) invc[ci] = invs[wc * 64 + ci * 16 + lr];
  }
  float rowsum[8][4], rowsq[8][4];
  if (HAS_EXP || HAS_PSUM2) {
    #pragma unroll
    for (int ri = 0; ri < 8; ri++)
      #pragma unroll
      for (int r = 0; r < 4; r++) { rowsum[ri][r] = 0.f; rowsq[ri][r] = 0.f; }
  }
  #pragma unroll
  for (int ri = 0; ri < 8; ri++) {
    const int rowl = wr * 128 + ri * 16 + dr;
    const int rowb = bm + rowl;
    float bvs[4] = {0.f, 0.f, 0.f, 0.f};
    float shv[4] = {0.f, 0.f, 0.f, 0.f};
    if (HAS_BIAS) {
      #pragma unroll
      for (int r = 0; r < 4; r++) bvs[r] = bias[rowb + r];
    }
    if (HAS_SHIFT) {
      #pragma unroll
      for (int r = 0; r < 4; r++) shv[r] = shift[rowb + r];
    }
    #pragma unroll
    for (int ci = 0; ci < 4; ci++) {
      const int coll = wc * 64 + ci * 16 + lr;
      float v[4];
      #pragma unroll
      for (int r = 0; r < 4; r++) {
        float tv = acc[ri][ci][r] * scale;
        if (HAS_CSP) tv *= invc[ci];
        if (HAS_SHIFT) tv -= shv[r];
        if (HAS_BIAS) tv += bvs[r];
        if (HAS_EXP) tv = __expf(tv);
        if (HAS_EXP || HAS_PSUM2) rowsum[ri][r] += tv;
        if (HAS_PSUM2) rowsq[ri][r] += tv * tv;
        v[r] = tv;
      }
      if (OM == 1) {
        u16x4 w;
        #pragma unroll
        for (int r = 0; r < 4; r++) w[r] = f2bf(v[r]);
        unsigned bo = (unsigned)((coll * 256 + rowl) * 2) ^ ((coll & 7) << 4);
        *(u16x4*)((char*)smem + bo) = w;
      } else {
        #pragma unroll
        for (int r = 0; r < 4; r++) {
          const int row = rowl + r;
          smem[row * 256 + (coll ^ (((row >> 2) & 3) << 4))] = f2bf(v[r]);
        }
      }
    }
  }
  if (HAS_EXP || HAS_PSUM2) {
    #pragma unroll
    for (int msk = 1; msk < 16; msk <<= 1)
      #pragma unroll
      for (int ri = 0; ri < 8; ri++)
        #pragma unroll
        for (int r = 0; r < 4; r++) {
          rowsum[ri][r] += __shfl_xor(rowsum[ri][r], msk);
          if (HAS_PSUM2) rowsq[ri][r] += __shfl_xor(rowsq[ri][r], msk);
        }
    if ((lane & 15) == 0) {
      #pragma unroll
      for (int ri = 0; ri < 8; ri++)
        #pragma unroll
        for (int r = 0; r < 4; r++) {
          psum[wc][wr * 128 + ri * 16 + dr + r] = rowsum[ri][r];
          if (HAS_PSUM2) psumq[wc][wr * 128 + ri * 16 + dr + r] = rowsq[ri][r];
        }
    }
  }
  __syncthreads();
  u16* C = (u16*)Cv + bzi * sC;
  if (OM == 1) {
    #pragma unroll
    for (int i = 0; i < 16; i++) {
      const int chunk = i * 512 + tid;
      const int coll = chunk >> 5, rq = chunk & 31;
      unsigned bo = (unsigned)(coll * 512 + rq * 16) ^ ((coll & 7) << 4);
      uint4 w = *(const uint4*)((const char*)smem + bo);
      *(uint4*)(C + (long)(bn + coll) * M + bm + rq * 8) = w;
    }
  } else {
    #pragma unroll
    for (int i = 0; i < 16; i++) {
      const int chunk = i * 512 + tid;
      const int row = chunk >> 5, cq = chunk & 31;
      const int cbase = (cq * 8) ^ (((row >> 2) & 3) << 4);
      uint4 w = *(const uint4*)(smem + row * 256 + cbase);
      *(uint4*)(C + (long)(bm + row) * N + bn + cq * 8) = w;
    }
  }
  if ((HAS_EXP || HAS_PSUM2) && tid < 256) {
    const int gX = XSWZ ? 4 : gridDim.x;
    if (HAS_EXP)
      psum_out[((long)bzi * gX + bxi) * 4096 + bm + tid] =
          psum[0][tid] + psum[1][tid] + psum[2][tid] + psum[3][tid];
    if (HAS_PSUM2) {
      const int gY = XSWZ ? 16 : gridDim.y;
      const long blk = ((long)bzi * gY + byi) * gX + bxi;
      psum_out[blk * 512 + tid] =
          psum[0][tid] + psum[1][tid] + psum[2][tid] + psum[3][tid];
      psum_out[blk * 512 + 256 + tid] =
          psumq[0][tid] + psumq[1][tid] + psumq[2][tid] + psumq[3][tid];
    }
  }
}

// ---------------- 128x128 GEMM (merged phi+g) ----------------
template<int OM, bool HAS_BIAS, bool HAS_CS, bool HAS_SHIFT, bool HAS_EXP,
         bool HAS_PSUM2, bool HAS_CSP>
__global__ __launch_bounds__(256)
void gemm_tn(const u16* __restrict__ A, const u16* __restrict__ B,
             void* __restrict__ Cv, void* __restrict__ Cv2,
             const float* __restrict__ bias, const float* __restrict__ bias2,
             long sBias,
             const float* __restrict__ cs, long sCS,
             const float* __restrict__ shift, long sShift,
             float* __restrict__ psum_out,
             float scale, int M, int N, int K, long sA, long sB, long sC)
{
  A += blockIdx.z * sA;
  B += blockIdx.z * sB;
  if (HAS_BIAS) bias += blockIdx.z * sBias;
  if (HAS_CS || HAS_CSP) cs += blockIdx.z * sCS;
  if (HAS_SHIFT) shift += blockIdx.z * sShift;
  const int bm = blockIdx.y * 128;
  const int bn = blockIdx.x * 128;
  __shared__ __align__(16) u16 smem[128 * 128];
  u16* As = smem;
  u16* Bs = smem + 128 * 64;
  __shared__ float psum[4][128];
  const int tid = threadIdx.x;
  const int lane = tid & 63;
  const int wave = tid >> 6;
  const int wm = (wave >> 1) * 64;
  const int wn = (wave & 1) * 64;
  const int lr = lane & 15;
  const int q  = lane >> 4;
  const int sxor = lane & 7;
  const bool gps = (OM == 3) && (bm >= 512);
  f32x4 acc[4][4] = {};

  if (HAS_CSP) {
    if (tid < 128) {
      float s = 0.f;
      #pragma unroll
      for (int xx = 0; xx < 8; xx++) s += cs[xx * 4096 + bn + tid];
      psum[0][tid] = 1.0f / s;
    }
  }

  const int swz = ((lane & 7) ^ (lane >> 3)) * 8;
  const long grow = 32 * wave + (lane >> 3);
  const u16* Ag = A + ((long)bm + grow) * K + swz;
  const u16* Bg = B + ((long)bn + grow) * K + swz;

  for (int kt = 0; kt < K; kt += 64) {
    __syncthreads();
    #pragma unroll
    for (int i = 0; i < 4; i++) {
      gload16(Ag + (long)(8 * i) * K + kt, &As[(wave * 4 + i) * 512]);
      gload16(Bg + (long)(8 * i) * K + kt, &Bs[(wave * 4 + i) * 512]);
    }
    __syncthreads();
    #pragma unroll
    for (int kk = 0; kk < 2; kk++) {
      short8 av[4], bv[4];
      #pragma unroll
      for (int mi = 0; mi < 4; mi++)
        av[mi] = *(const short8*)&As[(wm + mi * 16 + lr) * 64 +
                                     (((kk << 2) + q) ^ sxor) * 8];
      #pragma unroll
      for (int ni = 0; ni < 4; ni++)
        bv[ni] = *(const short8*)&Bs[(wn + ni * 16 + lr) * 64 +
                                     (((kk << 2) + q) ^ sxor) * 8];
      #pragma unroll
      for (int mi = 0; mi < 4; mi++) {
        #pragma unroll
        for (int ni = 0; ni < 4; ni++)
          acc[mi][ni] = __builtin_amdgcn_mfma_f32_16x16x32_bf16(
              av[mi], bv[ni], acc[mi][ni], 0, 0, 0);
      }
    }
  }

  float invc[4];
  if (HAS_CSP) {
    #pragma unroll
    for (int ni = 0; ni < 4; ni++) invc[ni] = psum[0][wn + ni * 16 + lr];
  }
  __syncthreads();
  const int dr = (lane >> 4) * 4;
  const bool trans_out = (OM == 1) || (OM == 3 && !gps);
  float rowsum[4][4];
  float rowsq[4][4];
  if (HAS_EXP || HAS_PSUM2 || gps) {
    #pragma unroll
    for (int mi = 0; mi < 4; mi++)
      #pragma unroll
      for (int r = 0; r < 4; r++) { rowsum[mi][r] = 0.f; rowsq[mi][r] = 0.f; }
  }
  const float* bp = (OM == 3 && gps) ? bias2 - 512 : bias;
  #pragma unroll
  for (int mi = 0; mi < 4; mi++) {
    const int rowl = wm + mi * 16 + dr;
    const int rowb = bm + rowl;
    float bvs[4] = {0.f, 0.f, 0.f, 0.f};
    float shv[4] = {0.f, 0.f, 0.f, 0.f};
    if (HAS_BIAS) {
      #pragma unroll
      for (int r = 0; r < 4; r++) bvs[r] = bp[rowb + r];
    }
    if (HAS_SHIFT) {
      #pragma unroll
      for (int r = 0; r < 4; r++) shv[r] = shift[rowb + r];
    }
    #pragma unroll
    for (int ni = 0; ni < 4; ni++) {
      const int coll = wn + ni * 16 + lr;
      const float csv = HAS_CSP ? invc[ni] : (HAS_CS ? cs[bn + coll] : 1.0f);
      float v[4];
      #pragma unroll
      for (int r = 0; r < 4; r++) {
        float t = acc[mi][ni][r] * scale;
        if (HAS_CS || HAS_CSP) t *= csv;
        if (HAS_SHIFT) t -= shv[r];
        if (HAS_BIAS) t += bvs[r];
        if (HAS_EXP) t = __expf(t);
        if (HAS_EXP || HAS_PSUM2 || gps) rowsum[mi][r] += t;
        if (HAS_PSUM2) rowsq[mi][r] += t * t;
        v[r] = t;
      }
      if (trans_out) {
        u16x4 w;
        #pragma unroll
        for (int r = 0; r < 4; r++) w[r] = f2bf(v[r]);
        unsigned bo = (unsigned)((coll * 128 + rowl) * 2) ^ ((coll & 7) << 4);
        *(u16x4*)((char*)smem + bo) = w;
      } else {
        #pragma unroll
        for (int r = 0; r < 4; r++) {
          const int row = rowl + r;
          smem[row * 128 + (coll ^ (((row >> 2) & 3) << 4))] = f2bf(v[r]);
        }
      }
    }
  }
  if (HAS_EXP || HAS_PSUM2 || gps) {
    #pragma unroll
    for (int msk = 1; msk < 16; msk <<= 1)
      #pragma unroll
      for (int mi = 0; mi < 4; mi++)
        #pragma unroll
        for (int r = 0; r < 4; r++) {
          rowsum[mi][r] += __shfl_xor(rowsum[mi][r], msk);
          if (HAS_PSUM2) rowsq[mi][r] += __shfl_xor(rowsq[mi][r], msk);
        }
    if ((lane & 15) == 0) {
      #pragma unroll
      for (int mi = 0; mi < 4; mi++)
        #pragma unroll
        for (int r = 0; r < 4; r++) {
          psum[wave & 1][wm + mi * 16 + dr + r] = rowsum[mi][r];
          if (HAS_PSUM2) psum[2 + (wave & 1)][wm + mi * 16 + dr + r] = rowsq[mi][r];
        }
    }
  }
  __syncthreads();
  if (trans_out) {
    const int Ms = (OM == 3) ? 512 : M;
    u16* C = (u16*)Cv + blockIdx.z * sC;
    #pragma unroll
    for (int i = 0; i < 8; i++) {
      const int chunk = i * 256 + tid;
      const int coll = chunk >> 4, rq = chunk & 15;
      unsigned bo = (unsigned)(coll * 256 + rq * 16) ^ ((coll & 7) << 4);
      uint4 w = *(const uint4*)((const char*)smem + bo);
      *(uint4*)(C + (long)(bn + coll) * Ms + bm + rq * 8) = w;
    }
  } else {
    u16* C = (OM == 3) ? (u16*)Cv2 + blockIdx.z * sC : (u16*)Cv + blockIdx.z * sC;
    const int rbase = (OM == 3) ? bm - 512 : bm;
    #pragma unroll
    for (int i = 0; i < 8; i++) {
      const int chunk = i * 256 + tid;
      const int row = chunk >> 4, cq = chunk & 15;
      const int cbase = (cq * 8) ^ (((row >> 2) & 3) << 4);
      uint4 w = *(const uint4*)(smem + row * 128 + cbase);
      *(uint4*)(C + (long)(rbase + row) * N + bn + cq * 8) = w;
    }
  }
  if (HAS_EXP || HAS_PSUM2 || gps) {
    if (tid < 128) {
      if (HAS_EXP)
        psum_out[((long)blockIdx.z * gridDim.x + blockIdx.x) * 4096 + bm + tid] =
            psum[0][tid] + psum[1][tid];
      if (HAS_PSUM2) {
        const long blk = ((long)blockIdx.z * gridDim.y + blockIdx.y) * gridDim.x
                         + blockIdx.x;
        psum_out[blk * 256 + tid] = psum[0][tid] + psum[1][tid];
        psum_out[blk * 256 + 128 + tid] = psum[2][tid] + psum[3][tid];
      }
      if (gps)
        psum_out[((long)blockIdx.z * gridDim.x + blockIdx.x) * 512 +
                 (bm - 512) + tid] = psum[0][tid] + psum[1][tid];
    }
  }
}

// --- c0[b][c] = out_b[c] + sum_d out_w_f32[c][d]*gbar[b][d] ; gbar inline --
__global__ __launch_bounds__(256) void c0_kernel(const float* __restrict__ out_w,
                                                 const float* __restrict__ out_b,
                                                 const float* __restrict__ g_ps,
                                                 float* __restrict__ gbar,
                                                 float* __restrict__ c0) {
  const int idx = blockIdx.x * 4 + (threadIdx.x >> 6);   // 0..8191 = b*1024+c
  const int lane = threadIdx.x & 63;
  const int b = idx >> 10, c = idx & 1023;
  const int d0 = lane * 8;
  float g8[8] = {0.f, 0.f, 0.f, 0.f, 0.f, 0.f, 0.f, 0.f};
  #pragma unroll
  for (int xx = 0; xx < 8; xx++) {
    const float* p = g_ps + ((long)b * 8 + xx) * 512 + d0;
    float4 a0 = *(const float4*)p;
    float4 a1 = *(const float4*)(p + 4);
    g8[0] += a0.x; g8[1] += a0.y; g8[2] += a0.z; g8[3] += a0.w;
    g8[4] += a1.x; g8[5] += a1.y; g8[6] += a1.z; g8[7] += a1.w;
  }
  #pragma unroll
  for (int k = 0; k < 8; k++) g8[k] *= (1.0f / 1024.0f);
  if (c == 0) {
    float4 o0, o1;
    o0.x = g8[0]; o0.y = g8[1]; o0.z = g8[2]; o0.w = g8[3];
    o1.x = g8[4]; o1.y = g8[5]; o1.z = g8[6]; o1.w = g8[7];
    *(float4*)(gbar + (long)b * 512 + d0) = o0;
    *(float4*)(gbar + (long)b * 512 + d0 + 4) = o1;
  }
  float4 w0 = *(const float4*)(out_w + (long)c * DI + d0);
  float4 w1 = *(const float4*)(out_w + (long)c * DI + d0 + 4);
  float s = w0.x * g8[0] + w0.y * g8[1] + w0.z * g8[2] + w0.w * g8[3]
          + w1.x * g8[4] + w1.y * g8[5] + w1.z * g8[6] + w1.w * g8[7];
  #pragma unroll
  for (int off = 32; off > 0; off >>= 1) s += __shfl_xor(s, off);
  if (lane == 0) c0[idx] = out_b[c] + s;
}

// ------ BN stats (from y-GEMM partials) + apply + residual, fused --------
__global__ __launch_bounds__(256) void final_kernel(const u16* __restrict__ dy,
    const float* __restrict__ x, const float* __restrict__ partial,
    const float* __restrict__ c0,
    const float* __restrict__ bnw, const float* __restrict__ bnb,
    float* __restrict__ out) {
  __shared__ float red[6];
  __shared__ float bcast[2];
  const int bc = blockIdx.x;
  const int co = bc & 1023;
  const int t = threadIdx.x;
  if (t < 128) {
    const int b2 = t >> 4, bx = t & 15;
    const int by = co >> 8, r = co & 255;
    const long blk = (((long)b2 * 4 + by) * 16 + bx) * 512;
    float s = partial[blk + r];
    float qq = partial[blk + 256 + r];
    #pragma unroll
    for (int off = 1; off < 16; off <<= 1) {
      s += __shfl_xor(s, off);
      qq += __shfl_xor(qq, off);
    }
    float sbc = c0[b2 * 1024 + co] * s;
    #pragma unroll
    for (int off = 16; off < 64; off <<= 1) {
      s += __shfl_xor(s, off);
      qq += __shfl_xor(qq, off);
      sbc += __shfl_xor(sbc, off);
    }
    if (t == 0)  { red[0] = s; red[1] = qq; red[2] = sbc; }
    if (t == 64) { red[3] = s; red[4] = qq; red[5] = sbc; }
  }
  __syncthreads();
  if (t == 0) {
    float sdT = red[0] + red[3], sd2T = red[1] + red[4], sbcT = red[2] + red[5];
    float sc0 = 0.f, sc02 = 0.f;
    #pragma unroll
    for (int bb = 0; bb < 8; bb++) {
      float c = c0[bb * 1024 + co];
      sc0 += c; sc02 += c * c;
    }
    float S = 4096.0f * sc0 + sdT;
    float S2 = 4096.0f * sc02 + 2.0f * sbcT + sd2T;
    float mean = S * (1.0f / 32768.0f);
    float var = S2 * (1.0f / 32768.0f) - mean * mean;
    float inv = rsqrtf(var + 1e-5f) * bnw[co];
    bcast[0] = inv;
    bcast[1] = bnb[co] - mean * inv + c0[bc] * inv;
  }
  __syncthreads();
  const float inv = bcast[0], addc = bcast[1];
  const long base = (long)bc * 4096;
  #pragma unroll
  for (int i = 0; i < 2; i++) {
    const long off = base + (long)(i * 256 + t) * 8;
    uint4 v = *(const uint4*)(dy + off);
    float f[8]; unpack8(v, f);
    const float4 x0 = *(const float4*)(x + off);
    const float4 x1 = *(const float4*)(x + off + 4);
    float4 o0, o1;
    o0.x = f[0] * inv + addc + x0.x;
    o0.y = f[1] * inv + addc + x0.y;
    o0.z = f[2] * inv + addc + x0.z;
    o0.w = f[3] * inv + addc + x0.w;
    o1.x = f[4] * inv + addc + x1.x;
    o1.y = f[5] * inv + addc + x1.y;
    o1.z = f[6] * inv + addc + x1.z;
    o1.w = f[7] * inv + addc + x1.w;
    *(float4*)(out + off) = o0;
    *(float4*)(out + off + 4) = o1;
  }
}

extern "C" void kernel_launch(void* const* d_in, const int* in_sizes, int n_in,
                              void* d_out, int out_size, void* d_ws, size_t ws_size,
                              hipStream_t stream) {
  (void)in_sizes; (void)n_in; (void)out_size; (void)ws_size;
  const float* x       = (const float*)d_in[0];
  const float* theta_w = (const float*)d_in[1];
  const float* theta_b = (const float*)d_in[2];
  const float* phi_w   = (const float*)d_in[3];
  const float* phi_b   = (const float*)d_in[4];
  const float* g_w     = (const float*)d_in[5];
  const float* g_b     = (const float*)d_in[6];
  const float* out_w   = (const float*)d_in[7];
  const float* out_b   = (const float*)d_in[8];
  const float* bn_w    = (const float*)d_in[9];
  const float* bn_b    = (const float*)d_in[10];
  float* out = (float*)d_out;
  char* ws = (char*)d_ws;
  const size_t MB = 1024 * 1024;

  // workspace layout
  u16* xT     = (u16*)(ws + 0 * MB);       // 64MB; later: dy bf16 [0,64MB)
  u16* poolT  = (u16*)(ws + 64 * MB);      // 16MB
  u16* w_th   = (u16*)(ws + 80 * MB);      // 1MB
  u16* w_ph   = (u16*)(ws + 81 * MB);      // 1MB  (w_ph || w_g contiguous)
  u16* w_g    = (u16*)(ws + 82 * MB);      // 1MB
  u16* thetaT = (u16*)(ws + 84 * MB);      // 32MB
  u16* phiT   = (u16*)(ws + 116 * MB);     // 8MB
  u16* g_n    = (u16*)(ws + 124 * MB);     // 8MB
  u16* e      = (u16*)(ws + 132 * MB);     // 64MB (exp(scores))
  u16* tT     = (u16*)(ws + 196 * MB);     // 32MB (delta-t bf16)
  u16* w_out  = (u16*)(ws + 228 * MB);     // 1MB
  float* gbar  = (float*)(ws + 229 * MB);            // 16KB
  float* c0b   = (float*)(ws + 229 * MB + 16384);    // 32KB
  float* partial = (float*)(ws + 230 * MB);          // 512KB (8*4*4096 f32)
  float* partial2 = (float*)(ws + 231 * MB);         // 1MB (512 blk * 512 f32)
  float* g_ps = (float*)(ws + 233 * MB);             // 128KB (8*8*512 f32)
  u16* dy = xT;               // alias: x_T dead after theta GEMM

  // 1. prep: weights->bf16 + x->x_T + pool (single launch)
  prep_kernel<<<6144, 256, 0, stream>>>(x, xT, poolT,
                                        theta_w, phi_w, g_w, out_w,
                                        w_th, w_ph, w_g, w_out);
  // 2. theta -> theta_T [b][4096][512]  (256-tile 8-phase GEMM)
  gemm256<1, true, false, false, false, false, false>
      <<<dim3(16, 2, 8), 512, 0, stream>>>(
      w_th, xT, thetaT, theta_b, 0L, nullptr, 0L, nullptr, 0L, nullptr,
      1.0f, 512, 4096, 1024, 0L, (long)NPIX * CIN, (long)NPIX * DI);
  // 3. merged phi+g GEMM (128-tile kernel) -> phiT, g_n, g_ps
  gemm_tn<3, true, false, false, false, false, false>
      <<<dim3(8, 8, 8), 256, 0, stream>>>(
      w_ph, poolT, phiT, g_n, phi_b, g_b, 0L, nullptr, 0L, nullptr, 0L,
      g_ps, 1.0f, 1024, 1024, 1024, 0L, (long)MPIX * CIN, (long)MPIX * DI);
  // 4. c0 (computes gbar inline from g_ps; writes gbar for t-GEMM)
  c0_kernel<<<2048, 256, 0, stream>>>(out_w, out_b, g_ps, gbar, c0b);
  // 5. e[n][m] = exp(scores) + rowsum partials; XCD-swizzled flat launch
  gemm256<0, false, false, true, false, false, true>
      <<<512, 512, 0, stream>>>(
      thetaT, phiT, e, nullptr, 0L, nullptr, 0L, nullptr, 0L, partial,
      0.044194173824159216f, 4096, 1024, 512,
      (long)NPIX * DI, (long)MPIX * DI, (long)NPIX * MPIX);
  // 6. delta-t = (g_n * e^T)*inv[n] - gbar[d]; inv from partials (CSP)
  gemm256<1, false, true, false, false, true, false>
      <<<dim3(16, 2, 8), 512, 0, stream>>>(
      g_n, e, tT, nullptr, 0L, partial, 16384L, gbar, 512L, nullptr,
      1.0f, 512, 4096, 1024,
      (long)DI * MPIX, (long)NPIX * MPIX, (long)NPIX * DI);
  // 7. dy = out_w * delta-t^T + BN partials (PSUM2)
  gemm256<0, false, false, false, true, false, false>
      <<<dim3(16, 4, 8), 512, 0, stream>>>(
      w_out, tT, dy, nullptr, 0L, nullptr, 0L, nullptr, 0L, partial2,
      1.0f, 1024, 4096, 512, 0L, (long)NPIX * DI, (long)1024 * NPIX);
  // 8. BN stats (from partials, in-block) + apply + residual
  final_kernel<<<8192, 256, 0, stream>>>(dy, x, partial2, c0b, bn_w, bn_b, out);
}

// Round 17
// 318.690 us; speedup vs baseline: 1.0817x; 1.0106x over previous
//
#include <hip/hip_runtime.h>
#include <cstdint>

typedef unsigned short u16;
typedef __attribute__((ext_vector_type(4))) unsigned short u16x4;
typedef __attribute__((ext_vector_type(8))) short short8;
typedef __attribute__((ext_vector_type(4))) float f32x4;

#define DI 512
#define CIN 1024
#define NPIX 4096   // 64*64
#define MPIX 1024   // 32*32

__device__ __forceinline__ float bf2f(u16 u) {
  union { unsigned int i; float f; } v; v.i = ((unsigned int)u) << 16; return v.f;
}
__device__ __forceinline__ u16 f2bf(float f) {
  union { float f; unsigned int i; } v; v.f = f;
  unsigned int r = v.i + 0x7fffu + ((v.i >> 16) & 1u);
  return (u16)(r >> 16);
}
__device__ __forceinline__ void unpack8(uint4 v, float* f) {
  union { unsigned int i; float f; } u;
  u.i = v.x << 16;          f[0] = u.f;
  u.i = v.x & 0xffff0000u;  f[1] = u.f;
  u.i = v.y << 16;          f[2] = u.f;
  u.i = v.y & 0xffff0000u;  f[3] = u.f;
  u.i = v.z << 16;          f[4] = u.f;
  u.i = v.z & 0xffff0000u;  f[5] = u.f;
  u.i = v.w << 16;          f[6] = u.f;
  u.i = v.w & 0xffff0000u;  f[7] = u.f;
}

// async global->LDS, 16B per lane, wave-uniform LDS base + lane*16
__device__ __forceinline__ void gload16(const u16* g, u16* l) {
  __builtin_amdgcn_global_load_lds(
      (const __attribute__((address_space(1))) void*)g,
      (__attribute__((address_space(3))) void*)l, 16, 0, 0);
}

template<int N> __device__ __forceinline__ void wait_vmcnt() {
  asm volatile("s_waitcnt vmcnt(%0)" :: "n"(N) : "memory");
}

// ---- prep: blocks [0,4096): x -> x_T + 2x2 maxpool; [4096,6144): cvt ----
__global__ __launch_bounds__(256) void prep_kernel(
    const float* __restrict__ x, u16* __restrict__ xT, u16* __restrict__ poolT,
    const float* __restrict__ s0, const float* __restrict__ s1,
    const float* __restrict__ s2, const float* __restrict__ s3,
    u16* __restrict__ d0, u16* __restrict__ d1,
    u16* __restrict__ d2, u16* __restrict__ d3) {
  __shared__ u16 tile[64][136];
  const int blk = blockIdx.x;
  const int t = threadIdx.x;
  if (blk >= 4096) {                       // weight f32 -> bf16 convert
    int i = (blk - 4096) * 256 + t;        // 0 .. 4*131072
    int sel = i >> 17;
    int j = i & 131071;
    const float* src = sel == 0 ? s0 : sel == 1 ? s1 : sel == 2 ? s2 : s3;
    u16* dst = sel == 0 ? d0 : sel == 1 ? d1 : sel == 2 ? d2 : d3;
    float4 v = *(const float4*)(src + (long)j * 4);
    u16x4 w;
    w[0] = f2bf(v.x); w[1] = f2bf(v.y); w[2] = f2bf(v.z); w[3] = f2bf(v.w);
    *(u16x4*)(dst + (long)j * 4) = w;
    return;
  }
  const int bx = blk & 31, by = (blk >> 5) & 15, b = blk >> 9;
  const int n0 = bx * 128, c0 = by * 64;
  const float* xb = x + (long)b * CIN * NPIX;
  u16* xTb = xT + (long)b * NPIX * CIN;
  const int tc = t >> 5, tn = (t & 31) * 4;
  #pragma unroll
  for (int i = 0; i < 8; i++) {
    int c = tc + i * 8;
    float4 v = *(const float4*)(xb + (long)(c0 + c) * NPIX + n0 + tn);
    u16x4 w;
    w[0] = f2bf(v.x); w[1] = f2bf(v.y); w[2] = f2bf(v.z); w[3] = f2bf(v.w);
    *(u16x4*)&tile[c][tn] = w;
  }
  __syncthreads();
  const int tn2 = t >> 4, tc2 = (t & 15) * 4;
  #pragma unroll
  for (int i = 0; i < 8; i++) {
    int n = tn2 + i * 16;
    u16x4 w;
    w[0] = tile[tc2 + 0][n];
    w[1] = tile[tc2 + 1][n];
    w[2] = tile[tc2 + 2][n];
    w[3] = tile[tc2 + 3][n];
    *(u16x4*)(xTb + (long)(n0 + n) * CIN + c0 + tc2) = w;
  }
  const int j = t & 31, g = t >> 5;
  u16 r[8] __attribute__((aligned(16)));
  #pragma unroll
  for (int k = 0; k < 8; k++) {
    const int c = g * 8 + k;
    const unsigned w0 = *(const unsigned*)&tile[c][2 * j];
    const unsigned w1 = *(const unsigned*)&tile[c][64 + 2 * j];
    float m0 = fmaxf(bf2f((u16)(w0 & 0xffffu)), bf2f((u16)(w0 >> 16)));
    float m1 = fmaxf(bf2f((u16)(w1 & 0xffffu)), bf2f((u16)(w1 >> 16)));
    r[k] = f2bf(fmaxf(m0, m1));
  }
  *(uint4*)(poolT + ((long)b * MPIX + bx * 32 + j) * CIN + c0 + g * 8) =
      *(uint4*)r;
}

// ====== 256x256-tile GEMM, 16 waves (1024 thr), 8-phase counted-vmcnt ====
// Wave tile 64x64 (wr=wave>>2, wc=wave&3), acc[4][4]. Stage-op = 1 gload/wave
// (16KB quarter = 16 waves x 1KB). Op-level schedule identical to the
// certified 8-wave version; vmcnt in 1-load units: main 4, tail [4,4,4,2,2,0,0,0].
// Single barrier per phase; RAW/WAR proofs unchanged.
template<int OM, bool HAS_BIAS, bool HAS_SHIFT, bool HAS_EXP, bool HAS_PSUM2,
         bool HAS_CSP, bool XSWZ>
__global__ __launch_bounds__(1024, 1)
void gemm256(const u16* __restrict__ A, const u16* __restrict__ B,
             void* __restrict__ Cv,
             const float* __restrict__ bias, long sBias,
             const float* __restrict__ cs, long sCS,
             const float* __restrict__ shift, long sShift,
             float* __restrict__ psum_out,
             float scale, int M, int N, int K, long sA, long sB, long sC)
{
  int bxi, byi, bzi;
  if (XSWZ) {
    const int q = blockIdx.x >> 5, s = blockIdx.x & 31;
    bxi = s >> 3;                       // 0..3
    const int yz = q * 8 + (s & 7);     // 0..127
    byi = yz & 15;
    bzi = yz >> 4;
  } else {
    bxi = blockIdx.x; byi = blockIdx.y; bzi = blockIdx.z;
  }
  A += bzi * sA;
  B += bzi * sB;
  if (HAS_BIAS) bias += bzi * sBias;
  if (HAS_CSP) cs += bzi * sCS;
  if (HAS_SHIFT) shift += bzi * sShift;
  const int bm = byi * 256, bn = bxi * 256;
  __shared__ __align__(16) u16 smem[65536];   // 2 slots x 64KB
  __shared__ float psum[4][256];
  __shared__ float psumq[4][256];
  __shared__ float invs[256];
  const int tid = threadIdx.x;
  const int lane = tid & 63, wave = tid >> 6;    // wave 0..15
  const int wr = wave >> 2, wc = wave & 3;       // 4M x 4N waves, 64x64 tile
  const int lr = lane & 15, q = lane >> 4;
  f32x4 acc[4][4] = {};

  if (HAS_CSP) {
    if (tid < 256) {
      float ssum = 0.f;
      #pragma unroll
      for (int xx = 0; xx < 4; xx++) ssum += cs[xx * 4096 + bn + tid];
      invs[tid] = 1.0f / ssum;
    }
    wait_vmcnt<0>();
    __builtin_amdgcn_sched_barrier(0);
  }

  // staging: wave covers quarter rows [16w,16w+16); lane l -> row 16w+(l>>2),
  // chunk (l&3); global chunk = (l&3)^((row>>1)&3) = (l&3)^((l>>3)&3)
  const int srow = 16 * wave + (lane >> 2);
  const int sk = (((lane & 3) ^ ((lane >> 3) & 3))) * 8;
  const u16* Abase = A + ((long)bm + srow) * K + sk;
  const u16* Bbase = B + ((long)bn + srow) * K + sk;
  const int rswz = (q ^ ((lr >> 1) & 3)) * 8;
  const int aoff = (wr * 64 + lr) * 32 + rswz;
  const int boff = 16384 + (wc * 64 + lr) * 32 + rswz;

#define SA(T_, KK_) { const u16* g_ = Abase + (long)(T_) * 64 + (KK_) * 32; \
    u16* d_ = &smem[(((T_) & 1)) * 32768 + (KK_) * 8192 + wave * 512]; \
    gload16(g_, d_); }
#define SB(T_, KK_) { const u16* g_ = Bbase + (long)(T_) * 64 + (KK_) * 32; \
    u16* d_ = &smem[(((T_) & 1)) * 32768 + 16384 + (KK_) * 8192 + wave * 512]; \
    gload16(g_, d_); }
#define PH(VM, STG, SLOT, KK, RI0, LOADBV) { \
    const int qb_ = (SLOT) * 32768 + (KK) * 8192; \
    short8 av_[2]; \
    if (LOADBV) { \
      _Pragma("unroll") \
      for (int ci_ = 0; ci_ < 4; ci_++) \
        bv[ci_] = *(const short8*)&smem[qb_ + boff + ci_ * 512]; \
    } \
    _Pragma("unroll") \
    for (int r_ = 0; r_ < 2; r_++) \
      av_[r_] = *(const short8*)&smem[qb_ + aoff + ((RI0) + r_) * 512]; \
    STG; \
    wait_vmcnt<VM>(); \
    __builtin_amdgcn_sched_barrier(0); \
    __builtin_amdgcn_s_barrier(); \
    asm volatile("s_waitcnt lgkmcnt(0)" ::: "memory"); \
    __builtin_amdgcn_sched_barrier(0); \
    __builtin_amdgcn_s_setprio(1); \
    _Pragma("unroll") \
    for (int r_ = 0; r_ < 2; r_++) \
      _Pragma("unroll") \
      for (int ci_ = 0; ci_ < 4; ci_++) \
        acc[(RI0) + r_][ci_] = __builtin_amdgcn_mfma_f32_16x16x32_bf16( \
            av_[r_], bv[ci_], acc[(RI0) + r_][ci_], 0, 0, 0); \
    __builtin_amdgcn_s_setprio(0); \
    __builtin_amdgcn_sched_barrier(0); }

  const int niter2 = K >> 7;
  short8 bv[4];

  // prologue: 6 stage-ops (6 loads); vmcnt(4) certifies S1,S2 for ph0 reads
  SA(0, 0); SB(0, 0); SA(0, 1); SB(0, 1); SA(1, 0); SB(1, 0);
  wait_vmcnt<4>();
  __builtin_amdgcn_s_barrier();
  __builtin_amdgcn_sched_barrier(0);

  for (int u = 0; u < niter2 - 1; ++u) {
    const int t1 = 2 * u + 1, t2 = 2 * u + 2, t3 = 2 * u + 3;
    PH(4, SA(t1, 1), 0, 0, 0, 1)
    PH(4, SB(t1, 1), 0, 0, 2, 0)
    PH(4, SA(t2, 0), 0, 1, 0, 1)
    PH(4, SB(t2, 0), 0, 1, 2, 0)
    PH(4, SA(t2, 1), 1, 0, 0, 1)
    PH(4, SB(t2, 1), 1, 0, 2, 0)
    PH(4, SA(t3, 0), 1, 1, 0, 1)
    PH(4, SB(t3, 0), 1, 1, 2, 0)
  }
  {
    const int t1 = 2 * (niter2 - 1) + 1;
    PH(4, SA(t1, 1), 0, 0, 0, 1)
    PH(4, SB(t1, 1), 0, 0, 2, 0)
    PH(4, ((void)0), 0, 1, 0, 1)
    PH(2, ((void)0), 0, 1, 2, 0)
    PH(2, ((void)0), 1, 0, 0, 1)
    PH(0, ((void)0), 1, 0, 2, 0)
    PH(0, ((void)0), 1, 1, 0, 1)
    PH(0, ((void)0), 1, 1, 2, 0)
  }
#undef SA
#undef SB
#undef PH

  __syncthreads();

  const int dr = (lane >> 4) * 4;
  float invc[4];
  if (HAS_CSP) {
    #pragma unroll
    for (int ci = 0; ci < 4; ci++) invc[ci] = invs[wc * 64 + ci * 16 + lr];
  }
  float rowsum[4][4], rowsq[4][4];
  if (HAS_EXP || HAS_PSUM2) {
    #pragma unroll
    for (int ri = 0; ri < 4; ri++)
      #pragma unroll
      for (int r = 0; r < 4; r++) { rowsum[ri][r] = 0.f; rowsq[ri][r] = 0.f; }
  }
  #pragma unroll
  for (int ri = 0; ri < 4; ri++) {
    const int rowl = wr * 64 + ri * 16 + dr;
    const int rowb = bm + rowl;
    float bvs[4] = {0.f, 0.f, 0.f, 0.f};
    float shv[4] = {0.f, 0.f, 0.f, 0.f};
    if (HAS_BIAS) {
      #pragma unroll
      for (int r = 0; r < 4; r++) bvs[r] = bias[rowb + r];
    }
    if (HAS_SHIFT) {
      #pragma unroll
      for (int r = 0; r < 4; r++) shv[r] = shift[rowb + r];
    }
    #pragma unroll
    for (int ci = 0; ci < 4; ci++) {
      const int coll = wc * 64 + ci * 16 + lr;
      float v[4];
      #pragma unroll
      for (int r = 0; r < 4; r++) {
        float tv = acc[ri][ci][r] * scale;
        if (HAS_CSP) tv *= invc[ci];
        if (HAS_SHIFT) tv -= shv[r];
        if (HAS_BIAS) tv += bvs[r];
        if (HAS_EXP) tv = __expf(tv);
        if (HAS_EXP || HAS_PSUM2) rowsum[ri][r] += tv;
        if (HAS_PSUM2) rowsq[ri][r] += tv * tv;
        v[r] = tv;
      }
      if (OM == 1) {
        u16x4 w;
        #pragma unroll
        for (int r = 0; r < 4; r++) w[r] = f2bf(v[r]);
        unsigned bo = (unsigned)((coll * 256 + rowl) * 2) ^ ((coll & 7) << 4);
        *(u16x4*)((char*)smem + bo) = w;
      } else {
        #pragma unroll
        for (int r = 0; r < 4; r++) {
          const int row = rowl + r;
          smem[row * 256 + (coll ^ (((row >> 2) & 3) << 4))] = f2bf(v[r]);
        }
      }
    }
  }
  if (HAS_EXP || HAS_PSUM2) {
    #pragma unroll
    for (int msk = 1; msk < 16; msk <<= 1)
      #pragma unroll
      for (int ri = 0; ri < 4; ri++)
        #pragma unroll
        for (int r = 0; r < 4; r++) {
          rowsum[ri][r] += __shfl_xor(rowsum[ri][r], msk);
          if (HAS_PSUM2) rowsq[ri][r] += __shfl_xor(rowsq[ri][r], msk);
        }
    if ((lane & 15) == 0) {
      #pragma unroll
      for (int ri = 0; ri < 4; ri++)
        #pragma unroll
        for (int r = 0; r < 4; r++) {
          psum[wc][wr * 64 + ri * 16 + dr + r] = rowsum[ri][r];
          if (HAS_PSUM2) psumq[wc][wr * 64 + ri * 16 + dr + r] = rowsq[ri][r];
        }
    }
  }
  __syncthreads();
  u16* C = (u16*)Cv + bzi * sC;
  if (OM == 1) {
    #pragma unroll
    for (int i = 0; i < 8; i++) {
      const int chunk = i * 1024 + tid;
      const int coll = chunk >> 5, rq = chunk & 31;
      unsigned bo = (unsigned)(coll * 512 + rq * 16) ^ ((coll & 7) << 4);
      uint4 w = *(const uint4*)((const char*)smem + bo);
      *(uint4*)(C + (long)(bn + coll) * M + bm + rq * 8) = w;
    }
  } else {
    #pragma unroll
    for (int i = 0; i < 8; i++) {
      const int chunk = i * 1024 + tid;
      const int row = chunk >> 5, cq = chunk & 31;
      const int cbase = (cq * 8) ^ (((row >> 2) & 3) << 4);
      uint4 w = *(const uint4*)(smem + row * 256 + cbase);
      *(uint4*)(C + (long)(bm + row) * N + bn + cq * 8) = w;
    }
  }
  if ((HAS_EXP || HAS_PSUM2) && tid < 256) {
    const int gX = XSWZ ? 4 : gridDim.x;
    if (HAS_EXP)
      psum_out[((long)bzi * gX + bxi) * 4096 + bm + tid] =
          psum[0][tid] + psum[1][tid] + psum[2][tid] + psum[3][tid];
    if (HAS_PSUM2) {
      const int gY = XSWZ ? 16 : gridDim.y;
      const long blk = ((long)bzi * gY + byi) * gX + bxi;
      psum_out[blk * 512 + tid] =
          psum[0][tid] + psum[1][tid] + psum[2][tid] + psum[3][tid];
      psum_out[blk * 512 + 256 + tid] =
          psumq[0][tid] + psumq[1][tid] + psumq[2][tid] + psumq[3][tid];
    }
  }
}

// ---------------- 128x128 GEMM (merged phi+g) ----------------
template<int OM, bool HAS_BIAS, bool HAS_CS, bool HAS_SHIFT, bool HAS_EXP,
         bool HAS_PSUM2, bool HAS_CSP>
__global__ __launch_bounds__(256)
void gemm_tn(const u16* __restrict__ A, const u16* __restrict__ B,
             void* __restrict__ Cv, void* __restrict__ Cv2,
             const float* __restrict__ bias, const float* __restrict__ bias2,
             long sBias,
             const float* __restrict__ cs, long sCS,
             const float* __restrict__ shift, long sShift,
             float* __restrict__ psum_out,
             float scale, int M, int N, int K, long sA, long sB, long sC)
{
  A += blockIdx.z * sA;
  B += blockIdx.z * sB;
  if (HAS_BIAS) bias += blockIdx.z * sBias;
  if (HAS_CS || HAS_CSP) cs += blockIdx.z * sCS;
  if (HAS_SHIFT) shift += blockIdx.z * sShift;
  const int bm = blockIdx.y * 128;
  const int bn = blockIdx.x * 128;
  __shared__ __align__(16) u16 smem[128 * 128];
  u16* As = smem;
  u16* Bs = smem + 128 * 64;
  __shared__ float psum[4][128];
  const int tid = threadIdx.x;
  const int lane = tid & 63;
  const int wave = tid >> 6;
  const int wm = (wave >> 1) * 64;
  const int wn = (wave & 1) * 64;
  const int lr = lane & 15;
  const int q  = lane >> 4;
  const int sxor = lane & 7;
  const bool gps = (OM == 3) && (bm >= 512);
  f32x4 acc[4][4] = {};

  if (HAS_CSP) {
    if (tid < 128) {
      float s = 0.f;
      #pragma unroll
      for (int xx = 0; xx < 8; xx++) s += cs[xx * 4096 + bn + tid];
      psum[0][tid] = 1.0f / s;
    }
  }

  const int swz = ((lane & 7) ^ (lane >> 3)) * 8;
  const long grow = 32 * wave + (lane >> 3);
  const u16* Ag = A + ((long)bm + grow) * K + swz;
  const u16* Bg = B + ((long)bn + grow) * K + swz;

  for (int kt = 0; kt < K; kt += 64) {
    __syncthreads();
    #pragma unroll
    for (int i = 0; i < 4; i++) {
      gload16(Ag + (long)(8 * i) * K + kt, &As[(wave * 4 + i) * 512]);
      gload16(Bg + (long)(8 * i) * K + kt, &Bs[(wave * 4 + i) * 512]);
    }
    __syncthreads();
    #pragma unroll
    for (int kk = 0; kk < 2; kk++) {
      short8 av[4], bv[4];
      #pragma unroll
      for (int mi = 0; mi < 4; mi++)
        av[mi] = *(const short8*)&As[(wm + mi * 16 + lr) * 64 +
                                     (((kk << 2) + q) ^ sxor) * 8];
      #pragma unroll
      for (int ni = 0; ni < 4; ni++)
        bv[ni] = *(const short8*)&Bs[(wn + ni * 16 + lr) * 64 +
                                     (((kk << 2) + q) ^ sxor) * 8];
      #pragma unroll
      for (int mi = 0; mi < 4; mi++) {
        #pragma unroll
        for (int ni = 0; ni < 4; ni++)
          acc[mi][ni] = __builtin_amdgcn_mfma_f32_16x16x32_bf16(
              av[mi], bv[ni], acc[mi][ni], 0, 0, 0);
      }
    }
  }

  float invc[4];
  if (HAS_CSP) {
    #pragma unroll
    for (int ni = 0; ni < 4; ni++) invc[ni] = psum[0][wn + ni * 16 + lr];
  }
  __syncthreads();
  const int dr = (lane >> 4) * 4;
  const bool trans_out = (OM == 1) || (OM == 3 && !gps);
  float rowsum[4][4];
  float rowsq[4][4];
  if (HAS_EXP || HAS_PSUM2 || gps) {
    #pragma unroll
    for (int mi = 0; mi < 4; mi++)
      #pragma unroll
      for (int r = 0; r < 4; r++) { rowsum[mi][r] = 0.f; rowsq[mi][r] = 0.f; }
  }
  const float* bp = (OM == 3 && gps) ? bias2 - 512 : bias;
  #pragma unroll
  for (int mi = 0; mi < 4; mi++) {
    const int rowl = wm + mi * 16 + dr;
    const int rowb = bm + rowl;
    float bvs[4] = {0.f, 0.f, 0.f, 0.f};
    float shv[4] = {0.f, 0.f, 0.f, 0.f};
    if (HAS_BIAS) {
      #pragma unroll
      for (int r = 0; r < 4; r++) bvs[r] = bp[rowb + r];
    }
    if (HAS_SHIFT) {
      #pragma unroll
      for (int r = 0; r < 4; r++) shv[r] = shift[rowb + r];
    }
    #pragma unroll
    for (int ni = 0; ni < 4; ni++) {
      const int coll = wn + ni * 16 + lr;
      const float csv = HAS_CSP ? invc[ni] : (HAS_CS ? cs[bn + coll] : 1.0f);
      float v[4];
      #pragma unroll
      for (int r = 0; r < 4; r++) {
        float t = acc[mi][ni][r] * scale;
        if (HAS_CS || HAS_CSP) t *= csv;
        if (HAS_SHIFT) t -= shv[r];
        if (HAS_BIAS) t += bvs[r];
        if (HAS_EXP) t = __expf(t);
        if (HAS_EXP || HAS_PSUM2 || gps) rowsum[mi][r] += t;
        if (HAS_PSUM2) rowsq[mi][r] += t * t;
        v[r] = t;
      }
      if (trans_out) {
        u16x4 w;
        #pragma unroll
        for (int r = 0; r < 4; r++) w[r] = f2bf(v[r]);
        unsigned bo = (unsigned)((coll * 128 + rowl) * 2) ^ ((coll & 7) << 4);
        *(u16x4*)((char*)smem + bo) = w;
      } else {
        #pragma unroll
        for (int r = 0; r < 4; r++) {
          const int row = rowl + r;
          smem[row * 128 + (coll ^ (((row >> 2) & 3) << 4))] = f2bf(v[r]);
        }
      }
    }
  }
  if (HAS_EXP || HAS_PSUM2 || gps) {
    #pragma unroll
    for (int msk = 1; msk < 16; msk <<= 1)
      #pragma unroll
      for (int mi = 0; mi < 4; mi++)
        #pragma unroll
        for (int r = 0; r < 4; r++) {
          rowsum[mi][r] += __shfl_xor(rowsum[mi][r], msk);
          if (HAS_PSUM2) rowsq[mi][r] += __shfl_xor(rowsq[mi][r], msk);
        }
    if ((lane & 15) == 0) {
      #pragma unroll
      for (int mi = 0; mi < 4; mi++)
        #pragma unroll
        for (int r = 0; r < 4; r++) {
          psum[wave & 1][wm + mi * 16 + dr + r] = rowsum[mi][r];
          if (HAS_PSUM2) psum[2 + (wave & 1)][wm + mi * 16 + dr + r] = rowsq[mi][r];
        }
    }
  }
  __syncthreads();
  if (trans_out) {
    const int Ms = (OM == 3) ? 512 : M;
    u16* C = (u16*)Cv + blockIdx.z * sC;
    #pragma unroll
    for (int i = 0; i < 8; i++) {
      const int chunk = i * 256 + tid;
      const int coll = chunk >> 4, rq = chunk & 15;
      unsigned bo = (unsigned)(coll * 256 + rq * 16) ^ ((coll & 7) << 4);
      uint4 w = *(const uint4*)((const char*)smem + bo);
      *(uint4*)(C + (long)(bn + coll) * Ms + bm + rq * 8) = w;
    }
  } else {
    u16* C = (OM == 3) ? (u16*)Cv2 + blockIdx.z * sC : (u16*)Cv + blockIdx.z * sC;
    const int rbase = (OM == 3) ? bm - 512 : bm;
    #pragma unroll
    for (int i = 0; i < 8; i++) {
      const int chunk = i * 256 + tid;
      const int row = chunk >> 4, cq = chunk & 15;
      const int cbase = (cq * 8) ^ (((row >> 2) & 3) << 4);
      uint4 w = *(const uint4*)(smem + row * 128 + cbase);
      *(uint4*)(C + (long)(rbase + row) * N + bn + cq * 8) = w;
    }
  }
  if (HAS_EXP || HAS_PSUM2 || gps) {
    if (tid < 128) {
      if (HAS_EXP)
        psum_out[((long)blockIdx.z * gridDim.x + blockIdx.x) * 4096 + bm + tid] =
            psum[0][tid] + psum[1][tid];
      if (HAS_PSUM2) {
        const long blk = ((long)blockIdx.z * gridDim.y + blockIdx.y) * gridDim.x
                         + blockIdx.x;
        psum_out[blk * 256 + tid] = psum[0][tid] + psum[1][tid];
        psum_out[blk * 256 + 128 + tid] = psum[2][tid] + psum[3][tid];
      }
      if (gps)
        psum_out[((long)blockIdx.z * gridDim.x + blockIdx.x) * 512 +
                 (bm - 512) + tid] = psum[0][tid] + psum[1][tid];
    }
  }
}

// --- c0[b][c] = out_b[c] + sum_d out_w_f32[c][d]*gbar[b][d] ; gbar inline --
__global__ __launch_bounds__(256) void c0_kernel(const float* __restrict__ out_w,
                                                 const float* __restrict__ out_b,
                                                 const float* __restrict__ g_ps,
                                                 float* __restrict__ gbar,
                                                 float* __restrict__ c0) {
  const int idx = blockIdx.x * 4 + (threadIdx.x >> 6);   // 0..8191 = b*1024+c
  const int lane = threadIdx.x & 63;
  const int b = idx >> 10, c = idx & 1023;
  const int d0 = lane * 8;
  float g8[8] = {0.f, 0.f, 0.f, 0.f, 0.f, 0.f, 0.f, 0.f};
  #pragma unroll
  for (int xx = 0; xx < 8; xx++) {
    const float* p = g_ps + ((long)b * 8 + xx) * 512 + d0;
    float4 a0 = *(const float4*)p;
    float4 a1 = *(const float4*)(p + 4);
    g8[0] += a0.x; g8[1] += a0.y; g8[2] += a0.z; g8[3] += a0.w;
    g8[4] += a1.x; g8[5] += a1.y; g8[6] += a1.z; g8[7] += a1.w;
  }
  #pragma unroll
  for (int k = 0; k < 8; k++) g8[k] *= (1.0f / 1024.0f);
  if (c == 0) {
    float4 o0, o1;
    o0.x = g8[0]; o0.y = g8[1]; o0.z = g8[2]; o0.w = g8[3];
    o1.x = g8[4]; o1.y = g8[5]; o1.z = g8[6]; o1.w = g8[7];
    *(float4*)(gbar + (long)b * 512 + d0) = o0;
    *(float4*)(gbar + (long)b * 512 + d0 + 4) = o1;
  }
  float4 w0 = *(const float4*)(out_w + (long)c * DI + d0);
  float4 w1 = *(const float4*)(out_w + (long)c * DI + d0 + 4);
  float s = w0.x * g8[0] + w0.y * g8[1] + w0.z * g8[2] + w0.w * g8[3]
          + w1.x * g8[4] + w1.y * g8[5] + w1.z * g8[6] + w1.w * g8[7];
  #pragma unroll
  for (int off = 32; off > 0; off >>= 1) s += __shfl_xor(s, off);
  if (lane == 0) c0[idx] = out_b[c] + s;
}

// ------ BN stats (from y-GEMM partials) + apply + residual, fused --------
__global__ __launch_bounds__(256) void final_kernel(const u16* __restrict__ dy,
    const float* __restrict__ x, const float* __restrict__ partial,
    const float* __restrict__ c0,
    const float* __restrict__ bnw, const float* __restrict__ bnb,
    float* __restrict__ out) {
  __shared__ float red[6];
  __shared__ float bcast[2];
  const int bc = blockIdx.x;
  const int co = bc & 1023;
  const int t = threadIdx.x;
  if (t < 128) {
    const int b2 = t >> 4, bx = t & 15;
    const int by = co >> 8, r = co & 255;
    const long blk = (((long)b2 * 4 + by) * 16 + bx) * 512;
    float s = partial[blk + r];
    float qq = partial[blk + 256 + r];
    #pragma unroll
    for (int off = 1; off < 16; off <<= 1) {
      s += __shfl_xor(s, off);
      qq += __shfl_xor(qq, off);
    }
    float sbc = c0[b2 * 1024 + co] * s;
    #pragma unroll
    for (int off = 16; off < 64; off <<= 1) {
      s += __shfl_xor(s, off);
      qq += __shfl_xor(qq, off);
      sbc += __shfl_xor(sbc, off);
    }
    if (t == 0)  { red[0] = s; red[1] = qq; red[2] = sbc; }
    if (t == 64) { red[3] = s; red[4] = qq; red[5] = sbc; }
  }
  __syncthreads();
  if (t == 0) {
    float sdT = red[0] + red[3], sd2T = red[1] + red[4], sbcT = red[2] + red[5];
    float sc0 = 0.f, sc02 = 0.f;
    #pragma unroll
    for (int bb = 0; bb < 8; bb++) {
      float c = c0[bb * 1024 + co];
      sc0 += c; sc02 += c * c;
    }
    float S = 4096.0f * sc0 + sdT;
    float S2 = 4096.0f * sc02 + 2.0f * sbcT + sd2T;
    float mean = S * (1.0f / 32768.0f);
    float var = S2 * (1.0f / 32768.0f) - mean * mean;
    float inv = rsqrtf(var + 1e-5f) * bnw[co];
    bcast[0] = inv;
    bcast[1] = bnb[co] - mean * inv + c0[bc] * inv;
  }
  __syncthreads();
  const float inv = bcast[0], addc = bcast[1];
  const long base = (long)bc * 4096;
  #pragma unroll
  for (int i = 0; i < 2; i++) {
    const long off = base + (long)(i * 256 + t) * 8;
    uint4 v = *(const uint4*)(dy + off);
    float f[8]; unpack8(v, f);
    const float4 x0 = *(const float4*)(x + off);
    const float4 x1 = *(const float4*)(x + off + 4);
    float4 o0, o1;
    o0.x = f[0] * inv + addc + x0.x;
    o0.y = f[1] * inv + addc + x0.y;
    o0.z = f[2] * inv + addc + x0.z;
    o0.w = f[3] * inv + addc + x0.w;
    o1.x = f[4] * inv + addc + x1.x;
    o1.y = f[5] * inv + addc + x1.y;
    o1.z = f[6] * inv + addc + x1.z;
    o1.w = f[7] * inv + addc + x1.w;
    *(float4*)(out + off) = o0;
    *(float4*)(out + off + 4) = o1;
  }
}

extern "C" void kernel_launch(void* const* d_in, const int* in_sizes, int n_in,
                              void* d_out, int out_size, void* d_ws, size_t ws_size,
                              hipStream_t stream) {
  (void)in_sizes; (void)n_in; (void)out_size; (void)ws_size;
  const float* x       = (const float*)d_in[0];
  const float* theta_w = (const float*)d_in[1];
  const float* theta_b = (const float*)d_in[2];
  const float* phi_w   = (const float*)d_in[3];
  const float* phi_b   = (const float*)d_in[4];
  const float* g_w     = (const float*)d_in[5];
  const float* g_b     = (const float*)d_in[6];
  const float* out_w   = (const float*)d_in[7];
  const float* out_b   = (const float*)d_in[8];
  const float* bn_w    = (const float*)d_in[9];
  const float* bn_b    = (const float*)d_in[10];
  float* out = (float*)d_out;
  char* ws = (char*)d_ws;
  const size_t MB = 1024 * 1024;

  // workspace layout
  u16* xT     = (u16*)(ws + 0 * MB);       // 64MB; later: dy bf16 [0,64MB)
  u16* poolT  = (u16*)(ws + 64 * MB);      // 16MB
  u16* w_th   = (u16*)(ws + 80 * MB);      // 1MB
  u16* w_ph   = (u16*)(ws + 81 * MB);      // 1MB  (w_ph || w_g contiguous)
  u16* w_g    = (u16*)(ws + 82 * MB);      // 1MB
  u16* thetaT = (u16*)(ws + 84 * MB);      // 32MB
  u16* phiT   = (u16*)(ws + 116 * MB);     // 8MB
  u16* g_n    = (u16*)(ws + 124 * MB);     // 8MB
  u16* e      = (u16*)(ws + 132 * MB);     // 64MB (exp(scores))
  u16* tT     = (u16*)(ws + 196 * MB);     // 32MB (delta-t bf16)
  u16* w_out  = (u16*)(ws + 228 * MB);     // 1MB
  float* gbar  = (float*)(ws + 229 * MB);            // 16KB
  float* c0b   = (float*)(ws + 229 * MB + 16384);    // 32KB
  float* partial = (float*)(ws + 230 * MB);          // 512KB (8*4*4096 f32)
  float* partial2 = (float*)(ws + 231 * MB);         // 1MB (512 blk * 512 f32)
  float* g_ps = (float*)(ws + 233 * MB);             // 128KB (8*8*512 f32)
  u16* dy = xT;               // alias: x_T dead after theta GEMM

  // 1. prep: weights->bf16 + x->x_T + pool (single launch)
  prep_kernel<<<6144, 256, 0, stream>>>(x, xT, poolT,
                                        theta_w, phi_w, g_w, out_w,
                                        w_th, w_ph, w_g, w_out);
  // 2. theta -> theta_T [b][4096][512]  (256-tile, 16-wave 8-phase GEMM)
  gemm256<1, true, false, false, false, false, false>
      <<<dim3(16, 2, 8), 1024, 0, stream>>>(
      w_th, xT, thetaT, theta_b, 0L, nullptr, 0L, nullptr, 0L, nullptr,
      1.0f, 512, 4096, 1024, 0L, (long)NPIX * CIN, (long)NPIX * DI);
  // 3. merged phi+g GEMM (128-tile kernel) -> phiT, g_n, g_ps
  gemm_tn<3, true, false, false, false, false, false>
      <<<dim3(8, 8, 8), 256, 0, stream>>>(
      w_ph, poolT, phiT, g_n, phi_b, g_b, 0L, nullptr, 0L, nullptr, 0L,
      g_ps, 1.0f, 1024, 1024, 1024, 0L, (long)MPIX * CIN, (long)MPIX * DI);
  // 4. c0 (computes gbar inline from g_ps; writes gbar for t-GEMM)
  c0_kernel<<<2048, 256, 0, stream>>>(out_w, out_b, g_ps, gbar, c0b);
  // 5. e[n][m] = exp(scores) + rowsum partials; XCD-swizzled flat launch
  gemm256<0, false, false, true, false, false, true>
      <<<512, 1024, 0, stream>>>(
      thetaT, phiT, e, nullptr, 0L, nullptr, 0L, nullptr, 0L, partial,
      0.044194173824159216f, 4096, 1024, 512,
      (long)NPIX * DI, (long)MPIX * DI, (long)NPIX * MPIX);
  // 6. delta-t = (g_n * e^T)*inv[n] - gbar[d]; inv from partials (CSP)
  gemm256<1, false, true, false, false, true, false>
      <<<dim3(16, 2, 8), 1024, 0, stream>>>(
      g_n, e, tT, nullptr, 0L, partial, 16384L, gbar, 512L, nullptr,
      1.0f, 512, 4096, 1024,
      (long)DI * MPIX, (long)NPIX * MPIX, (long)NPIX * DI);
  // 7. dy = out_w * delta-t^T + BN partials (PSUM2)
  gemm256<0, false, false, false, true, false, false>
      <<<dim3(16, 4, 8), 1024, 0, stream>>>(
      w_out, tT, dy, nullptr, 0L, nullptr, 0L, nullptr, 0L, partial2,
      1.0f, 1024, 4096, 512, 0L, (long)NPIX * DI, (long)1024 * NPIX);
  // 8. BN stats (from partials, in-block) + apply + residual
  final_kernel<<<8192, 256, 0, stream>>>(dy, x, partial2, c0b, bn_w, bn_b, out);
}